// Round 2
// baseline (6288.324 us; speedup 1.0000x reference)
//
#include <hip/hip_runtime.h>
#include <cstddef>

#define DEVINF __builtin_inff()

// ---------------------------------------------------------------------------
// FPS: farthest point sampling, exact numpy semantics. (unchanged — correct)
// ---------------------------------------------------------------------------
template <int N, int PPL>
__global__ __launch_bounds__(256) void fps_kernel(const float* __restrict__ pos,
                                                  int S, float* __restrict__ ctr) {
#pragma clang fp contract(off)
  const int b = blockIdx.x;
  const int tid = threadIdx.x;
  __shared__ float px[N], py[N], pz[N];
  __shared__ float rv[2][4];
  __shared__ int ri[2][4];
  for (int i = tid; i < N; i += 256) {
    px[i] = pos[((size_t)b * N + i) * 3 + 0];
    py[i] = pos[((size_t)b * N + i) * 3 + 1];
    pz[i] = pos[((size_t)b * N + i) * 3 + 2];
  }
  __syncthreads();
  float qx[PPL], qy[PPL], qz[PPL], d[PPL];
#pragma unroll
  for (int q = 0; q < PPL; ++q) {
    int i = q * 256 + tid;
    qx[q] = px[i]; qy[q] = py[i]; qz[q] = pz[i];
    d[q] = DEVINF;
  }
  int last = 0;
  for (int s = 0; s < S; ++s) {
    if (tid == 0) {
      ctr[((size_t)b * S + s) * 3 + 0] = px[last];
      ctr[((size_t)b * S + s) * 3 + 1] = py[last];
      ctr[((size_t)b * S + s) * 3 + 2] = pz[last];
    }
    float lx = px[last], ly = py[last], lz = pz[last];
    float bv = -DEVINF;
    int bi = 0x7fffffff;
#pragma unroll
    for (int q = 0; q < PPL; ++q) {
      float dx = qx[q] - lx, dy = qy[q] - ly, dz = qz[q] - lz;
      float t0 = dx * dx, t1 = dy * dy, t2 = dz * dz;
      float d2 = (t0 + t1) + t2;
      float dn = fminf(d[q], d2);
      d[q] = dn;
      int i = q * 256 + tid;
      if (dn > bv) { bv = dn; bi = i; }
    }
#pragma unroll
    for (int off = 1; off < 64; off <<= 1) {
      float ov = __shfl_xor(bv, off, 64);
      int oi = __shfl_xor(bi, off, 64);
      if (ov > bv || (ov == bv && oi < bi)) { bv = ov; bi = oi; }
    }
    int pb = s & 1;
    if ((tid & 63) == 0) { rv[pb][tid >> 6] = bv; ri[pb][tid >> 6] = bi; }
    __syncthreads();
    float fv = rv[pb][0];
    int fi = ri[pb][0];
#pragma unroll
    for (int w = 1; w < 4; ++w) {
      float ov = rv[pb][w];
      int oi = ri[pb][w];
      if (ov > fv || (ov == fv && oi < fi)) { fv = ov; fi = oi; }
    }
    last = fi;
  }
}

// ---------------------------------------------------------------------------
// SA1 v2: one center per block, 4 waves o-split the MLP output channels.
// lane = edge. hb is lane-major (stride 68 floats) -> ds_read_b128.
// Summation order per output (bias + ascending k) identical to reference path.
// ---------------------------------------------------------------------------
__global__ __launch_bounds__(256, 4) void sa1_kernel(
    const float* __restrict__ x,    // [16][2048][9]
    const float* __restrict__ pos,  // [16][2048][3]
    const float* __restrict__ ctr,  // [16][1024][3]
    const float* __restrict__ w1, const float* __restrict__ b1,
    const float* __restrict__ w2, const float* __restrict__ b2,
    const float* __restrict__ w3, const float* __restrict__ b3,
    float* __restrict__ out)        // [16][1024][128]
{
  const int N = 2048;
  const float r2 = (float)(0.2 * 0.2);
  const int bs = blockIdx.x;
  const int b = bs >> 10;
  const int tid = threadIdx.x;
  const int w = tid >> 6, lane = tid & 63;
  const float cx = ctr[bs * 3 + 0], cy = ctr[bs * 3 + 1], cz = ctr[bs * 3 + 2];
  __shared__ int nb[4][64];
  __shared__ __align__(16) float hb[64][68];   // 17 float4 stride
  // ball query — each wave computes it redundantly in its own nb slice
  nb[w][lane] = 0;
  int cnt = 0;
  {
#pragma clang fp contract(off)
    for (int base = 0; base < N && cnt < 64; base += 64) {
      int i = base + lane;
      const float* p = pos + ((size_t)b * N + i) * 3;
      float dx = p[0] - cx, dy = p[1] - cy, dz = p[2] - cz;
      float t0 = dx * dx, t1 = dy * dy, t2 = dz * dz;
      float d2 = (t0 + t1) + t2;
      bool inr = d2 <= r2;
      unsigned long long m = __ballot(inr);
      int posn = cnt + (int)__popcll(m & ((1ull << lane) - 1ull));
      if (inr && posn < 64) nb[w][posn] = i;
      cnt += (int)__popcll(m);
    }
  }
  const int nvalid = cnt < 64 ? cnt : 64;
  const bool valid = lane < nvalid;
  const int j = nb[w][lane];
  float feat[12];
  {
    const float* xr = x + ((size_t)b * N + j) * 9;
#pragma unroll
    for (int k = 0; k < 9; ++k) feat[k] = xr[k];
    const float* pr = pos + ((size_t)b * N + j) * 3;
    feat[9] = pr[0] - cx; feat[10] = pr[1] - cy; feat[11] = pr[2] - cz;
  }
  // ---- layer1: out 64, this wave does [w*16, w*16+16) ----
  {
    const float* w1s = w1 + w * 16;
    float acc[16];
#pragma unroll
    for (int o = 0; o < 16; ++o) acc[o] = b1[w * 16 + o];
#pragma unroll
    for (int k = 0; k < 12; ++k) {
      float v = feat[k];
#pragma unroll
      for (int o = 0; o < 16; ++o) acc[o] = fmaf(v, w1s[k * 64 + o], acc[o]);
    }
#pragma unroll
    for (int o = 0; o < 16; ++o) hb[lane][w * 16 + o] = fmaxf(acc[o], 0.f);
  }
  __syncthreads();
  // ---- layer2: 64 -> 64, this wave does [w*16, w*16+16) ----
  float acc2[16];
  {
    const float* w2s = w2 + w * 16;
#pragma unroll
    for (int o = 0; o < 16; ++o) acc2[o] = b2[w * 16 + o];
    float4 cur = *(const float4*)&hb[lane][0];
#pragma unroll 1
    for (int g = 0; g < 16; ++g) {
      float4 nxt;
      if (g < 15) nxt = *(const float4*)&hb[lane][4 * (g + 1)];
      float vv[4] = {cur.x, cur.y, cur.z, cur.w};
#pragma unroll
      for (int jj = 0; jj < 4; ++jj) {
        float v = vv[jj];
        const float* wr = w2s + (g * 4 + jj) * 64;
#pragma unroll
        for (int o = 0; o < 16; ++o) acc2[o] = fmaf(v, wr[o], acc2[o]);
      }
      cur = nxt;
    }
  }
  __syncthreads();   // all waves done reading hb
#pragma unroll
  for (int o = 0; o < 16; ++o) hb[lane][w * 16 + o] = fmaxf(acc2[o], 0.f);
  __syncthreads();
  // ---- layer3: 64 -> 128, this wave does [w*32, w*32+32) + maxpool ----
  {
    const float* w3s = w3 + w * 32;
    float a3[32];
#pragma unroll
    for (int o = 0; o < 32; ++o) a3[o] = b3[w * 32 + o];
    float4 cur = *(const float4*)&hb[lane][0];
#pragma unroll 1
    for (int g = 0; g < 16; ++g) {
      float4 nxt;
      if (g < 15) nxt = *(const float4*)&hb[lane][4 * (g + 1)];
      float vv[4] = {cur.x, cur.y, cur.z, cur.w};
#pragma unroll
      for (int jj = 0; jj < 4; ++jj) {
        float v = vv[jj];
        const float* wr = w3s + (g * 4 + jj) * 128;
#pragma unroll
        for (int o = 0; o < 32; ++o) a3[o] = fmaf(v, wr[o], a3[o]);
      }
      cur = nxt;
    }
    float res = 0.f;
#pragma unroll
    for (int oo = 0; oo < 32; ++oo) {
      float a = fmaxf(a3[oo], 0.f);
      if (!valid) a = -DEVINF;
#pragma unroll
      for (int off = 1; off < 64; off <<= 1) a = fmaxf(a, __shfl_xor(a, off, 64));
      if (lane == oo) res = a;
    }
    if (lane < 32) out[(size_t)bs * 128 + w * 32 + lane] = res;
  }
}

// ---------------------------------------------------------------------------
// SA2 v2: one center per block, 4 waves o-split. lane = edge.
// hb stride 132 floats (33 float4). x1 rows gathered per lane with prefetch.
// ---------------------------------------------------------------------------
__global__ __launch_bounds__(256, 4) void sa2_kernel(
    const float* __restrict__ x1,   // [16][1024][128]
    const float* __restrict__ pos1, // [16][1024][3]
    const float* __restrict__ ctr,  // [16][256][3]
    const float* __restrict__ w1, const float* __restrict__ b1,
    const float* __restrict__ w2, const float* __restrict__ b2,
    const float* __restrict__ w3, const float* __restrict__ b3,
    float* __restrict__ out)        // [16][256][256]
{
  const int N = 1024;
  const float r2 = (float)(0.4 * 0.4);
  const int bs = blockIdx.x;
  const int b = bs >> 8;
  const int tid = threadIdx.x;
  const int w = tid >> 6, lane = tid & 63;
  const float cx = ctr[bs * 3 + 0], cy = ctr[bs * 3 + 1], cz = ctr[bs * 3 + 2];
  __shared__ int nb[4][64];
  __shared__ __align__(16) float hb[64][132];  // 33 float4 stride
  nb[w][lane] = 0;
  int cnt = 0;
  {
#pragma clang fp contract(off)
    for (int base = 0; base < N && cnt < 64; base += 64) {
      int i = base + lane;
      const float* p = pos1 + ((size_t)b * N + i) * 3;
      float dx = p[0] - cx, dy = p[1] - cy, dz = p[2] - cz;
      float t0 = dx * dx, t1 = dy * dy, t2 = dz * dz;
      float d2 = (t0 + t1) + t2;
      bool inr = d2 <= r2;
      unsigned long long m = __ballot(inr);
      int posn = cnt + (int)__popcll(m & ((1ull << lane) - 1ull));
      if (inr && posn < 64) nb[w][posn] = i;
      cnt += (int)__popcll(m);
    }
  }
  const int nvalid = cnt < 64 ? cnt : 64;
  const bool valid = lane < nvalid;
  const int j = nb[w][lane];
  const float* xr = x1 + ((size_t)b * N + j) * 128;
  const float* pr = pos1 + ((size_t)b * N + j) * 3;
  const float rel0 = pr[0] - cx, rel1 = pr[1] - cy, rel2 = pr[2] - cz;
  // ---- layer1: 131 -> 128, this wave does [w*32, w*32+32) ----
  {
    const float* w1s = w1 + w * 32;
    float acc[32];
#pragma unroll
    for (int o = 0; o < 32; ++o) acc[o] = b1[w * 32 + o];
    float4 cur = *(const float4*)xr;
#pragma unroll 1
    for (int g = 0; g < 32; ++g) {
      float4 nxt;
      if (g < 31) nxt = *(const float4*)(xr + 4 * (g + 1));
      float vv[4] = {cur.x, cur.y, cur.z, cur.w};
#pragma unroll
      for (int jj = 0; jj < 4; ++jj) {
        float v = vv[jj];
        const float* wr = w1s + (g * 4 + jj) * 128;
#pragma unroll
        for (int o = 0; o < 32; ++o) acc[o] = fmaf(v, wr[o], acc[o]);
      }
      cur = nxt;
    }
    float rr[3] = {rel0, rel1, rel2};
#pragma unroll
    for (int kk = 0; kk < 3; ++kk) {
      float v = rr[kk];
      const float* wr = w1s + (128 + kk) * 128;
#pragma unroll
      for (int o = 0; o < 32; ++o) acc[o] = fmaf(v, wr[o], acc[o]);
    }
#pragma unroll
    for (int o = 0; o < 32; ++o) hb[lane][w * 32 + o] = fmaxf(acc[o], 0.f);
  }
  __syncthreads();
  // ---- layer2: 128 -> 128, this wave does [w*32, w*32+32) ----
  float acc2[32];
  {
    const float* w2s = w2 + w * 32;
#pragma unroll
    for (int o = 0; o < 32; ++o) acc2[o] = b2[w * 32 + o];
    float4 cur = *(const float4*)&hb[lane][0];
#pragma unroll 1
    for (int g = 0; g < 32; ++g) {
      float4 nxt;
      if (g < 31) nxt = *(const float4*)&hb[lane][4 * (g + 1)];
      float vv[4] = {cur.x, cur.y, cur.z, cur.w};
#pragma unroll
      for (int jj = 0; jj < 4; ++jj) {
        float v = vv[jj];
        const float* wr = w2s + (g * 4 + jj) * 128;
#pragma unroll
        for (int o = 0; o < 32; ++o) acc2[o] = fmaf(v, wr[o], acc2[o]);
      }
      cur = nxt;
    }
  }
  __syncthreads();
#pragma unroll
  for (int o = 0; o < 32; ++o) hb[lane][w * 32 + o] = fmaxf(acc2[o], 0.f);
  __syncthreads();
  // ---- layer3: 128 -> 256, this wave does [w*64, w*64+64) + maxpool ----
  {
    const float* w3s = w3 + w * 64;
    float a3[64];
#pragma unroll
    for (int o = 0; o < 64; ++o) a3[o] = b3[w * 64 + o];
    float4 cur = *(const float4*)&hb[lane][0];
#pragma unroll 1
    for (int g = 0; g < 32; ++g) {
      float4 nxt;
      if (g < 31) nxt = *(const float4*)&hb[lane][4 * (g + 1)];
      float vv[4] = {cur.x, cur.y, cur.z, cur.w};
#pragma unroll
      for (int jj = 0; jj < 4; ++jj) {
        float v = vv[jj];
        const float* wr = w3s + (g * 4 + jj) * 256;
#pragma unroll
        for (int o = 0; o < 64; ++o) a3[o] = fmaf(v, wr[o], a3[o]);
      }
      cur = nxt;
    }
    float res = 0.f;
#pragma unroll
    for (int oo = 0; oo < 64; ++oo) {
      float a = fmaxf(a3[oo], 0.f);
      if (!valid) a = -DEVINF;
#pragma unroll
      for (int off = 1; off < 64; off <<= 1) a = fmaxf(a, __shfl_xor(a, off, 64));
      if (lane == oo) res = a;
    }
    out[(size_t)bs * 256 + w * 64 + lane] = res;
  }
}

// ---------------------------------------------------------------------------
// Global SA: MLP 259->256->512->1024 per point, max over 8 points per block.
// ---------------------------------------------------------------------------
__global__ __launch_bounds__(256, 2) void gsa_kernel(
    const float* __restrict__ x2,  // [16][256][256]
    const float* __restrict__ p2,  // [16][256][3]
    const float* __restrict__ w1, const float* __restrict__ b1,
    const float* __restrict__ w2, const float* __restrict__ b2,
    const float* __restrict__ w3, const float* __restrict__ b3,
    float* __restrict__ part)      // [16][32][1024]
{
  const int P = 8;
  const int blk = blockIdx.x;      // 512 blocks
  const int b = blk >> 5, gg = blk & 31;
  const int tid = threadIdx.x;
  __shared__ __align__(16) float in_t[259][P];
  __shared__ __align__(16) float h1_t[256][P];
  __shared__ __align__(16) float h2_t[512][P];
  const int base_pt = gg * P;
#pragma unroll
  for (int p = 0; p < P; ++p)
    in_t[tid][p] = x2[((size_t)(b * 256 + base_pt + p)) * 256 + tid];
  if (tid < 3 * P) {
    int p = tid & (P - 1), c = tid >> 3;
    in_t[256 + c][p] = p2[(b * 256 + base_pt + p) * 3 + c];
  }
  __syncthreads();
  { // layer1
    float acc[P];
#pragma unroll
    for (int p = 0; p < P; ++p) acc[p] = b1[tid];
#pragma unroll 1
    for (int k = 0; k < 259; ++k) {
      float w = w1[k * 256 + tid];
      const float4* vp = (const float4*)in_t[k];
      float4 v0 = vp[0], v1 = vp[1];
      acc[0] = fmaf(v0.x, w, acc[0]); acc[1] = fmaf(v0.y, w, acc[1]);
      acc[2] = fmaf(v0.z, w, acc[2]); acc[3] = fmaf(v0.w, w, acc[3]);
      acc[4] = fmaf(v1.x, w, acc[4]); acc[5] = fmaf(v1.y, w, acc[5]);
      acc[6] = fmaf(v1.z, w, acc[6]); acc[7] = fmaf(v1.w, w, acc[7]);
    }
#pragma unroll
    for (int p = 0; p < P; ++p) h1_t[tid][p] = fmaxf(acc[p], 0.f);
  }
  __syncthreads();
  { // layer2
    float a0[P], a1[P];
#pragma unroll
    for (int p = 0; p < P; ++p) { a0[p] = b2[tid]; a1[p] = b2[tid + 256]; }
#pragma unroll 1
    for (int k = 0; k < 256; ++k) {
      float wa = w2[k * 512 + tid], wb = w2[k * 512 + tid + 256];
      const float4* vp = (const float4*)h1_t[k];
      float4 v0 = vp[0], v1 = vp[1];
      float v[8] = {v0.x, v0.y, v0.z, v0.w, v1.x, v1.y, v1.z, v1.w};
#pragma unroll
      for (int p = 0; p < P; ++p) { a0[p] = fmaf(v[p], wa, a0[p]); a1[p] = fmaf(v[p], wb, a1[p]); }
    }
#pragma unroll
    for (int p = 0; p < P; ++p) {
      h2_t[tid][p] = fmaxf(a0[p], 0.f);
      h2_t[tid + 256][p] = fmaxf(a1[p], 0.f);
    }
  }
  __syncthreads();
  { // layer3 + max over P points
    float a[4][P];
#pragma unroll
    for (int q = 0; q < 4; ++q)
#pragma unroll
      for (int p = 0; p < P; ++p) a[q][p] = b3[q * 256 + tid];
#pragma unroll 1
    for (int k = 0; k < 512; ++k) {
      float w0 = w3[(size_t)k * 1024 + tid];
      float wq1 = w3[(size_t)k * 1024 + tid + 256];
      float wq2 = w3[(size_t)k * 1024 + tid + 512];
      float wq3 = w3[(size_t)k * 1024 + tid + 768];
      const float4* vp = (const float4*)h2_t[k];
      float4 v0 = vp[0], v1 = vp[1];
      float v[8] = {v0.x, v0.y, v0.z, v0.w, v1.x, v1.y, v1.z, v1.w};
#pragma unroll
      for (int p = 0; p < P; ++p) {
        a[0][p] = fmaf(v[p], w0, a[0][p]);
        a[1][p] = fmaf(v[p], wq1, a[1][p]);
        a[2][p] = fmaf(v[p], wq2, a[2][p]);
        a[3][p] = fmaf(v[p], wq3, a[3][p]);
      }
    }
#pragma unroll
    for (int q = 0; q < 4; ++q) {
      float m = -DEVINF;
#pragma unroll
      for (int p = 0; p < P; ++p) m = fmaxf(m, fmaxf(a[q][p], 0.f));
      part[((size_t)(b * 32 + gg)) * 1024 + q * 256 + tid] = m;
    }
  }
}

__global__ __launch_bounds__(256) void gmax_kernel(const float* __restrict__ part,
                                                   float* __restrict__ g) {
  int i = blockIdx.x * 256 + threadIdx.x;  // 16384
  int b = i >> 10, c = i & 1023;
  float m = -DEVINF;
#pragma unroll
  for (int t = 0; t < 32; ++t) m = fmaxf(m, part[((size_t)(b * 32 + t) << 10) + c]);
  g[i] = m;
}

// ---------------------------------------------------------------------------
// Dense layer: out[M][N] = (relu?)(in @ w + b). block=64 (one m, 64 n's).
// ---------------------------------------------------------------------------
__global__ __launch_bounds__(64, 4) void dense_kernel(
    const float* __restrict__ in, const float* __restrict__ w,
    const float* __restrict__ bias, float* __restrict__ out,
    int M, int K, int N, int relu) {
  int nb = N >> 6;
  int m = blockIdx.x / nb, cb = blockIdx.x % nb;
  int n = cb * 64 + threadIdx.x;
  const float* ir = in + (size_t)m * K;
  float acc = bias[n];
  for (int k = 0; k < K; ++k) acc = fmaf(ir[k], w[(size_t)k * N + n], acc);
  if (relu) acc = fmaxf(acc, 0.f);
  out[(size_t)m * N + n] = acc;
}

// ---------------------------------------------------------------------------
extern "C" void kernel_launch(void* const* d_in, const int* in_sizes, int n_in,
                              void* d_out, int out_size, void* d_ws, size_t ws_size,
                              hipStream_t stream) {
  (void)in_sizes; (void)n_in; (void)out_size; (void)ws_size;
  const float* x    = (const float*)d_in[0];
  const float* pos  = (const float*)d_in[1];
  const float* s1w1 = (const float*)d_in[2];  const float* s1b1 = (const float*)d_in[3];
  const float* s1w2 = (const float*)d_in[4];  const float* s1b2 = (const float*)d_in[5];
  const float* s1w3 = (const float*)d_in[6];  const float* s1b3 = (const float*)d_in[7];
  const float* s2w1 = (const float*)d_in[8];  const float* s2b1 = (const float*)d_in[9];
  const float* s2w2 = (const float*)d_in[10]; const float* s2b2 = (const float*)d_in[11];
  const float* s2w3 = (const float*)d_in[12]; const float* s2b3 = (const float*)d_in[13];
  const float* s3w1 = (const float*)d_in[14]; const float* s3b1 = (const float*)d_in[15];
  const float* s3w2 = (const float*)d_in[16]; const float* s3b2 = (const float*)d_in[17];
  const float* s3w3 = (const float*)d_in[18]; const float* s3b3 = (const float*)d_in[19];
  const float* fw1  = (const float*)d_in[20]; const float* fb1  = (const float*)d_in[21];
  const float* fw2  = (const float*)d_in[22]; const float* fb2  = (const float*)d_in[23];
  const float* fw3  = (const float*)d_in[24]; const float* fb3  = (const float*)d_in[25];
  const float* l1w  = (const float*)d_in[26]; const float* l1b  = (const float*)d_in[27];
  const float* l2w  = (const float*)d_in[28]; const float* l2b  = (const float*)d_in[29];
  const float* l3w  = (const float*)d_in[30]; const float* l3b  = (const float*)d_in[31];
  const float* l4w  = (const float*)d_in[32]; const float* l4b  = (const float*)d_in[33];
  const float* l5w  = (const float*)d_in[34]; const float* l5b  = (const float*)d_in[35];
  float* out = (float*)d_out;

  float* ws = (float*)d_ws;
  float* p1   = ws;                  // 16*1024*3    = 49152
  float* x1   = p1 + 49152;          // 16*1024*128  = 2097152
  float* p2   = x1 + 2097152;        // 16*256*3     = 12288
  float* x2   = p2 + 12288;          // 16*256*256   = 1048576
  float* part = x2 + 1048576;        // 16*32*1024   = 524288
  float* g    = part + 524288;       // 16*1024      = 16384
  float* hA   = g + 16384;           // 16*512
  float* hB   = hA + 8192;           // 16*256
  float* hC   = hB + 4096;           // 16*256
  float* hD   = hC + 4096;           // 4*512
  float* hE   = hD + 2048;           // 4*512
  float* hF   = hE + 2048;           // 4*256
  float* hG   = hF + 1024;           // 4*128

  fps_kernel<2048, 8><<<16, 256, 0, stream>>>(pos, 1024, p1);
  fps_kernel<1024, 4><<<16, 256, 0, stream>>>(p1, 256, p2);
  sa1_kernel<<<16 * 1024, 256, 0, stream>>>(x, pos, p1, s1w1, s1b1, s1w2, s1b2,
                                            s1w3, s1b3, x1);
  sa2_kernel<<<16 * 256, 256, 0, stream>>>(x1, p1, p2, s2w1, s2b1, s2w2, s2b2,
                                           s2w3, s2b3, x2);
  gsa_kernel<<<512, 256, 0, stream>>>(x2, p2, s3w1, s3b1, s3w2, s3b2, s3w3, s3b3, part);
  gmax_kernel<<<64, 256, 0, stream>>>(part, g);
  dense_kernel<<<16 * 8, 64, 0, stream>>>(g,  l1w, l1b, hA, 16, 1024, 512, 1);
  dense_kernel<<<16 * 4, 64, 0, stream>>>(hA, l2w, l2b, hB, 16, 512, 256, 1);
  dense_kernel<<<16 * 4, 64, 0, stream>>>(hB, l3w, l3b, hC, 16, 256, 256, 0);
  // hC [16][256] viewed as [4][1024]
  dense_kernel<<<4 * 8, 64, 0, stream>>>(hC, fw1, fb1, hD, 4, 1024, 512, 1);
  dense_kernel<<<4 * 8, 64, 0, stream>>>(hD, fw2, fb2, hE, 4, 512, 512, 1);
  dense_kernel<<<4 * 4, 64, 0, stream>>>(hE, fw3, fb3, hF, 4, 512, 256, 1);
  dense_kernel<<<4 * 2, 64, 0, stream>>>(hF, l4w, l4b, hG, 4, 256, 128, 1);
  dense_kernel<<<4 * 2, 64, 0, stream>>>(hG, l5w, l5b, out, 4, 128, 128, 0);
}

// Round 3
// 3429.094 us; speedup vs baseline: 1.8338x; 1.8338x over previous
//
#include <hip/hip_runtime.h>
#include <cstddef>

#define DEVINF __builtin_inff()

typedef __attribute__((ext_vector_type(8))) short bf16x8;
typedef __attribute__((ext_vector_type(4))) float f32x4;

__device__ __forceinline__ unsigned short f2bf(float x) {
  unsigned u = __float_as_uint(x);
  return (unsigned short)((u + 0x7fff + ((u >> 16) & 1)) >> 16);
}
__device__ __forceinline__ float bf2f(unsigned short h) {
  return __uint_as_float(((unsigned)h) << 16);
}
__device__ __forceinline__ void split_bf(float x, unsigned short& hi, unsigned short& lo) {
  hi = f2bf(x);
  lo = f2bf(x - bf2f(hi));
}

// ---------------------------------------------------------------------------
// FPS: farthest point sampling, exact numpy semantics. (unchanged — correct)
// ---------------------------------------------------------------------------
template <int N, int PPL>
__global__ __launch_bounds__(256) void fps_kernel(const float* __restrict__ pos,
                                                  int S, float* __restrict__ ctr) {
#pragma clang fp contract(off)
  const int b = blockIdx.x;
  const int tid = threadIdx.x;
  __shared__ float px[N], py[N], pz[N];
  __shared__ float rv[2][4];
  __shared__ int ri[2][4];
  for (int i = tid; i < N; i += 256) {
    px[i] = pos[((size_t)b * N + i) * 3 + 0];
    py[i] = pos[((size_t)b * N + i) * 3 + 1];
    pz[i] = pos[((size_t)b * N + i) * 3 + 2];
  }
  __syncthreads();
  float qx[PPL], qy[PPL], qz[PPL], d[PPL];
#pragma unroll
  for (int q = 0; q < PPL; ++q) {
    int i = q * 256 + tid;
    qx[q] = px[i]; qy[q] = py[i]; qz[q] = pz[i];
    d[q] = DEVINF;
  }
  int last = 0;
  for (int s = 0; s < S; ++s) {
    if (tid == 0) {
      ctr[((size_t)b * S + s) * 3 + 0] = px[last];
      ctr[((size_t)b * S + s) * 3 + 1] = py[last];
      ctr[((size_t)b * S + s) * 3 + 2] = pz[last];
    }
    float lx = px[last], ly = py[last], lz = pz[last];
    float bv = -DEVINF;
    int bi = 0x7fffffff;
#pragma unroll
    for (int q = 0; q < PPL; ++q) {
      float dx = qx[q] - lx, dy = qy[q] - ly, dz = qz[q] - lz;
      float t0 = dx * dx, t1 = dy * dy, t2 = dz * dz;
      float d2 = (t0 + t1) + t2;
      float dn = fminf(d[q], d2);
      d[q] = dn;
      int i = q * 256 + tid;
      if (dn > bv) { bv = dn; bi = i; }
    }
#pragma unroll
    for (int off = 1; off < 64; off <<= 1) {
      float ov = __shfl_xor(bv, off, 64);
      int oi = __shfl_xor(bi, off, 64);
      if (ov > bv || (ov == bv && oi < bi)) { bv = ov; bi = oi; }
    }
    int pb = s & 1;
    if ((tid & 63) == 0) { rv[pb][tid >> 6] = bv; ri[pb][tid >> 6] = bi; }
    __syncthreads();
    float fv = rv[pb][0];
    int fi = ri[pb][0];
#pragma unroll
    for (int w = 1; w < 4; ++w) {
      float ov = rv[pb][w];
      int oi = ri[pb][w];
      if (ov > fv || (ov == fv && oi < fi)) { fv = ov; fi = oi; }
    }
    last = fi;
  }
}

// ---------------------------------------------------------------------------
// prep_w: transpose weight [K][N] -> padded bf16 hi/lo planes [N][rl],
// rl = roundup(K,32)+8. Zeros in pad region.
// ---------------------------------------------------------------------------
__global__ __launch_bounds__(256) void prep_w(const float* __restrict__ w, int K,
                                              int N, int rl,
                                              unsigned short* __restrict__ hi,
                                              unsigned short* __restrict__ lo) {
  int idx = blockIdx.x * 256 + threadIdx.x;
  if (idx >= N * rl) return;
  int n = idx / rl, k = idx - n * rl;
  float v = (k < K) ? w[(size_t)k * N + n] : 0.f;
  unsigned short h, l;
  split_bf(v, h, l);
  hi[idx] = h;
  lo[idx] = l;
}

// ---------------------------------------------------------------------------
// MFMA helpers. Wave w handles m-tile w (edges w*16..w*16+15).
// A-frag: lane l -> A[m=l&15][k = ks*32 + (l>>4)*8 + j], contiguous 8 bf16.
// B-frag: lane l -> B[k = ks*32 + (l>>4)*8 + j][n = l&15], read from wT[n][k].
// C/D: col = l&15, row = (l>>4)*4 + reg.
// ---------------------------------------------------------------------------
__device__ __forceinline__ void mfma_layer(const unsigned short* inHi,
                                           const unsigned short* inLo, int sIn,
                                           const unsigned short* wHi,
                                           const unsigned short* wLo, int rl,
                                           const float* bias, int Ksteps, int n0,
                                           int T, int lane, int w, f32x4* acc) {
  const int col = lane & 15, quad = lane >> 4;
  const int edge = w * 16 + col;
#pragma unroll
  for (int t = 0; t < T; ++t) {
    float bv = bias[n0 + t * 16 + col];
    acc[t].x = bv; acc[t].y = bv; acc[t].z = bv; acc[t].w = bv;
  }
  const unsigned short* aH = inHi + edge * sIn + quad * 8;
  const unsigned short* aL = inLo + edge * sIn + quad * 8;
#pragma unroll 1
  for (int ks = 0; ks < Ksteps; ++ks) {
    bf16x8 ah = *(const bf16x8*)(aH + ks * 32);
    bf16x8 al = *(const bf16x8*)(aL + ks * 32);
#pragma unroll
    for (int t = 0; t < T; ++t) {
      size_t boff = (size_t)(n0 + t * 16 + col) * rl + ks * 32 + quad * 8;
      bf16x8 bh = *(const bf16x8*)(wHi + boff);
      bf16x8 bl = *(const bf16x8*)(wLo + boff);
      acc[t] = __builtin_amdgcn_mfma_f32_16x16x32_bf16(ah, bh, acc[t], 0, 0, 0);
      acc[t] = __builtin_amdgcn_mfma_f32_16x16x32_bf16(ah, bl, acc[t], 0, 0, 0);
      acc[t] = __builtin_amdgcn_mfma_f32_16x16x32_bf16(al, bh, acc[t], 0, 0, 0);
    }
  }
}

__device__ __forceinline__ void store_h(const f32x4* acc, int T, int n0,
                                        unsigned short* outHi,
                                        unsigned short* outLo, int sOut, int lane,
                                        int w) {
  const int col = lane & 15, quad = lane >> 4;
#pragma unroll
  for (int t = 0; t < T; ++t) {
#pragma unroll
    for (int r = 0; r < 4; ++r) {
      int edge = w * 16 + quad * 4 + r;
      float v = fmaxf(acc[t][r], 0.f);
      unsigned short h, l;
      split_bf(v, h, l);
      outHi[edge * sOut + n0 + t * 16 + col] = h;
      outLo[edge * sOut + n0 + t * 16 + col] = l;
    }
  }
}

__device__ __forceinline__ void pool_store(const f32x4* acc, int T, int n0,
                                           float* pool, int Npool, int lane,
                                           int w, int nvalid) {
  const int col = lane & 15, quad = lane >> 4;
#pragma unroll
  for (int t = 0; t < T; ++t) {
    float m = -DEVINF;
#pragma unroll
    for (int r = 0; r < 4; ++r) {
      int edge = w * 16 + quad * 4 + r;
      float v = fmaxf(acc[t][r], 0.f);
      if (edge >= nvalid) v = -DEVINF;
      m = fmaxf(m, v);
    }
    m = fmaxf(m, __shfl_xor(m, 16, 64));
    m = fmaxf(m, __shfl_xor(m, 32, 64));
    if (quad == 0) pool[w * Npool + n0 + t * 16 + col] = m;
  }
}

// ---------------------------------------------------------------------------
// SA1 (MFMA): ball query + MLP 12->64->64->128 + maxpool. 1 center/block.
// ---------------------------------------------------------------------------
__global__ __launch_bounds__(256, 4) void sa1_kernel(
    const float* __restrict__ x,    // [16][2048][9]
    const float* __restrict__ pos,  // [16][2048][3]
    const float* __restrict__ ctr,  // [16][1024][3]
    const unsigned short* __restrict__ w1h, const unsigned short* __restrict__ w1l,
    const unsigned short* __restrict__ w2h, const unsigned short* __restrict__ w2l,
    const unsigned short* __restrict__ w3h, const unsigned short* __restrict__ w3l,
    const float* __restrict__ b1, const float* __restrict__ b2,
    const float* __restrict__ b3,
    float* __restrict__ out)        // [16][1024][128]
{
  const int N = 2048;
  const float r2 = (float)(0.2 * 0.2);
  const int bs = blockIdx.x;
  const int b = bs >> 10;
  const int tid = threadIdx.x;
  const int w = tid >> 6, lane = tid & 63;
  const float cx = ctr[bs * 3 + 0], cy = ctr[bs * 3 + 1], cz = ctr[bs * 3 + 2];
  __shared__ __align__(16) unsigned short bufA_hi[64 * 72], bufA_lo[64 * 72];
  __shared__ __align__(16) unsigned short bufB_hi[64 * 72], bufB_lo[64 * 72];
  __shared__ int nb[64];
  __shared__ int nval_s;
  __shared__ float pool[4 * 128];
  // ---- ball query (wave 0 only; exact f32, no fma contraction) ----
  if (w == 0) {
    nb[lane] = 0;
    int cnt = 0;
    {
#pragma clang fp contract(off)
#pragma unroll 1
      for (int base = 0; base < N; base += 64) {
        int i = base + lane;
        const float* p = pos + ((size_t)b * N + i) * 3;
        float dx = p[0] - cx, dy = p[1] - cy, dz = p[2] - cz;
        float t0 = dx * dx, t1 = dy * dy, t2 = dz * dz;
        float d2 = (t0 + t1) + t2;
        bool inr = d2 <= r2;
        unsigned long long m = __ballot(inr);
        int posn = cnt + (int)__popcll(m & ((1ull << lane) - 1ull));
        if (inr && posn < 64) nb[posn] = i;
        cnt += (int)__popcll(m);
      }
    }
    if (lane == 0) nval_s = cnt < 64 ? cnt : 64;
  }
  __syncthreads();
  const int nvalid = nval_s;
  // ---- stage features into bufA planes (stride 72, k 0..31 used) ----
  if (w == 0) {
    int j = nb[lane];
    const float* xr = x + ((size_t)b * N + j) * 9;
    const float* pr = pos + ((size_t)b * N + j) * 3;
    float f[12];
#pragma unroll
    for (int k = 0; k < 9; ++k) f[k] = xr[k];
    f[9] = pr[0] - cx; f[10] = pr[1] - cy; f[11] = pr[2] - cz;
#pragma unroll
    for (int k = 0; k < 12; ++k) {
      unsigned short h, l;
      split_bf(f[k], h, l);
      bufA_hi[lane * 72 + k] = h;
      bufA_lo[lane * 72 + k] = l;
    }
  } else if (w == 1) {
#pragma unroll
    for (int k = 12; k < 32; ++k) {
      bufA_hi[lane * 72 + k] = 0;
      bufA_lo[lane * 72 + k] = 0;
    }
  }
  __syncthreads();
  f32x4 acc[8];
  // L1: K=32(12), N=64
  mfma_layer(bufA_hi, bufA_lo, 72, w1h, w1l, 40, b1, 1, 0, 4, lane, w, acc);
  store_h(acc, 4, 0, bufB_hi, bufB_lo, 72, lane, w);
  __syncthreads();
  // L2: K=64, N=64 (bufB -> bufA)
  mfma_layer(bufB_hi, bufB_lo, 72, w2h, w2l, 72, b2, 2, 0, 4, lane, w, acc);
  store_h(acc, 4, 0, bufA_hi, bufA_lo, 72, lane, w);
  __syncthreads();
  // L3: K=64, N=128 + pool
  mfma_layer(bufA_hi, bufA_lo, 72, w3h, w3l, 72, b3, 2, 0, 8, lane, w, acc);
  pool_store(acc, 8, 0, pool, 128, lane, w, nvalid);
  __syncthreads();
  if (tid < 128) {
    float m = fmaxf(fmaxf(pool[tid], pool[128 + tid]),
                    fmaxf(pool[256 + tid], pool[384 + tid]));
    out[(size_t)bs * 128 + tid] = m;
  }
}

// ---------------------------------------------------------------------------
// SA2 (MFMA): ball query + MLP 131->128->128->256 + maxpool. 1 center/block.
// bufA stride 168 (L1 input, Kp=160); bufB stride 136 (hidden, reused in-place).
// ---------------------------------------------------------------------------
__global__ __launch_bounds__(256, 2) void sa2_kernel(
    const float* __restrict__ x1,   // [16][1024][128]
    const float* __restrict__ pos1, // [16][1024][3]
    const float* __restrict__ ctr,  // [16][256][3]
    const unsigned short* __restrict__ w1h, const unsigned short* __restrict__ w1l,
    const unsigned short* __restrict__ w2h, const unsigned short* __restrict__ w2l,
    const unsigned short* __restrict__ w3h, const unsigned short* __restrict__ w3l,
    const float* __restrict__ b1, const float* __restrict__ b2,
    const float* __restrict__ b3,
    float* __restrict__ out)        // [16][256][256]
{
  const int N = 1024;
  const float r2 = (float)(0.4 * 0.4);
  const int bs = blockIdx.x;
  const int b = bs >> 8;
  const int tid = threadIdx.x;
  const int w = tid >> 6, lane = tid & 63;
  const float cx = ctr[bs * 3 + 0], cy = ctr[bs * 3 + 1], cz = ctr[bs * 3 + 2];
  __shared__ __align__(16) unsigned short bufA_hi[64 * 168], bufA_lo[64 * 168];
  __shared__ __align__(16) unsigned short bufB_hi[64 * 136], bufB_lo[64 * 136];
  __shared__ int nb[64];
  __shared__ int nval_s;
  float* pool = (float*)bufA_hi;  // bufA dead after L1; pool needs 4 KB
  if (w == 0) {
    nb[lane] = 0;
    int cnt = 0;
    {
#pragma clang fp contract(off)
#pragma unroll 1
      for (int base = 0; base < N; base += 64) {
        int i = base + lane;
        const float* p = pos1 + ((size_t)b * N + i) * 3;
        float dx = p[0] - cx, dy = p[1] - cy, dz = p[2] - cz;
        float t0 = dx * dx, t1 = dy * dy, t2 = dz * dz;
        float d2 = (t0 + t1) + t2;
        bool inr = d2 <= r2;
        unsigned long long m = __ballot(inr);
        int posn = cnt + (int)__popcll(m & ((1ull << lane) - 1ull));
        if (inr && posn < 64) nb[posn] = i;
        cnt += (int)__popcll(m);
      }
    }
    if (lane == 0) nval_s = cnt < 64 ? cnt : 64;
  }
  __syncthreads();
  const int nvalid = nval_s;
  // ---- stage features: quarter w loads k in [32w, 32w+32); w0 also rel+pad ----
  {
    int j = nb[lane];
    const float* xr = x1 + ((size_t)b * N + j) * 128 + 32 * w;
#pragma unroll
    for (int g = 0; g < 8; ++g) {
      float4 v = *(const float4*)(xr + 4 * g);
      float vv[4] = {v.x, v.y, v.z, v.w};
#pragma unroll
      for (int e = 0; e < 4; ++e) {
        unsigned short h, l;
        split_bf(vv[e], h, l);
        int k = 32 * w + 4 * g + e;
        bufA_hi[lane * 168 + k] = h;
        bufA_lo[lane * 168 + k] = l;
      }
    }
    if (w == 0) {
      const float* pr = pos1 + ((size_t)b * N + j) * 3;
      float rr[3] = {pr[0] - cx, pr[1] - cy, pr[2] - cz};
#pragma unroll
      for (int c = 0; c < 3; ++c) {
        unsigned short h, l;
        split_bf(rr[c], h, l);
        bufA_hi[lane * 168 + 128 + c] = h;
        bufA_lo[lane * 168 + 128 + c] = l;
      }
#pragma unroll
      for (int k = 131; k < 160; ++k) {
        bufA_hi[lane * 168 + k] = 0;
        bufA_lo[lane * 168 + k] = 0;
      }
    }
  }
  __syncthreads();
  f32x4 acc[8];
  // L1: K=160(131), N=128
  mfma_layer(bufA_hi, bufA_lo, 168, w1h, w1l, 168, b1, 5, 0, 8, lane, w, acc);
  store_h(acc, 8, 0, bufB_hi, bufB_lo, 136, lane, w);
  __syncthreads();
  // L2: K=128, N=128 (bufB -> regs -> bufB, barrier-separated)
  mfma_layer(bufB_hi, bufB_lo, 136, w2h, w2l, 136, b2, 4, 0, 8, lane, w, acc);
  __syncthreads();
  store_h(acc, 8, 0, bufB_hi, bufB_lo, 136, lane, w);
  __syncthreads();
  // L3: K=128, N=256 in two n-chunks + pool
#pragma unroll 1
  for (int c = 0; c < 2; ++c) {
    mfma_layer(bufB_hi, bufB_lo, 136, w3h, w3l, 136, b3, 4, c * 128, 8, lane, w, acc);
    pool_store(acc, 8, c * 128, pool, 256, lane, w, nvalid);
  }
  __syncthreads();
  {
    float m = fmaxf(fmaxf(pool[tid], pool[256 + tid]),
                    fmaxf(pool[512 + tid], pool[768 + tid]));
    out[(size_t)bs * 256 + tid] = m;
  }
}

// ---------------------------------------------------------------------------
// Global SA: MLP 259->256->512->1024 per point, max over 8 points per block.
// ---------------------------------------------------------------------------
__global__ __launch_bounds__(256, 2) void gsa_kernel(
    const float* __restrict__ x2,  // [16][256][256]
    const float* __restrict__ p2,  // [16][256][3]
    const float* __restrict__ w1, const float* __restrict__ b1,
    const float* __restrict__ w2, const float* __restrict__ b2,
    const float* __restrict__ w3, const float* __restrict__ b3,
    float* __restrict__ part)      // [16][32][1024]
{
  const int P = 8;
  const int blk = blockIdx.x;      // 512 blocks
  const int b = blk >> 5, gg = blk & 31;
  const int tid = threadIdx.x;
  __shared__ __align__(16) float in_t[259][P];
  __shared__ __align__(16) float h1_t[256][P];
  __shared__ __align__(16) float h2_t[512][P];
  const int base_pt = gg * P;
#pragma unroll
  for (int p = 0; p < P; ++p)
    in_t[tid][p] = x2[((size_t)(b * 256 + base_pt + p)) * 256 + tid];
  if (tid < 3 * P) {
    int p = tid & (P - 1), c = tid >> 3;
    in_t[256 + c][p] = p2[(b * 256 + base_pt + p) * 3 + c];
  }
  __syncthreads();
  { // layer1
    float acc[P];
#pragma unroll
    for (int p = 0; p < P; ++p) acc[p] = b1[tid];
#pragma unroll 1
    for (int k = 0; k < 259; ++k) {
      float w = w1[k * 256 + tid];
      const float4* vp = (const float4*)in_t[k];
      float4 v0 = vp[0], v1 = vp[1];
      acc[0] = fmaf(v0.x, w, acc[0]); acc[1] = fmaf(v0.y, w, acc[1]);
      acc[2] = fmaf(v0.z, w, acc[2]); acc[3] = fmaf(v0.w, w, acc[3]);
      acc[4] = fmaf(v1.x, w, acc[4]); acc[5] = fmaf(v1.y, w, acc[5]);
      acc[6] = fmaf(v1.z, w, acc[6]); acc[7] = fmaf(v1.w, w, acc[7]);
    }
#pragma unroll
    for (int p = 0; p < P; ++p) h1_t[tid][p] = fmaxf(acc[p], 0.f);
  }
  __syncthreads();
  { // layer2
    float a0[P], a1[P];
#pragma unroll
    for (int p = 0; p < P; ++p) { a0[p] = b2[tid]; a1[p] = b2[tid + 256]; }
#pragma unroll 1
    for (int k = 0; k < 256; ++k) {
      float wa = w2[k * 512 + tid], wb = w2[k * 512 + tid + 256];
      const float4* vp = (const float4*)h1_t[k];
      float4 v0 = vp[0], v1 = vp[1];
      float v[8] = {v0.x, v0.y, v0.z, v0.w, v1.x, v1.y, v1.z, v1.w};
#pragma unroll
      for (int p = 0; p < P; ++p) { a0[p] = fmaf(v[p], wa, a0[p]); a1[p] = fmaf(v[p], wb, a1[p]); }
    }
#pragma unroll
    for (int p = 0; p < P; ++p) {
      h2_t[tid][p] = fmaxf(a0[p], 0.f);
      h2_t[tid + 256][p] = fmaxf(a1[p], 0.f);
    }
  }
  __syncthreads();
  { // layer3 + max over P points
    float a[4][P];
#pragma unroll
    for (int q = 0; q < 4; ++q)
#pragma unroll
      for (int p = 0; p < P; ++p) a[q][p] = b3[q * 256 + tid];
#pragma unroll 1
    for (int k = 0; k < 512; ++k) {
      float w0 = w3[(size_t)k * 1024 + tid];
      float wq1 = w3[(size_t)k * 1024 + tid + 256];
      float wq2 = w3[(size_t)k * 1024 + tid + 512];
      float wq3 = w3[(size_t)k * 1024 + tid + 768];
      const float4* vp = (const float4*)h2_t[k];
      float4 v0 = vp[0], v1 = vp[1];
      float v[8] = {v0.x, v0.y, v0.z, v0.w, v1.x, v1.y, v1.z, v1.w};
#pragma unroll
      for (int p = 0; p < P; ++p) {
        a[0][p] = fmaf(v[p], w0, a[0][p]);
        a[1][p] = fmaf(v[p], wq1, a[1][p]);
        a[2][p] = fmaf(v[p], wq2, a[2][p]);
        a[3][p] = fmaf(v[p], wq3, a[3][p]);
      }
    }
#pragma unroll
    for (int q = 0; q < 4; ++q) {
      float m = -DEVINF;
#pragma unroll
      for (int p = 0; p < P; ++p) m = fmaxf(m, fmaxf(a[q][p], 0.f));
      part[((size_t)(b * 32 + gg)) * 1024 + q * 256 + tid] = m;
    }
  }
}

__global__ __launch_bounds__(256) void gmax_kernel(const float* __restrict__ part,
                                                   float* __restrict__ g) {
  int i = blockIdx.x * 256 + threadIdx.x;  // 16384
  int b = i >> 10, c = i & 1023;
  float m = -DEVINF;
#pragma unroll
  for (int t = 0; t < 32; ++t) m = fmaxf(m, part[((size_t)(b * 32 + t) << 10) + c]);
  g[i] = m;
}

// ---------------------------------------------------------------------------
// Dense layer: out[M][N] = (relu?)(in @ w + b). block=64 (one m, 64 n's).
// ---------------------------------------------------------------------------
__global__ __launch_bounds__(64, 4) void dense_kernel(
    const float* __restrict__ in, const float* __restrict__ w,
    const float* __restrict__ bias, float* __restrict__ out,
    int M, int K, int N, int relu) {
  int nb = N >> 6;
  int m = blockIdx.x / nb, cb = blockIdx.x % nb;
  int n = cb * 64 + threadIdx.x;
  const float* ir = in + (size_t)m * K;
  float acc = bias[n];
  for (int k = 0; k < K; ++k) acc = fmaf(ir[k], w[(size_t)k * N + n], acc);
  if (relu) acc = fmaxf(acc, 0.f);
  out[(size_t)m * N + n] = acc;
}

// ---------------------------------------------------------------------------
extern "C" void kernel_launch(void* const* d_in, const int* in_sizes, int n_in,
                              void* d_out, int out_size, void* d_ws, size_t ws_size,
                              hipStream_t stream) {
  (void)in_sizes; (void)n_in; (void)out_size; (void)ws_size;
  const float* x    = (const float*)d_in[0];
  const float* pos  = (const float*)d_in[1];
  const float* s1w1 = (const float*)d_in[2];  const float* s1b1 = (const float*)d_in[3];
  const float* s1w2 = (const float*)d_in[4];  const float* s1b2 = (const float*)d_in[5];
  const float* s1w3 = (const float*)d_in[6];  const float* s1b3 = (const float*)d_in[7];
  const float* s2w1 = (const float*)d_in[8];  const float* s2b1 = (const float*)d_in[9];
  const float* s2w2 = (const float*)d_in[10]; const float* s2b2 = (const float*)d_in[11];
  const float* s2w3 = (const float*)d_in[12]; const float* s2b3 = (const float*)d_in[13];
  const float* s3w1 = (const float*)d_in[14]; const float* s3b1 = (const float*)d_in[15];
  const float* s3w2 = (const float*)d_in[16]; const float* s3b2 = (const float*)d_in[17];
  const float* s3w3 = (const float*)d_in[18]; const float* s3b3 = (const float*)d_in[19];
  const float* fw1  = (const float*)d_in[20]; const float* fb1  = (const float*)d_in[21];
  const float* fw2  = (const float*)d_in[22]; const float* fb2  = (const float*)d_in[23];
  const float* fw3  = (const float*)d_in[24]; const float* fb3  = (const float*)d_in[25];
  const float* l1w  = (const float*)d_in[26]; const float* l1b  = (const float*)d_in[27];
  const float* l2w  = (const float*)d_in[28]; const float* l2b  = (const float*)d_in[29];
  const float* l3w  = (const float*)d_in[30]; const float* l3b  = (const float*)d_in[31];
  const float* l4w  = (const float*)d_in[32]; const float* l4b  = (const float*)d_in[33];
  const float* l5w  = (const float*)d_in[34]; const float* l5b  = (const float*)d_in[35];
  float* out = (float*)d_out;

  float* ws = (float*)d_ws;
  float* p1   = ws;                  // 16*1024*3    = 49152
  float* x1   = p1 + 49152;          // 16*1024*128  = 2097152
  float* p2   = x1 + 2097152;        // 16*256*3     = 12288
  float* x2   = p2 + 12288;          // 16*256*256   = 1048576
  float* part = x2 + 1048576;        // 16*32*1024   = 524288
  float* g    = part + 524288;       // 16*1024      = 16384
  float* hA   = g + 16384;           // 16*512
  float* hB   = hA + 8192;           // 16*256
  float* hC   = hB + 4096;           // 16*256
  float* hD   = hC + 4096;           // 4*512
  float* hE   = hD + 2048;           // 4*512
  float* hF   = hE + 2048;           // 4*256
  float* hG   = hF + 1024;           // 4*128
  // bf16 hi/lo transposed weight planes (u16), 16B-aligned base
  unsigned short* wp = (unsigned short*)(hG + 512);
  unsigned short* s1w1h = wp;              unsigned short* s1w1l = s1w1h + 2560;   // [64][40]
  unsigned short* s1w2h = s1w1l + 2560;    unsigned short* s1w2l = s1w2h + 4608;   // [64][72]
  unsigned short* s1w3h = s1w2l + 4608;    unsigned short* s1w3l = s1w3h + 9216;   // [128][72]
  unsigned short* s2w1h = s1w3l + 9216;    unsigned short* s2w1l = s2w1h + 21504;  // [128][168]
  unsigned short* s2w2h = s2w1l + 21504;   unsigned short* s2w2l = s2w2h + 17408;  // [128][136]
  unsigned short* s2w3h = s2w2l + 17408;   unsigned short* s2w3l = s2w3h + 34816;  // [256][136]

  prep_w<<<10, 256, 0, stream>>>(s1w1, 12, 64, 40, s1w1h, s1w1l);
  prep_w<<<18, 256, 0, stream>>>(s1w2, 64, 64, 72, s1w2h, s1w2l);
  prep_w<<<36, 256, 0, stream>>>(s1w3, 64, 128, 72, s1w3h, s1w3l);
  prep_w<<<84, 256, 0, stream>>>(s2w1, 131, 128, 168, s2w1h, s2w1l);
  prep_w<<<68, 256, 0, stream>>>(s2w2, 128, 128, 136, s2w2h, s2w2l);
  prep_w<<<136, 256, 0, stream>>>(s2w3, 128, 256, 136, s2w3h, s2w3l);

  fps_kernel<2048, 8><<<16, 256, 0, stream>>>(pos, 1024, p1);
  fps_kernel<1024, 4><<<16, 256, 0, stream>>>(p1, 256, p2);
  sa1_kernel<<<16 * 1024, 256, 0, stream>>>(x, pos, p1, s1w1h, s1w1l, s1w2h,
                                            s1w2l, s1w3h, s1w3l, s1b1, s1b2,
                                            s1b3, x1);
  sa2_kernel<<<16 * 256, 256, 0, stream>>>(x1, p1, p2, s2w1h, s2w1l, s2w2h,
                                           s2w2l, s2w3h, s2w3l, s2b1, s2b2,
                                           s2b3, x2);
  gsa_kernel<<<512, 256, 0, stream>>>(x2, p2, s3w1, s3b1, s3w2, s3b2, s3w3, s3b3, part);
  gmax_kernel<<<64, 256, 0, stream>>>(part, g);
  dense_kernel<<<16 * 8, 64, 0, stream>>>(g,  l1w, l1b, hA, 16, 1024, 512, 1);
  dense_kernel<<<16 * 4, 64, 0, stream>>>(hA, l2w, l2b, hB, 16, 512, 256, 1);
  dense_kernel<<<16 * 4, 64, 0, stream>>>(hB, l3w, l3b, hC, 16, 256, 256, 0);
  // hC [16][256] viewed as [4][1024]
  dense_kernel<<<4 * 8, 64, 0, stream>>>(hC, fw1, fb1, hD, 4, 1024, 512, 1);
  dense_kernel<<<4 * 8, 64, 0, stream>>>(hD, fw2, fb2, hE, 4, 512, 512, 1);
  dense_kernel<<<4 * 4, 64, 0, stream>>>(hE, fw3, fb3, hF, 4, 512, 256, 1);
  dense_kernel<<<4 * 2, 64, 0, stream>>>(hF, l4w, l4b, hG, 4, 256, 128, 1);
  dense_kernel<<<4 * 2, 64, 0, stream>>>(hG, l5w, l5b, out, 4, 128, 128, 0);
}

// Round 4
// 3234.550 us; speedup vs baseline: 1.9441x; 1.0601x over previous
//
#include <hip/hip_runtime.h>
#include <cstddef>

#define DEVINF __builtin_inff()

typedef __attribute__((ext_vector_type(8))) short bf16x8;
typedef __attribute__((ext_vector_type(4))) float f32x4;

__device__ __forceinline__ unsigned short f2bf(float x) {
  unsigned u = __float_as_uint(x);
  return (unsigned short)((u + 0x7fff + ((u >> 16) & 1)) >> 16);
}
__device__ __forceinline__ float bf2f(unsigned short h) {
  return __uint_as_float(((unsigned)h) << 16);
}
__device__ __forceinline__ void split_bf(float x, unsigned short& hi, unsigned short& lo) {
  hi = f2bf(x);
  lo = f2bf(x - bf2f(hi));
}

// ---------------------------------------------------------------------------
// FPS v2: single wave per batch. Per-point state (coords, min-dist) lives in
// VGPRs (PPL = N/64 points per lane, global idx = q*64+lane, ascending in q so
// strict-> keeps the lowest index per lane). Cross-lane argmax: 6-level
// shfl_xor butterfly on packed u64 (val_bits<<32 | ~idx) -> max gives
// (max val, lowest idx) = numpy first-max. No barriers, no LDS reduction.
// LDS holds a coord copy only for the 3 broadcast reads of the winner.
// Distance math contract(off), same expression order as reference.
// ---------------------------------------------------------------------------
template <int N, int PPL>
__global__ __launch_bounds__(64) void fps_kernel(const float* __restrict__ pos,
                                                 int S, float* __restrict__ ctr) {
#pragma clang fp contract(off)
  const int b = blockIdx.x;
  const int lane = threadIdx.x;
  __shared__ float px[N], py[N], pz[N];
  float qx[PPL], qy[PPL], qz[PPL], d[PPL];
#pragma unroll
  for (int q = 0; q < PPL; ++q) {
    int i = q * 64 + lane;
    float x0 = pos[((size_t)b * N + i) * 3 + 0];
    float y0 = pos[((size_t)b * N + i) * 3 + 1];
    float z0 = pos[((size_t)b * N + i) * 3 + 2];
    qx[q] = x0; qy[q] = y0; qz[q] = z0; d[q] = DEVINF;
    px[i] = x0; py[i] = y0; pz[i] = z0;
  }
  __syncthreads();
  int last = 0;
  for (int s = 0; s < S; ++s) {
    float lx = px[last], ly = py[last], lz = pz[last];
    if (lane == 0) {
      ctr[((size_t)b * S + s) * 3 + 0] = lx;
      ctr[((size_t)b * S + s) * 3 + 1] = ly;
      ctr[((size_t)b * S + s) * 3 + 2] = lz;
    }
    float bv = -DEVINF;
    int bi = 0;
#pragma unroll
    for (int q = 0; q < PPL; ++q) {
      float dx = qx[q] - lx, dy = qy[q] - ly, dz = qz[q] - lz;
      float t0 = dx * dx, t1 = dy * dy, t2 = dz * dz;
      float d2 = (t0 + t1) + t2;
      float dn = fminf(d[q], d2);
      d[q] = dn;
      if (dn > bv) { bv = dn; bi = q * 64 + lane; }
    }
    unsigned long long pk =
        ((unsigned long long)__float_as_uint(bv) << 32) | (unsigned)(~bi);
#pragma unroll
    for (int off = 1; off < 64; off <<= 1) {
      unsigned long long o = __shfl_xor(pk, off, 64);
      pk = (pk > o) ? pk : o;
    }
    last = (int)(~(unsigned)pk);
    last = __builtin_amdgcn_readfirstlane(last);
  }
}

// ---------------------------------------------------------------------------
// prep_w: transpose weight [K][N] -> padded bf16 hi/lo planes [N][rl],
// rl = roundup(K,32)+8. Zeros in pad region.
// ---------------------------------------------------------------------------
__global__ __launch_bounds__(256) void prep_w(const float* __restrict__ w, int K,
                                              int N, int rl,
                                              unsigned short* __restrict__ hi,
                                              unsigned short* __restrict__ lo) {
  int idx = blockIdx.x * 256 + threadIdx.x;
  if (idx >= N * rl) return;
  int n = idx / rl, k = idx - n * rl;
  float v = (k < K) ? w[(size_t)k * N + n] : 0.f;
  unsigned short h, l;
  split_bf(v, h, l);
  hi[idx] = h;
  lo[idx] = l;
}

// ---------------------------------------------------------------------------
// MFMA helpers. Wave w handles m-tile w (edges w*16..w*16+15).
// A-frag: lane l -> A[m=l&15][k = ks*32 + (l>>4)*8 + j], contiguous 8 bf16.
// B-frag: lane l -> B[k = ks*32 + (l>>4)*8 + j][n = l&15], read from wT[n][k].
// C/D: col = l&15, row = (l>>4)*4 + reg.
// ---------------------------------------------------------------------------
__device__ __forceinline__ void mfma_layer(const unsigned short* inHi,
                                           const unsigned short* inLo, int sIn,
                                           const unsigned short* wHi,
                                           const unsigned short* wLo, int rl,
                                           const float* bias, int Ksteps, int n0,
                                           int T, int lane, int w, f32x4* acc) {
  const int col = lane & 15, quad = lane >> 4;
  const int edge = w * 16 + col;
#pragma unroll
  for (int t = 0; t < T; ++t) {
    float bv = bias[n0 + t * 16 + col];
    acc[t].x = bv; acc[t].y = bv; acc[t].z = bv; acc[t].w = bv;
  }
  const unsigned short* aH = inHi + edge * sIn + quad * 8;
  const unsigned short* aL = inLo + edge * sIn + quad * 8;
#pragma unroll 1
  for (int ks = 0; ks < Ksteps; ++ks) {
    bf16x8 ah = *(const bf16x8*)(aH + ks * 32);
    bf16x8 al = *(const bf16x8*)(aL + ks * 32);
#pragma unroll
    for (int t = 0; t < T; ++t) {
      size_t boff = (size_t)(n0 + t * 16 + col) * rl + ks * 32 + quad * 8;
      bf16x8 bh = *(const bf16x8*)(wHi + boff);
      bf16x8 bl = *(const bf16x8*)(wLo + boff);
      acc[t] = __builtin_amdgcn_mfma_f32_16x16x32_bf16(ah, bh, acc[t], 0, 0, 0);
      acc[t] = __builtin_amdgcn_mfma_f32_16x16x32_bf16(ah, bl, acc[t], 0, 0, 0);
      acc[t] = __builtin_amdgcn_mfma_f32_16x16x32_bf16(al, bh, acc[t], 0, 0, 0);
    }
  }
}

__device__ __forceinline__ void store_h(const f32x4* acc, int T, int n0,
                                        unsigned short* outHi,
                                        unsigned short* outLo, int sOut, int lane,
                                        int w) {
  const int col = lane & 15, quad = lane >> 4;
#pragma unroll
  for (int t = 0; t < T; ++t) {
#pragma unroll
    for (int r = 0; r < 4; ++r) {
      int edge = w * 16 + quad * 4 + r;
      float v = fmaxf(acc[t][r], 0.f);
      unsigned short h, l;
      split_bf(v, h, l);
      outHi[edge * sOut + n0 + t * 16 + col] = h;
      outLo[edge * sOut + n0 + t * 16 + col] = l;
    }
  }
}

__device__ __forceinline__ void pool_store(const f32x4* acc, int T, int n0,
                                           float* pool, int Npool, int lane,
                                           int w, int nvalid) {
  const int col = lane & 15, quad = lane >> 4;
#pragma unroll
  for (int t = 0; t < T; ++t) {
    float m = -DEVINF;
#pragma unroll
    for (int r = 0; r < 4; ++r) {
      int edge = w * 16 + quad * 4 + r;
      float v = fmaxf(acc[t][r], 0.f);
      if (edge >= nvalid) v = -DEVINF;
      m = fmaxf(m, v);
    }
    m = fmaxf(m, __shfl_xor(m, 16, 64));
    m = fmaxf(m, __shfl_xor(m, 32, 64));
    if (quad == 0) pool[w * Npool + n0 + t * 16 + col] = m;
  }
}

// ---------------------------------------------------------------------------
// SA1 (MFMA): ball query + MLP 12->64->64->128 + maxpool. 1 center/block.
// ---------------------------------------------------------------------------
__global__ __launch_bounds__(256, 4) void sa1_kernel(
    const float* __restrict__ x,    // [16][2048][9]
    const float* __restrict__ pos,  // [16][2048][3]
    const float* __restrict__ ctr,  // [16][1024][3]
    const unsigned short* __restrict__ w1h, const unsigned short* __restrict__ w1l,
    const unsigned short* __restrict__ w2h, const unsigned short* __restrict__ w2l,
    const unsigned short* __restrict__ w3h, const unsigned short* __restrict__ w3l,
    const float* __restrict__ b1, const float* __restrict__ b2,
    const float* __restrict__ b3,
    float* __restrict__ out)        // [16][1024][128]
{
  const int N = 2048;
  const float r2 = (float)(0.2 * 0.2);
  const int bs = blockIdx.x;
  const int b = bs >> 10;
  const int tid = threadIdx.x;
  const int w = tid >> 6, lane = tid & 63;
  const float cx = ctr[bs * 3 + 0], cy = ctr[bs * 3 + 1], cz = ctr[bs * 3 + 2];
  __shared__ __align__(16) unsigned short bufA_hi[64 * 72], bufA_lo[64 * 72];
  __shared__ __align__(16) unsigned short bufB_hi[64 * 72], bufB_lo[64 * 72];
  __shared__ int nb[64];
  __shared__ int nval_s;
  __shared__ float pool[4 * 128];
  // ---- ball query (wave 0 only; exact f32, no fma contraction) ----
  if (w == 0) {
    nb[lane] = 0;
    int cnt = 0;
    {
#pragma clang fp contract(off)
#pragma unroll 1
      for (int base = 0; base < N; base += 64) {
        int i = base + lane;
        const float* p = pos + ((size_t)b * N + i) * 3;
        float dx = p[0] - cx, dy = p[1] - cy, dz = p[2] - cz;
        float t0 = dx * dx, t1 = dy * dy, t2 = dz * dz;
        float d2 = (t0 + t1) + t2;
        bool inr = d2 <= r2;
        unsigned long long m = __ballot(inr);
        int posn = cnt + (int)__popcll(m & ((1ull << lane) - 1ull));
        if (inr && posn < 64) nb[posn] = i;
        cnt += (int)__popcll(m);
      }
    }
    if (lane == 0) nval_s = cnt < 64 ? cnt : 64;
  }
  __syncthreads();
  const int nvalid = nval_s;
  // ---- stage features into bufA planes (stride 72, k 0..31 used) ----
  if (w == 0) {
    int j = nb[lane];
    const float* xr = x + ((size_t)b * N + j) * 9;
    const float* pr = pos + ((size_t)b * N + j) * 3;
    float f[12];
#pragma unroll
    for (int k = 0; k < 9; ++k) f[k] = xr[k];
    f[9] = pr[0] - cx; f[10] = pr[1] - cy; f[11] = pr[2] - cz;
#pragma unroll
    for (int k = 0; k < 12; ++k) {
      unsigned short h, l;
      split_bf(f[k], h, l);
      bufA_hi[lane * 72 + k] = h;
      bufA_lo[lane * 72 + k] = l;
    }
  } else if (w == 1) {
#pragma unroll
    for (int k = 12; k < 32; ++k) {
      bufA_hi[lane * 72 + k] = 0;
      bufA_lo[lane * 72 + k] = 0;
    }
  }
  __syncthreads();
  f32x4 acc[8];
  // L1: K=32(12), N=64
  mfma_layer(bufA_hi, bufA_lo, 72, w1h, w1l, 40, b1, 1, 0, 4, lane, w, acc);
  store_h(acc, 4, 0, bufB_hi, bufB_lo, 72, lane, w);
  __syncthreads();
  // L2: K=64, N=64 (bufB -> bufA)
  mfma_layer(bufB_hi, bufB_lo, 72, w2h, w2l, 72, b2, 2, 0, 4, lane, w, acc);
  store_h(acc, 4, 0, bufA_hi, bufA_lo, 72, lane, w);
  __syncthreads();
  // L3: K=64, N=128 + pool
  mfma_layer(bufA_hi, bufA_lo, 72, w3h, w3l, 72, b3, 2, 0, 8, lane, w, acc);
  pool_store(acc, 8, 0, pool, 128, lane, w, nvalid);
  __syncthreads();
  if (tid < 128) {
    float m = fmaxf(fmaxf(pool[tid], pool[128 + tid]),
                    fmaxf(pool[256 + tid], pool[384 + tid]));
    out[(size_t)bs * 128 + tid] = m;
  }
}

// ---------------------------------------------------------------------------
// SA2 (MFMA): ball query + MLP 131->128->128->256 + maxpool. 1 center/block.
// bufA stride 168 (L1 input, Kp=160); bufB stride 136 (hidden, reused in-place).
// ---------------------------------------------------------------------------
__global__ __launch_bounds__(256, 2) void sa2_kernel(
    const float* __restrict__ x1,   // [16][1024][128]
    const float* __restrict__ pos1, // [16][1024][3]
    const float* __restrict__ ctr,  // [16][256][3]
    const unsigned short* __restrict__ w1h, const unsigned short* __restrict__ w1l,
    const unsigned short* __restrict__ w2h, const unsigned short* __restrict__ w2l,
    const unsigned short* __restrict__ w3h, const unsigned short* __restrict__ w3l,
    const float* __restrict__ b1, const float* __restrict__ b2,
    const float* __restrict__ b3,
    float* __restrict__ out)        // [16][256][256]
{
  const int N = 1024;
  const float r2 = (float)(0.4 * 0.4);
  const int bs = blockIdx.x;
  const int b = bs >> 8;
  const int tid = threadIdx.x;
  const int w = tid >> 6, lane = tid & 63;
  const float cx = ctr[bs * 3 + 0], cy = ctr[bs * 3 + 1], cz = ctr[bs * 3 + 2];
  __shared__ __align__(16) unsigned short bufA_hi[64 * 168], bufA_lo[64 * 168];
  __shared__ __align__(16) unsigned short bufB_hi[64 * 136], bufB_lo[64 * 136];
  __shared__ int nb[64];
  __shared__ int nval_s;
  float* pool = (float*)bufA_hi;  // bufA dead after L1; pool needs 4 KB
  if (w == 0) {
    nb[lane] = 0;
    int cnt = 0;
    {
#pragma clang fp contract(off)
#pragma unroll 1
      for (int base = 0; base < N; base += 64) {
        int i = base + lane;
        const float* p = pos1 + ((size_t)b * N + i) * 3;
        float dx = p[0] - cx, dy = p[1] - cy, dz = p[2] - cz;
        float t0 = dx * dx, t1 = dy * dy, t2 = dz * dz;
        float d2 = (t0 + t1) + t2;
        bool inr = d2 <= r2;
        unsigned long long m = __ballot(inr);
        int posn = cnt + (int)__popcll(m & ((1ull << lane) - 1ull));
        if (inr && posn < 64) nb[posn] = i;
        cnt += (int)__popcll(m);
      }
    }
    if (lane == 0) nval_s = cnt < 64 ? cnt : 64;
  }
  __syncthreads();
  const int nvalid = nval_s;
  // ---- stage features: quarter w loads k in [32w, 32w+32); w0 also rel+pad ----
  {
    int j = nb[lane];
    const float* xr = x1 + ((size_t)b * N + j) * 128 + 32 * w;
#pragma unroll
    for (int g = 0; g < 8; ++g) {
      float4 v = *(const float4*)(xr + 4 * g);
      float vv[4] = {v.x, v.y, v.z, v.w};
#pragma unroll
      for (int e = 0; e < 4; ++e) {
        unsigned short h, l;
        split_bf(vv[e], h, l);
        int k = 32 * w + 4 * g + e;
        bufA_hi[lane * 168 + k] = h;
        bufA_lo[lane * 168 + k] = l;
      }
    }
    if (w == 0) {
      const float* pr = pos1 + ((size_t)b * N + j) * 3;
      float rr[3] = {pr[0] - cx, pr[1] - cy, pr[2] - cz};
#pragma unroll
      for (int c = 0; c < 3; ++c) {
        unsigned short h, l;
        split_bf(rr[c], h, l);
        bufA_hi[lane * 168 + 128 + c] = h;
        bufA_lo[lane * 168 + 128 + c] = l;
      }
#pragma unroll
      for (int k = 131; k < 160; ++k) {
        bufA_hi[lane * 168 + k] = 0;
        bufA_lo[lane * 168 + k] = 0;
      }
    }
  }
  __syncthreads();
  f32x4 acc[8];
  // L1: K=160(131), N=128
  mfma_layer(bufA_hi, bufA_lo, 168, w1h, w1l, 168, b1, 5, 0, 8, lane, w, acc);
  store_h(acc, 8, 0, bufB_hi, bufB_lo, 136, lane, w);
  __syncthreads();
  // L2: K=128, N=128 (bufB -> regs -> bufB, barrier-separated)
  mfma_layer(bufB_hi, bufB_lo, 136, w2h, w2l, 136, b2, 4, 0, 8, lane, w, acc);
  __syncthreads();
  store_h(acc, 8, 0, bufB_hi, bufB_lo, 136, lane, w);
  __syncthreads();
  // L3: K=128, N=256 in two n-chunks + pool
#pragma unroll 1
  for (int c = 0; c < 2; ++c) {
    mfma_layer(bufB_hi, bufB_lo, 136, w3h, w3l, 136, b3, 4, c * 128, 8, lane, w, acc);
    pool_store(acc, 8, c * 128, pool, 256, lane, w, nvalid);
  }
  __syncthreads();
  {
    float m = fmaxf(fmaxf(pool[tid], pool[256 + tid]),
                    fmaxf(pool[512 + tid], pool[768 + tid]));
    out[(size_t)bs * 256 + tid] = m;
  }
}

// ---------------------------------------------------------------------------
// Global SA: MLP 259->256->512->1024 per point, max over 8 points per block.
// ---------------------------------------------------------------------------
__global__ __launch_bounds__(256, 2) void gsa_kernel(
    const float* __restrict__ x2,  // [16][256][256]
    const float* __restrict__ p2,  // [16][256][3]
    const float* __restrict__ w1, const float* __restrict__ b1,
    const float* __restrict__ w2, const float* __restrict__ b2,
    const float* __restrict__ w3, const float* __restrict__ b3,
    float* __restrict__ part)      // [16][32][1024]
{
  const int P = 8;
  const int blk = blockIdx.x;      // 512 blocks
  const int b = blk >> 5, gg = blk & 31;
  const int tid = threadIdx.x;
  __shared__ __align__(16) float in_t[259][P];
  __shared__ __align__(16) float h1_t[256][P];
  __shared__ __align__(16) float h2_t[512][P];
  const int base_pt = gg * P;
#pragma unroll
  for (int p = 0; p < P; ++p)
    in_t[tid][p] = x2[((size_t)(b * 256 + base_pt + p)) * 256 + tid];
  if (tid < 3 * P) {
    int p = tid & (P - 1), c = tid >> 3;
    in_t[256 + c][p] = p2[(b * 256 + base_pt + p) * 3 + c];
  }
  __syncthreads();
  { // layer1
    float acc[P];
#pragma unroll
    for (int p = 0; p < P; ++p) acc[p] = b1[tid];
#pragma unroll 1
    for (int k = 0; k < 259; ++k) {
      float w = w1[k * 256 + tid];
      const float4* vp = (const float4*)in_t[k];
      float4 v0 = vp[0], v1 = vp[1];
      acc[0] = fmaf(v0.x, w, acc[0]); acc[1] = fmaf(v0.y, w, acc[1]);
      acc[2] = fmaf(v0.z, w, acc[2]); acc[3] = fmaf(v0.w, w, acc[3]);
      acc[4] = fmaf(v1.x, w, acc[4]); acc[5] = fmaf(v1.y, w, acc[5]);
      acc[6] = fmaf(v1.z, w, acc[6]); acc[7] = fmaf(v1.w, w, acc[7]);
    }
#pragma unroll
    for (int p = 0; p < P; ++p) h1_t[tid][p] = fmaxf(acc[p], 0.f);
  }
  __syncthreads();
  { // layer2
    float a0[P], a1[P];
#pragma unroll
    for (int p = 0; p < P; ++p) { a0[p] = b2[tid]; a1[p] = b2[tid + 256]; }
#pragma unroll 1
    for (int k = 0; k < 256; ++k) {
      float wa = w2[k * 512 + tid], wb = w2[k * 512 + tid + 256];
      const float4* vp = (const float4*)h1_t[k];
      float4 v0 = vp[0], v1 = vp[1];
      float v[8] = {v0.x, v0.y, v0.z, v0.w, v1.x, v1.y, v1.z, v1.w};
#pragma unroll
      for (int p = 0; p < P; ++p) { a0[p] = fmaf(v[p], wa, a0[p]); a1[p] = fmaf(v[p], wb, a1[p]); }
    }
#pragma unroll
    for (int p = 0; p < P; ++p) {
      h2_t[tid][p] = fmaxf(a0[p], 0.f);
      h2_t[tid + 256][p] = fmaxf(a1[p], 0.f);
    }
  }
  __syncthreads();
  { // layer3 + max over P points
    float a[4][P];
#pragma unroll
    for (int q = 0; q < 4; ++q)
#pragma unroll
      for (int p = 0; p < P; ++p) a[q][p] = b3[q * 256 + tid];
#pragma unroll 1
    for (int k = 0; k < 512; ++k) {
      float w0 = w3[(size_t)k * 1024 + tid];
      float wq1 = w3[(size_t)k * 1024 + tid + 256];
      float wq2 = w3[(size_t)k * 1024 + tid + 512];
      float wq3 = w3[(size_t)k * 1024 + tid + 768];
      const float4* vp = (const float4*)h2_t[k];
      float4 v0 = vp[0], v1 = vp[1];
      float v[8] = {v0.x, v0.y, v0.z, v0.w, v1.x, v1.y, v1.z, v1.w};
#pragma unroll
      for (int p = 0; p < P; ++p) {
        a[0][p] = fmaf(v[p], w0, a[0][p]);
        a[1][p] = fmaf(v[p], wq1, a[1][p]);
        a[2][p] = fmaf(v[p], wq2, a[2][p]);
        a[3][p] = fmaf(v[p], wq3, a[3][p]);
      }
    }
#pragma unroll
    for (int q = 0; q < 4; ++q) {
      float m = -DEVINF;
#pragma unroll
      for (int p = 0; p < P; ++p) m = fmaxf(m, fmaxf(a[q][p], 0.f));
      part[((size_t)(b * 32 + gg)) * 1024 + q * 256 + tid] = m;
    }
  }
}

__global__ __launch_bounds__(256) void gmax_kernel(const float* __restrict__ part,
                                                   float* __restrict__ g) {
  int i = blockIdx.x * 256 + threadIdx.x;  // 16384
  int b = i >> 10, c = i & 1023;
  float m = -DEVINF;
#pragma unroll
  for (int t = 0; t < 32; ++t) m = fmaxf(m, part[((size_t)(b * 32 + t) << 10) + c]);
  g[i] = m;
}

// ---------------------------------------------------------------------------
// Dense layer: out[M][N] = (relu?)(in @ w + b). block=64 (one m, 64 n's).
// ---------------------------------------------------------------------------
__global__ __launch_bounds__(64, 4) void dense_kernel(
    const float* __restrict__ in, const float* __restrict__ w,
    const float* __restrict__ bias, float* __restrict__ out,
    int M, int K, int N, int relu) {
  int nb = N >> 6;
  int m = blockIdx.x / nb, cb = blockIdx.x % nb;
  int n = cb * 64 + threadIdx.x;
  const float* ir = in + (size_t)m * K;
  float acc = bias[n];
  for (int k = 0; k < K; ++k) acc = fmaf(ir[k], w[(size_t)k * N + n], acc);
  if (relu) acc = fmaxf(acc, 0.f);
  out[(size_t)m * N + n] = acc;
}

// ---------------------------------------------------------------------------
extern "C" void kernel_launch(void* const* d_in, const int* in_sizes, int n_in,
                              void* d_out, int out_size, void* d_ws, size_t ws_size,
                              hipStream_t stream) {
  (void)in_sizes; (void)n_in; (void)out_size; (void)ws_size;
  const float* x    = (const float*)d_in[0];
  const float* pos  = (const float*)d_in[1];
  const float* s1w1 = (const float*)d_in[2];  const float* s1b1 = (const float*)d_in[3];
  const float* s1w2 = (const float*)d_in[4];  const float* s1b2 = (const float*)d_in[5];
  const float* s1w3 = (const float*)d_in[6];  const float* s1b3 = (const float*)d_in[7];
  const float* s2w1 = (const float*)d_in[8];  const float* s2b1 = (const float*)d_in[9];
  const float* s2w2 = (const float*)d_in[10]; const float* s2b2 = (const float*)d_in[11];
  const float* s2w3 = (const float*)d_in[12]; const float* s2b3 = (const float*)d_in[13];
  const float* s3w1 = (const float*)d_in[14]; const float* s3b1 = (const float*)d_in[15];
  const float* s3w2 = (const float*)d_in[16]; const float* s3b2 = (const float*)d_in[17];
  const float* s3w3 = (const float*)d_in[18]; const float* s3b3 = (const float*)d_in[19];
  const float* fw1  = (const float*)d_in[20]; const float* fb1  = (const float*)d_in[21];
  const float* fw2  = (const float*)d_in[22]; const float* fb2  = (const float*)d_in[23];
  const float* fw3  = (const float*)d_in[24]; const float* fb3  = (const float*)d_in[25];
  const float* l1w  = (const float*)d_in[26]; const float* l1b  = (const float*)d_in[27];
  const float* l2w  = (const float*)d_in[28]; const float* l2b  = (const float*)d_in[29];
  const float* l3w  = (const float*)d_in[30]; const float* l3b  = (const float*)d_in[31];
  const float* l4w  = (const float*)d_in[32]; const float* l4b  = (const float*)d_in[33];
  const float* l5w  = (const float*)d_in[34]; const float* l5b  = (const float*)d_in[35];
  float* out = (float*)d_out;

  float* ws = (float*)d_ws;
  float* p1   = ws;                  // 16*1024*3    = 49152
  float* x1   = p1 + 49152;          // 16*1024*128  = 2097152
  float* p2   = x1 + 2097152;        // 16*256*3     = 12288
  float* x2   = p2 + 12288;          // 16*256*256   = 1048576
  float* part = x2 + 1048576;        // 16*32*1024   = 524288
  float* g    = part + 524288;       // 16*1024      = 16384
  float* hA   = g + 16384;           // 16*512
  float* hB   = hA + 8192;           // 16*256
  float* hC   = hB + 4096;           // 16*256
  float* hD   = hC + 4096;           // 4*512
  float* hE   = hD + 2048;           // 4*512
  float* hF   = hE + 2048;           // 4*256
  float* hG   = hF + 1024;           // 4*128
  // bf16 hi/lo transposed weight planes (u16), 16B-aligned base
  unsigned short* wp = (unsigned short*)(hG + 512);
  unsigned short* s1w1h = wp;              unsigned short* s1w1l = s1w1h + 2560;   // [64][40]
  unsigned short* s1w2h = s1w1l + 2560;    unsigned short* s1w2l = s1w2h + 4608;   // [64][72]
  unsigned short* s1w3h = s1w2l + 4608;    unsigned short* s1w3l = s1w3h + 9216;   // [128][72]
  unsigned short* s2w1h = s1w3l + 9216;    unsigned short* s2w1l = s2w1h + 21504;  // [128][168]
  unsigned short* s2w2h = s2w1l + 21504;   unsigned short* s2w2l = s2w2h + 17408;  // [128][136]
  unsigned short* s2w3h = s2w2l + 17408;   unsigned short* s2w3l = s2w3h + 34816;  // [256][136]

  prep_w<<<10, 256, 0, stream>>>(s1w1, 12, 64, 40, s1w1h, s1w1l);
  prep_w<<<18, 256, 0, stream>>>(s1w2, 64, 64, 72, s1w2h, s1w2l);
  prep_w<<<36, 256, 0, stream>>>(s1w3, 64, 128, 72, s1w3h, s1w3l);
  prep_w<<<84, 256, 0, stream>>>(s2w1, 131, 128, 168, s2w1h, s2w1l);
  prep_w<<<68, 256, 0, stream>>>(s2w2, 128, 128, 136, s2w2h, s2w2l);
  prep_w<<<136, 256, 0, stream>>>(s2w3, 128, 256, 136, s2w3h, s2w3l);

  fps_kernel<2048, 32><<<16, 64, 0, stream>>>(pos, 1024, p1);
  fps_kernel<1024, 16><<<16, 64, 0, stream>>>(p1, 256, p2);
  sa1_kernel<<<16 * 1024, 256, 0, stream>>>(x, pos, p1, s1w1h, s1w1l, s1w2h,
                                            s1w2l, s1w3h, s1w3l, s1b1, s1b2,
                                            s1b3, x1);
  sa2_kernel<<<16 * 256, 256, 0, stream>>>(x1, p1, p2, s2w1h, s2w1l, s2w2h,
                                           s2w2l, s2w3h, s2w3l, s2b1, s2b2,
                                           s2b3, x2);
  gsa_kernel<<<512, 256, 0, stream>>>(x2, p2, s3w1, s3b1, s3w2, s3b2, s3w3, s3b3, part);
  gmax_kernel<<<64, 256, 0, stream>>>(part, g);
  dense_kernel<<<16 * 8, 64, 0, stream>>>(g,  l1w, l1b, hA, 16, 1024, 512, 1);
  dense_kernel<<<16 * 4, 64, 0, stream>>>(hA, l2w, l2b, hB, 16, 512, 256, 1);
  dense_kernel<<<16 * 4, 64, 0, stream>>>(hB, l3w, l3b, hC, 16, 256, 256, 0);
  // hC [16][256] viewed as [4][1024]
  dense_kernel<<<4 * 8, 64, 0, stream>>>(hC, fw1, fb1, hD, 4, 1024, 512, 1);
  dense_kernel<<<4 * 8, 64, 0, stream>>>(hD, fw2, fb2, hE, 4, 512, 512, 1);
  dense_kernel<<<4 * 4, 64, 0, stream>>>(hE, fw3, fb3, hF, 4, 512, 256, 1);
  dense_kernel<<<4 * 2, 64, 0, stream>>>(hF, l4w, l4b, hG, 4, 256, 128, 1);
  dense_kernel<<<4 * 2, 64, 0, stream>>>(hG, l5w, l5b, out, 4, 128, 128, 0);
}

// Round 5
// 2724.297 us; speedup vs baseline: 2.3082x; 1.1873x over previous
//
#include <hip/hip_runtime.h>
#include <cstddef>

#define DEVINF __builtin_inff()

typedef __attribute__((ext_vector_type(8))) short bf16x8;
typedef __attribute__((ext_vector_type(4))) float f32x4;
typedef __attribute__((ext_vector_type(2))) float f32x2;

__device__ __forceinline__ unsigned short f2bf(float x) {
  unsigned u = __float_as_uint(x);
  return (unsigned short)((u + 0x7fff + ((u >> 16) & 1)) >> 16);
}
__device__ __forceinline__ float bf2f(unsigned short h) {
  return __uint_as_float(((unsigned)h) << 16);
}
__device__ __forceinline__ void split_bf(float x, unsigned short& hi, unsigned short& lo) {
  hi = f2bf(x);
  lo = f2bf(x - bf2f(hi));
}

// ---------------------------------------------------------------------------
// FPS step: update per-lane min-dists (PPLH float2 halves), find global argmax
// with numpy first-max semantics. 4 independent argmax chains (short dep
// chains), combined + reduced via packed key (val_bits<<32 | ~idx): u64 max
// == (max val, lowest idx). Cross-lane reduce: DPP row_shr/row_bcast ladder
// (VALU speed) -> lane 63 -> readlane. Distance math contract(off), exact
// reference expression order; packed ops are elementwise IEEE so bit-exact.
// ---------------------------------------------------------------------------
#define FPS_RED_LEVEL(CTRL)                                                      \
  {                                                                              \
    int th = __builtin_amdgcn_update_dpp((int)hi, (int)hi, CTRL, 0xf, 0xf, false); \
    int tl = __builtin_amdgcn_update_dpp((int)lo, (int)lo, CTRL, 0xf, 0xf, false); \
    bool take = ((unsigned)th > hi) || (((unsigned)th == hi) && ((unsigned)tl > lo)); \
    hi = take ? (unsigned)th : hi;                                               \
    lo = take ? (unsigned)tl : lo;                                               \
  }

template <int PPLH>
__device__ __forceinline__ int fps_step(f32x2* qx, f32x2* qy, f32x2* qz,
                                        f32x2* d, float lx, float ly, float lz,
                                        int lane) {
#pragma clang fp contract(off)
  const int CH = PPLH / 4;
  float bv[4];
  int bi[4];
#pragma unroll
  for (int c = 0; c < 4; ++c) { bv[c] = -DEVINF; bi[c] = 0x7fffffff; }
  f32x2 lxv = {lx, lx}, lyv = {ly, ly}, lzv = {lz, lz};
#pragma unroll
  for (int h = 0; h < PPLH; ++h) {
    const int c = h / CH;
    f32x2 dx = qx[h] - lxv, dy = qy[h] - lyv, dz = qz[h] - lzv;
    f32x2 t0 = dx * dx, t1 = dy * dy, t2 = dz * dz;
    f32x2 d2 = (t0 + t1) + t2;
    f32x2 dn;
    dn.x = fminf(d[h].x, d2.x);
    dn.y = fminf(d[h].y, d2.y);
    d[h] = dn;
    int i0 = (2 * h) * 64 + lane;
    if (dn.x > bv[c]) { bv[c] = dn.x; bi[c] = i0; }
    if (dn.y > bv[c]) { bv[c] = dn.y; bi[c] = i0 + 64; }
  }
  unsigned hi = __float_as_uint(bv[0]), lo = ~(unsigned)bi[0];
#pragma unroll
  for (int c = 1; c < 4; ++c) {
    unsigned th = __float_as_uint(bv[c]), tl = ~(unsigned)bi[c];
    bool take = (th > hi) || ((th == hi) && (tl > lo));
    hi = take ? th : hi;
    lo = take ? tl : lo;
  }
  FPS_RED_LEVEL(0x111)  // row_shr:1
  FPS_RED_LEVEL(0x112)  // row_shr:2
  FPS_RED_LEVEL(0x114)  // row_shr:4
  FPS_RED_LEVEL(0x118)  // row_shr:8
  FPS_RED_LEVEL(0x142)  // row_bcast:15
  FPS_RED_LEVEL(0x143)  // row_bcast:31
  unsigned flo = (unsigned)__builtin_amdgcn_readlane((int)lo, 63);
  return (int)~flo;
}

// fps1 (2048->1024) and fps2 (1024->256) fused; centers cached in LDS.
__global__ __launch_bounds__(64) void fps_chain(const float* __restrict__ pos,
                                                float* __restrict__ p1,
                                                float* __restrict__ p2) {
#pragma clang fp contract(off)
  const int b = blockIdx.x;
  const int lane = threadIdx.x;
  __shared__ float px[2048], py[2048], pz[2048];
  __shared__ float cxa[1024], cya[1024], cza[1024];
  {
    f32x2 qx[16], qy[16], qz[16], d[16];
#pragma unroll
    for (int h = 0; h < 16; ++h) {
      int i0 = (2 * h) * 64 + lane, i1 = i0 + 64;
      const float* a = pos + ((size_t)b * 2048 + i0) * 3;
      const float* c = pos + ((size_t)b * 2048 + i1) * 3;
      float x0 = a[0], y0 = a[1], z0 = a[2];
      float x1 = c[0], y1 = c[1], z1 = c[2];
      qx[h].x = x0; qx[h].y = x1;
      qy[h].x = y0; qy[h].y = y1;
      qz[h].x = z0; qz[h].y = z1;
      d[h].x = DEVINF; d[h].y = DEVINF;
      px[i0] = x0; py[i0] = y0; pz[i0] = z0;
      px[i1] = x1; py[i1] = y1; pz[i1] = z1;
    }
    __syncthreads();
    int last = 0;
    for (int s = 0; s < 1024; ++s) {
      float lx = px[last], ly = py[last], lz = pz[last];
      if (lane == 0) {
        p1[((size_t)b * 1024 + s) * 3 + 0] = lx;
        p1[((size_t)b * 1024 + s) * 3 + 1] = ly;
        p1[((size_t)b * 1024 + s) * 3 + 2] = lz;
        cxa[s] = lx; cya[s] = ly; cza[s] = lz;
      }
      last = fps_step<16>(qx, qy, qz, d, lx, ly, lz, lane);
    }
  }
  __syncthreads();
  {
    f32x2 qx[8], qy[8], qz[8], d[8];
#pragma unroll
    for (int h = 0; h < 8; ++h) {
      int i0 = (2 * h) * 64 + lane, i1 = i0 + 64;
      qx[h].x = cxa[i0]; qx[h].y = cxa[i1];
      qy[h].x = cya[i0]; qy[h].y = cya[i1];
      qz[h].x = cza[i0]; qz[h].y = cza[i1];
      d[h].x = DEVINF; d[h].y = DEVINF;
    }
    int last = 0;
    for (int s = 0; s < 256; ++s) {
      float lx = cxa[last], ly = cya[last], lz = cza[last];
      if (lane == 0) {
        p2[((size_t)b * 256 + s) * 3 + 0] = lx;
        p2[((size_t)b * 256 + s) * 3 + 1] = ly;
        p2[((size_t)b * 256 + s) * 3 + 2] = lz;
      }
      last = fps_step<8>(qx, qy, qz, d, lx, ly, lz, lane);
    }
  }
}

// ---------------------------------------------------------------------------
// prep_all: all 9 weight transposes ([K][N] -> padded bf16 hi/lo [N][rl]) in
// one launch. Segment table passed by value.
// ---------------------------------------------------------------------------
struct PrepJobs {
  const float* src[9];
  unsigned short* hi[9];
  unsigned short* lo[9];
  int K[9], N[9], rl[9];
  int blk0[10];
};

__global__ __launch_bounds__(256) void prep_all(PrepJobs jb) {
  int blk = blockIdx.x;
  int j = 0;
#pragma unroll
  for (int t = 1; t < 9; ++t)
    if (blk >= jb.blk0[t]) j = t;
  int idx = (blk - jb.blk0[j]) * 256 + threadIdx.x;
  int rl = jb.rl[j], N = jb.N[j], K = jb.K[j];
  if (idx >= N * rl) return;
  int n = idx / rl, k = idx - n * rl;
  float v = (k < K) ? jb.src[j][(size_t)k * N + n] : 0.f;
  unsigned short h, l;
  split_bf(v, h, l);
  jb.hi[j][idx] = h;
  jb.lo[j][idx] = l;
}

// ---------------------------------------------------------------------------
// MFMA building blocks. Wave handles n-range [n0, n0+T*16) for ALL 4 m-tiles
// (64 edges): B fragments loaded once per 12 mfmas (4x fewer global loads
// than the m-tile-per-wave layout).
// A-frag: lane l -> A[m=l&15][k=ks*32+(l>>4)*8+j]; B from wT[n][k];
// C/D: col=l&15, row=(l>>4)*4+reg.
// ---------------------------------------------------------------------------
template <int KS, int T>
__device__ __forceinline__ void mfma_allm(
    const unsigned short* __restrict__ inHi, const unsigned short* __restrict__ inLo,
    int sIn, const unsigned short* __restrict__ wHi,
    const unsigned short* __restrict__ wLo, int rl, const float* __restrict__ bias,
    int n0, int lane, f32x4 acc[4][T]) {
  const int col = lane & 15, quad = lane >> 4;
#pragma unroll
  for (int t = 0; t < T; ++t) {
    float bv = bias[n0 + t * 16 + col];
#pragma unroll
    for (int mt = 0; mt < 4; ++mt) {
      acc[mt][t].x = bv; acc[mt][t].y = bv; acc[mt][t].z = bv; acc[mt][t].w = bv;
    }
  }
#pragma unroll 1
  for (int ks = 0; ks < KS; ++ks) {
    bf16x8 ah[4], al[4];
#pragma unroll
    for (int mt = 0; mt < 4; ++mt) {
      int aoff = (mt * 16 + col) * sIn + ks * 32 + quad * 8;
      ah[mt] = *(const bf16x8*)(inHi + aoff);
      al[mt] = *(const bf16x8*)(inLo + aoff);
    }
#pragma unroll
    for (int t = 0; t < T; ++t) {
      size_t boff = (size_t)(n0 + t * 16 + col) * rl + ks * 32 + quad * 8;
      bf16x8 bh = *(const bf16x8*)(wHi + boff);
      bf16x8 bl = *(const bf16x8*)(wLo + boff);
#pragma unroll
      for (int mt = 0; mt < 4; ++mt) {
        acc[mt][t] = __builtin_amdgcn_mfma_f32_16x16x32_bf16(ah[mt], bh, acc[mt][t], 0, 0, 0);
        acc[mt][t] = __builtin_amdgcn_mfma_f32_16x16x32_bf16(ah[mt], bl, acc[mt][t], 0, 0, 0);
        acc[mt][t] = __builtin_amdgcn_mfma_f32_16x16x32_bf16(al[mt], bh, acc[mt][t], 0, 0, 0);
      }
    }
  }
}

template <int T>
__device__ __forceinline__ void store_allm(const f32x4 acc[4][T], int n0,
                                           unsigned short* outHi,
                                           unsigned short* outLo, int sOut,
                                           int lane) {
  const int col = lane & 15, quad = lane >> 4;
#pragma unroll
  for (int mt = 0; mt < 4; ++mt)
#pragma unroll
    for (int t = 0; t < T; ++t)
#pragma unroll
      for (int r = 0; r < 4; ++r) {
        int edge = mt * 16 + quad * 4 + r;
        float v = fmaxf(acc[mt][t][r], 0.f);
        unsigned short h, l;
        split_bf(v, h, l);
        outHi[edge * sOut + n0 + t * 16 + col] = h;
        outLo[edge * sOut + n0 + t * 16 + col] = l;
      }
}

template <int T>
__device__ __forceinline__ void outpool_allm(const f32x4 acc[4][T], int n0,
                                             float* __restrict__ outp, int nvalid,
                                             int lane) {
  const int col = lane & 15, quad = lane >> 4;
#pragma unroll
  for (int t = 0; t < T; ++t) {
    float m = -DEVINF;
#pragma unroll
    for (int mt = 0; mt < 4; ++mt)
#pragma unroll
      for (int r = 0; r < 4; ++r) {
        int edge = mt * 16 + quad * 4 + r;
        float v = fmaxf(acc[mt][t][r], 0.f);
        if (edge >= nvalid) v = -DEVINF;
        m = fmaxf(m, v);
      }
    m = fmaxf(m, __shfl_xor(m, 16, 64));
    m = fmaxf(m, __shfl_xor(m, 32, 64));
    if (quad == 0) outp[n0 + t * 16 + col] = m;
  }
}

// single-m-tile variants (gsa: 16 points per block)
template <int KS, int T>
__device__ __forceinline__ void mfma_1m(
    const unsigned short* __restrict__ inHi, const unsigned short* __restrict__ inLo,
    int sIn, const unsigned short* __restrict__ wHi,
    const unsigned short* __restrict__ wLo, int rl, const float* __restrict__ bias,
    int n0, int lane, f32x4 acc[T]) {
  const int col = lane & 15, quad = lane >> 4;
#pragma unroll
  for (int t = 0; t < T; ++t) {
    float bv = bias[n0 + t * 16 + col];
    acc[t].x = bv; acc[t].y = bv; acc[t].z = bv; acc[t].w = bv;
  }
#pragma unroll 1
  for (int ks = 0; ks < KS; ++ks) {
    int aoff = col * sIn + ks * 32 + quad * 8;
    bf16x8 ah = *(const bf16x8*)(inHi + aoff);
    bf16x8 al = *(const bf16x8*)(inLo + aoff);
#pragma unroll
    for (int t = 0; t < T; ++t) {
      size_t boff = (size_t)(n0 + t * 16 + col) * rl + ks * 32 + quad * 8;
      bf16x8 bh = *(const bf16x8*)(wHi + boff);
      bf16x8 bl = *(const bf16x8*)(wLo + boff);
      acc[t] = __builtin_amdgcn_mfma_f32_16x16x32_bf16(ah, bh, acc[t], 0, 0, 0);
      acc[t] = __builtin_amdgcn_mfma_f32_16x16x32_bf16(ah, bl, acc[t], 0, 0, 0);
      acc[t] = __builtin_amdgcn_mfma_f32_16x16x32_bf16(al, bh, acc[t], 0, 0, 0);
    }
  }
}

template <int T>
__device__ __forceinline__ void store_1m(const f32x4 acc[T], int n0,
                                         unsigned short* outHi,
                                         unsigned short* outLo, int sOut, int lane) {
  const int col = lane & 15, quad = lane >> 4;
#pragma unroll
  for (int t = 0; t < T; ++t)
#pragma unroll
    for (int r = 0; r < 4; ++r) {
      int p = quad * 4 + r;
      float v = fmaxf(acc[t][r], 0.f);
      unsigned short h, l;
      split_bf(v, h, l);
      outHi[p * sOut + n0 + t * 16 + col] = h;
      outLo[p * sOut + n0 + t * 16 + col] = l;
    }
}

// ---------------------------------------------------------------------------
// SA1 (MFMA, wave=n-slice): ball query + MLP 12->64->64->128 + maxpool.
// ---------------------------------------------------------------------------
__global__ __launch_bounds__(256, 4) void sa1_kernel(
    const float* __restrict__ x,    // [16][2048][9]
    const float* __restrict__ pos,  // [16][2048][3]
    const float* __restrict__ ctr,  // [16][1024][3]
    const unsigned short* __restrict__ w1h, const unsigned short* __restrict__ w1l,
    const unsigned short* __restrict__ w2h, const unsigned short* __restrict__ w2l,
    const unsigned short* __restrict__ w3h, const unsigned short* __restrict__ w3l,
    const float* __restrict__ b1, const float* __restrict__ b2,
    const float* __restrict__ b3,
    float* __restrict__ out)        // [16][1024][128]
{
  const int N = 2048;
  const float r2 = (float)(0.2 * 0.2);
  const int bs = blockIdx.x;
  const int b = bs >> 10;
  const int tid = threadIdx.x;
  const int w = tid >> 6, lane = tid & 63;
  const float cx = ctr[bs * 3 + 0], cy = ctr[bs * 3 + 1], cz = ctr[bs * 3 + 2];
  __shared__ __align__(16) unsigned short bufA_hi[64 * 72], bufA_lo[64 * 72];
  __shared__ __align__(16) unsigned short bufB_hi[64 * 72], bufB_lo[64 * 72];
  __shared__ int nb[64];
  __shared__ int nval_s;
  if (w == 0) {
    nb[lane] = 0;
    int cnt = 0;
    {
#pragma clang fp contract(off)
#pragma unroll 1
      for (int base = 0; base < N; base += 64) {
        int i = base + lane;
        const float* p = pos + ((size_t)b * N + i) * 3;
        float dx = p[0] - cx, dy = p[1] - cy, dz = p[2] - cz;
        float t0 = dx * dx, t1 = dy * dy, t2 = dz * dz;
        float d2 = (t0 + t1) + t2;
        bool inr = d2 <= r2;
        unsigned long long m = __ballot(inr);
        int posn = cnt + (int)__popcll(m & ((1ull << lane) - 1ull));
        if (inr && posn < 64) nb[posn] = i;
        cnt += (int)__popcll(m);
      }
    }
    if (lane == 0) nval_s = cnt < 64 ? cnt : 64;
  }
  __syncthreads();
  const int nvalid = nval_s;
  if (w == 0) {
    int j = nb[lane];
    const float* xr = x + ((size_t)b * N + j) * 9;
    const float* pr = pos + ((size_t)b * N + j) * 3;
    float f[12];
#pragma unroll
    for (int k = 0; k < 9; ++k) f[k] = xr[k];
    f[9] = pr[0] - cx; f[10] = pr[1] - cy; f[11] = pr[2] - cz;
#pragma unroll
    for (int k = 0; k < 12; ++k) {
      unsigned short h, l;
      split_bf(f[k], h, l);
      bufA_hi[lane * 72 + k] = h;
      bufA_lo[lane * 72 + k] = l;
    }
  } else if (w == 1) {
#pragma unroll
    for (int k = 12; k < 32; ++k) {
      bufA_hi[lane * 72 + k] = 0;
      bufA_lo[lane * 72 + k] = 0;
    }
  }
  __syncthreads();
  {  // L1: K=32(12), N=64; wave n-slice [w*16, w*16+16)
    f32x4 acc[4][1];
    mfma_allm<1, 1>(bufA_hi, bufA_lo, 72, w1h, w1l, 40, b1, w * 16, lane, acc);
    store_allm<1>(acc, w * 16, bufB_hi, bufB_lo, 72, lane);
  }
  __syncthreads();
  {  // L2: K=64, N=64; reads B, writes A (A dead after L1)
    f32x4 acc[4][1];
    mfma_allm<2, 1>(bufB_hi, bufB_lo, 72, w2h, w2l, 72, b2, w * 16, lane, acc);
    store_allm<1>(acc, w * 16, bufA_hi, bufA_lo, 72, lane);
  }
  __syncthreads();
  {  // L3: K=64, N=128; wave n-slice [w*32, w*32+32) + pool over all 64 edges
    f32x4 acc[4][2];
    mfma_allm<2, 2>(bufA_hi, bufA_lo, 72, w3h, w3l, 72, b3, w * 32, lane, acc);
    outpool_allm<2>(acc, w * 32, out + (size_t)bs * 128, nvalid, lane);
  }
}

// ---------------------------------------------------------------------------
// SA2 (MFMA, wave=n-slice): ball query + MLP 131->128->128->256 + maxpool.
// ---------------------------------------------------------------------------
__global__ __launch_bounds__(256, 2) void sa2_kernel(
    const float* __restrict__ x1,   // [16][1024][128]
    const float* __restrict__ pos1, // [16][1024][3]
    const float* __restrict__ ctr,  // [16][256][3]
    const unsigned short* __restrict__ w1h, const unsigned short* __restrict__ w1l,
    const unsigned short* __restrict__ w2h, const unsigned short* __restrict__ w2l,
    const unsigned short* __restrict__ w3h, const unsigned short* __restrict__ w3l,
    const float* __restrict__ b1, const float* __restrict__ b2,
    const float* __restrict__ b3,
    float* __restrict__ out)        // [16][256][256]
{
  const int N = 1024;
  const float r2 = (float)(0.4 * 0.4);
  const int bs = blockIdx.x;
  const int b = bs >> 8;
  const int tid = threadIdx.x;
  const int w = tid >> 6, lane = tid & 63;
  const float cx = ctr[bs * 3 + 0], cy = ctr[bs * 3 + 1], cz = ctr[bs * 3 + 2];
  __shared__ __align__(16) unsigned short bufA_hi[64 * 168], bufA_lo[64 * 168];
  __shared__ __align__(16) unsigned short bufB_hi[64 * 136], bufB_lo[64 * 136];
  __shared__ int nb[64];
  __shared__ int nval_s;
  if (w == 0) {
    nb[lane] = 0;
    int cnt = 0;
    {
#pragma clang fp contract(off)
#pragma unroll 1
      for (int base = 0; base < N; base += 64) {
        int i = base + lane;
        const float* p = pos1 + ((size_t)b * N + i) * 3;
        float dx = p[0] - cx, dy = p[1] - cy, dz = p[2] - cz;
        float t0 = dx * dx, t1 = dy * dy, t2 = dz * dz;
        float d2 = (t0 + t1) + t2;
        bool inr = d2 <= r2;
        unsigned long long m = __ballot(inr);
        int posn = cnt + (int)__popcll(m & ((1ull << lane) - 1ull));
        if (inr && posn < 64) nb[posn] = i;
        cnt += (int)__popcll(m);
      }
    }
    if (lane == 0) nval_s = cnt < 64 ? cnt : 64;
  }
  __syncthreads();
  const int nvalid = nval_s;
  {  // stage features: quarter w loads k in [32w, 32w+32); w0 also rel+pad
    int j = nb[lane];
    const float* xr = x1 + ((size_t)b * N + j) * 128 + 32 * w;
#pragma unroll
    for (int g = 0; g < 8; ++g) {
      float4 v = *(const float4*)(xr + 4 * g);
      float vv[4] = {v.x, v.y, v.z, v.w};
#pragma unroll
      for (int e = 0; e < 4; ++e) {
        unsigned short h, l;
        split_bf(vv[e], h, l);
        int k = 32 * w + 4 * g + e;
        bufA_hi[lane * 168 + k] = h;
        bufA_lo[lane * 168 + k] = l;
      }
    }
    if (w == 0) {
      const float* pr = pos1 + ((size_t)b * N + j) * 3;
      float rr[3] = {pr[0] - cx, pr[1] - cy, pr[2] - cz};
#pragma unroll
      for (int c = 0; c < 3; ++c) {
        unsigned short h, l;
        split_bf(rr[c], h, l);
        bufA_hi[lane * 168 + 128 + c] = h;
        bufA_lo[lane * 168 + 128 + c] = l;
      }
#pragma unroll
      for (int k = 131; k < 160; ++k) {
        bufA_hi[lane * 168 + k] = 0;
        bufA_lo[lane * 168 + k] = 0;
      }
    }
  }
  __syncthreads();
  {  // L1: K=160(131), N=128; n-slice [w*32, w*32+32)
    f32x4 acc[4][2];
    mfma_allm<5, 2>(bufA_hi, bufA_lo, 168, w1h, w1l, 168, b1, w * 32, lane, acc);
    store_allm<2>(acc, w * 32, bufB_hi, bufB_lo, 136, lane);
  }
  __syncthreads();
  {  // L2: K=128, N=128; reads B, writes A (dead after L1)
    f32x4 acc[4][2];
    mfma_allm<4, 2>(bufB_hi, bufB_lo, 136, w2h, w2l, 136, b2, w * 32, lane, acc);
    store_allm<2>(acc, w * 32, bufA_hi, bufA_lo, 168, lane);
  }
  __syncthreads();
  {  // L3: K=128, N=256; n-slice [w*64, w*64+64) + pool
    f32x4 acc[4][4];
    mfma_allm<4, 4>(bufA_hi, bufA_lo, 168, w3h, w3l, 136, b3, w * 64, lane, acc);
    outpool_allm<4>(acc, w * 64, out + (size_t)bs * 256, nvalid, lane);
  }
}

// ---------------------------------------------------------------------------
// Global SA (MFMA): MLP 259->256->512->1024, 16 points/block (one m-tile),
// wave = n-quarter, partial max over the 16 points -> part[16][16][1024].
// ---------------------------------------------------------------------------
__global__ __launch_bounds__(256, 2) void gsa_kernel(
    const float* __restrict__ x2,  // [16][256][256]
    const float* __restrict__ p2,  // [16][256][3]
    const unsigned short* __restrict__ g1h, const unsigned short* __restrict__ g1l,
    const unsigned short* __restrict__ g2h, const unsigned short* __restrict__ g2l,
    const unsigned short* __restrict__ g3h, const unsigned short* __restrict__ g3l,
    const float* __restrict__ b1, const float* __restrict__ b2,
    const float* __restrict__ b3,
    float* __restrict__ part)      // [16][16][1024]
{
  const int blk = blockIdx.x;  // 256
  const int bt = blk >> 4, gidx = blk & 15;
  const int tid = threadIdx.x;
  const int w = tid >> 6, lane = tid & 63;
  const int p0 = gidx * 16;
  __shared__ __align__(16) unsigned short inH[16 * 296], inL[16 * 296];
  __shared__ __align__(16) unsigned short h1H[16 * 264], h1L[16 * 264];
  __shared__ __align__(16) unsigned short h2H[16 * 520], h2L[16 * 520];
  {  // stage 16 points x 256 feats + 3 pos + zero pad to 288
    int p = tid >> 4, seg = tid & 15;
    const float* xr = x2 + ((size_t)(bt * 256 + p0 + p)) * 256 + seg * 16;
#pragma unroll
    for (int g = 0; g < 4; ++g) {
      float4 v = *(const float4*)(xr + 4 * g);
      float vv[4] = {v.x, v.y, v.z, v.w};
#pragma unroll
      for (int e = 0; e < 4; ++e) {
        unsigned short h, l;
        split_bf(vv[e], h, l);
        int k = seg * 16 + 4 * g + e;
        inH[p * 296 + k] = h;
        inL[p * 296 + k] = l;
      }
    }
    if (tid < 16) {
      const float* pr = p2 + (bt * 256 + p0 + tid) * 3;
#pragma unroll
      for (int c = 0; c < 3; ++c) {
        unsigned short h, l;
        split_bf(pr[c], h, l);
        inH[tid * 296 + 256 + c] = h;
        inL[tid * 296 + 256 + c] = l;
      }
      for (int k = 259; k < 288; ++k) {
        inH[tid * 296 + k] = 0;
        inL[tid * 296 + k] = 0;
      }
    }
  }
  __syncthreads();
  {  // L1: K=288(259), N=256; wave n-quarter [w*64, w*64+64)
    f32x4 acc[4];
    mfma_1m<9, 4>(inH, inL, 296, g1h, g1l, 296, b1, w * 64, lane, acc);
    store_1m<4>(acc, w * 64, h1H, h1L, 264, lane);
  }
  __syncthreads();
  {  // L2: K=256, N=512; n-quarter [w*128, w*128+128)
    f32x4 acc[8];
    mfma_1m<8, 8>(h1H, h1L, 264, g2h, g2l, 264, b2, w * 128, lane, acc);
    store_1m<8>(acc, w * 128, h2H, h2L, 520, lane);
  }
  __syncthreads();
  {  // L3: K=512, N=1024; n-quarter [w*256, w*256+256) + max over 16 points
    f32x4 acc[16];
    mfma_1m<16, 16>(h2H, h2L, 520, g3h, g3l, 520, b3, w * 256, lane, acc);
    const int col = lane & 15;
    float* op = part + ((size_t)(bt * 16 + gidx)) * 1024 + w * 256;
#pragma unroll
    for (int t = 0; t < 16; ++t) {
      float m = -DEVINF;
#pragma unroll
      for (int r = 0; r < 4; ++r) m = fmaxf(m, fmaxf(acc[t][r], 0.f));
      m = fmaxf(m, __shfl_xor(m, 16, 64));
      m = fmaxf(m, __shfl_xor(m, 32, 64));
      if ((lane >> 4) == 0) op[t * 16 + col] = m;
    }
  }
}

__global__ __launch_bounds__(256) void gmax_kernel(const float* __restrict__ part,
                                                   float* __restrict__ g) {
  int i = blockIdx.x * 256 + threadIdx.x;  // 16384
  int b = i >> 10, c = i & 1023;
  float m = -DEVINF;
#pragma unroll
  for (int t = 0; t < 16; ++t) m = fmaxf(m, part[((size_t)(b * 16 + t) << 10) + c]);
  g[i] = m;
}

// ---------------------------------------------------------------------------
// Dense layer: out[M][N] = (relu?)(in @ w + b). block=64 (one m, 64 n's).
// ---------------------------------------------------------------------------
__global__ __launch_bounds__(64, 4) void dense_kernel(
    const float* __restrict__ in, const float* __restrict__ w,
    const float* __restrict__ bias, float* __restrict__ out,
    int M, int K, int N, int relu) {
  int nb = N >> 6;
  int m = blockIdx.x / nb, cb = blockIdx.x % nb;
  int n = cb * 64 + threadIdx.x;
  const float* ir = in + (size_t)m * K;
  float acc = bias[n];
  for (int k = 0; k < K; ++k) acc = fmaf(ir[k], w[(size_t)k * N + n], acc);
  if (relu) acc = fmaxf(acc, 0.f);
  out[(size_t)m * N + n] = acc;
}

// ---------------------------------------------------------------------------
extern "C" void kernel_launch(void* const* d_in, const int* in_sizes, int n_in,
                              void* d_out, int out_size, void* d_ws, size_t ws_size,
                              hipStream_t stream) {
  (void)in_sizes; (void)n_in; (void)out_size; (void)ws_size;
  const float* x    = (const float*)d_in[0];
  const float* pos  = (const float*)d_in[1];
  const float* s1w1 = (const float*)d_in[2];  const float* s1b1 = (const float*)d_in[3];
  const float* s1w2 = (const float*)d_in[4];  const float* s1b2 = (const float*)d_in[5];
  const float* s1w3 = (const float*)d_in[6];  const float* s1b3 = (const float*)d_in[7];
  const float* s2w1 = (const float*)d_in[8];  const float* s2b1 = (const float*)d_in[9];
  const float* s2w2 = (const float*)d_in[10]; const float* s2b2 = (const float*)d_in[11];
  const float* s2w3 = (const float*)d_in[12]; const float* s2b3 = (const float*)d_in[13];
  const float* s3w1 = (const float*)d_in[14]; const float* s3b1 = (const float*)d_in[15];
  const float* s3w2 = (const float*)d_in[16]; const float* s3b2 = (const float*)d_in[17];
  const float* s3w3 = (const float*)d_in[18]; const float* s3b3 = (const float*)d_in[19];
  const float* fw1  = (const float*)d_in[20]; const float* fb1  = (const float*)d_in[21];
  const float* fw2  = (const float*)d_in[22]; const float* fb2  = (const float*)d_in[23];
  const float* fw3  = (const float*)d_in[24]; const float* fb3  = (const float*)d_in[25];
  const float* l1w  = (const float*)d_in[26]; const float* l1b  = (const float*)d_in[27];
  const float* l2w  = (const float*)d_in[28]; const float* l2b  = (const float*)d_in[29];
  const float* l3w  = (const float*)d_in[30]; const float* l3b  = (const float*)d_in[31];
  const float* l4w  = (const float*)d_in[32]; const float* l4b  = (const float*)d_in[33];
  const float* l5w  = (const float*)d_in[34]; const float* l5b  = (const float*)d_in[35];
  float* out = (float*)d_out;

  float* ws = (float*)d_ws;
  float* p1   = ws;                  // 16*1024*3
  float* x1   = p1 + 49152;          // 16*1024*128
  float* p2   = x1 + 2097152;        // 16*256*3
  float* x2   = p2 + 12288;          // 16*256*256
  float* part = x2 + 1048576;        // 16*16*1024
  float* g    = part + 262144;       // 16*1024
  float* hA   = g + 16384;
  float* hB   = hA + 8192;
  float* hC   = hB + 4096;
  float* hD   = hC + 4096;
  float* hE   = hD + 2048;
  float* hF   = hE + 2048;
  float* hG   = hF + 1024;
  // bf16 hi/lo transposed weight planes (u16)
  unsigned short* wp = (unsigned short*)(hG + 512);
  unsigned short* s1w1h = wp;              unsigned short* s1w1l = s1w1h + 2560;    // [64][40]
  unsigned short* s1w2h = s1w1l + 2560;    unsigned short* s1w2l = s1w2h + 4608;    // [64][72]
  unsigned short* s1w3h = s1w2l + 4608;    unsigned short* s1w3l = s1w3h + 9216;    // [128][72]
  unsigned short* s2w1h = s1w3l + 9216;    unsigned short* s2w1l = s2w1h + 21504;   // [128][168]
  unsigned short* s2w2h = s2w1l + 21504;   unsigned short* s2w2l = s2w2h + 17408;   // [128][136]
  unsigned short* s2w3h = s2w2l + 17408;   unsigned short* s2w3l = s2w3h + 34816;   // [256][136]
  unsigned short* g1h   = s2w3l + 34816;   unsigned short* g1l   = g1h + 75776;     // [256][296]
  unsigned short* g2h   = g1l + 75776;     unsigned short* g2l   = g2h + 135168;    // [512][264]
  unsigned short* g3h   = g2l + 135168;    unsigned short* g3l   = g3h + 532480;    // [1024][520]

  PrepJobs jb;
  const float* srcs[9] = {s1w1, s1w2, s1w3, s2w1, s2w2, s2w3, s3w1, s3w2, s3w3};
  unsigned short* his[9] = {s1w1h, s1w2h, s1w3h, s2w1h, s2w2h, s2w3h, g1h, g2h, g3h};
  unsigned short* los[9] = {s1w1l, s1w2l, s1w3l, s2w1l, s2w2l, s2w3l, g1l, g2l, g3l};
  int Ks[9]  = {12, 64, 64, 131, 128, 128, 259, 256, 512};
  int Ns[9]  = {64, 64, 128, 128, 128, 256, 256, 512, 1024};
  int rls[9] = {40, 72, 72, 168, 136, 136, 296, 264, 520};
  int acc_blk = 0;
  for (int j = 0; j < 9; ++j) {
    jb.src[j] = srcs[j]; jb.hi[j] = his[j]; jb.lo[j] = los[j];
    jb.K[j] = Ks[j]; jb.N[j] = Ns[j]; jb.rl[j] = rls[j];
    jb.blk0[j] = acc_blk;
    acc_blk += (Ns[j] * rls[j] + 255) / 256;
  }
  jb.blk0[9] = acc_blk;

  prep_all<<<acc_blk, 256, 0, stream>>>(jb);
  fps_chain<<<16, 64, 0, stream>>>(pos, p1, p2);
  sa1_kernel<<<16 * 1024, 256, 0, stream>>>(x, pos, p1, s1w1h, s1w1l, s1w2h,
                                            s1w2l, s1w3h, s1w3l, s1b1, s1b2,
                                            s1b3, x1);
  sa2_kernel<<<16 * 256, 256, 0, stream>>>(x1, p1, p2, s2w1h, s2w1l, s2w2h,
                                           s2w2l, s2w3h, s2w3l, s2b1, s2b2,
                                           s2b3, x2);
  gsa_kernel<<<256, 256, 0, stream>>>(x2, p2, g1h, g1l, g2h, g2l, g3h, g3l,
                                      s3b1, s3b2, s3b3, part);
  gmax_kernel<<<64, 256, 0, stream>>>(part, g);
  dense_kernel<<<16 * 8, 64, 0, stream>>>(g,  l1w, l1b, hA, 16, 1024, 512, 1);
  dense_kernel<<<16 * 4, 64, 0, stream>>>(hA, l2w, l2b, hB, 16, 512, 256, 1);
  dense_kernel<<<16 * 4, 64, 0, stream>>>(hB, l3w, l3b, hC, 16, 256, 256, 0);
  // hC [16][256] viewed as [4][1024]
  dense_kernel<<<4 * 8, 64, 0, stream>>>(hC, fw1, fb1, hD, 4, 1024, 512, 1);
  dense_kernel<<<4 * 8, 64, 0, stream>>>(hD, fw2, fb2, hE, 4, 512, 512, 1);
  dense_kernel<<<4 * 4, 64, 0, stream>>>(hE, fw3, fb3, hF, 4, 512, 256, 1);
  dense_kernel<<<4 * 2, 64, 0, stream>>>(hF, l4w, l4b, hG, 4, 256, 128, 1);
  dense_kernel<<<4 * 2, 64, 0, stream>>>(hG, l5w, l5b, out, 4, 128, 128, 0);
}

// Round 6
// 1856.384 us; speedup vs baseline: 3.3874x; 1.4675x over previous
//
#include <hip/hip_runtime.h>
#include <cstddef>

#define DEVINF __builtin_inff()

typedef __attribute__((ext_vector_type(8))) short bf16x8;
typedef __attribute__((ext_vector_type(4))) float f32x4;
typedef __attribute__((ext_vector_type(2))) float f32x2;

__device__ __forceinline__ unsigned short f2bf(float x) {
  unsigned u = __float_as_uint(x);
  return (unsigned short)((u + 0x7fff + ((u >> 16) & 1)) >> 16);
}
__device__ __forceinline__ float bf2f(unsigned short h) {
  return __uint_as_float(((unsigned)h) << 16);
}
__device__ __forceinline__ void split_bf(float x, unsigned short& hi, unsigned short& lo) {
  hi = f2bf(x);
  lo = f2bf(x - bf2f(hi));
}

// ---------------------------------------------------------------------------
// FPS step: update per-lane min-dists, argmax with numpy first-max semantics.
// 4 independent chains -> pairwise combine -> DPP row_shr/row_bcast ladder on
// packed key (val_bits, ~idx); u32-pair max == (max val, lowest idx).
// ---------------------------------------------------------------------------
#define FPS_RED_LEVEL(CTRL)                                                      \
  {                                                                              \
    int th = __builtin_amdgcn_update_dpp((int)hi, (int)hi, CTRL, 0xf, 0xf, false); \
    int tl = __builtin_amdgcn_update_dpp((int)lo, (int)lo, CTRL, 0xf, 0xf, false); \
    bool take = ((unsigned)th > hi) || (((unsigned)th == hi) && ((unsigned)tl > lo)); \
    hi = take ? (unsigned)th : hi;                                               \
    lo = take ? (unsigned)tl : lo;                                               \
  }

template <int PPLH>
__device__ __forceinline__ int fps_step(f32x2* qx, f32x2* qy, f32x2* qz,
                                        f32x2* d, float lx, float ly, float lz,
                                        int lane) {
#pragma clang fp contract(off)
  const int CH = PPLH / 4;
  float bv[4];
  int bi[4];
#pragma unroll
  for (int c = 0; c < 4; ++c) { bv[c] = -DEVINF; bi[c] = 0x7fffffff; }
  f32x2 lxv = {lx, lx}, lyv = {ly, ly}, lzv = {lz, lz};
#pragma unroll
  for (int h = 0; h < PPLH; ++h) {
    const int c = h / CH;
    f32x2 dx = qx[h] - lxv, dy = qy[h] - lyv, dz = qz[h] - lzv;
    f32x2 t0 = dx * dx, t1 = dy * dy, t2 = dz * dz;
    f32x2 d2 = (t0 + t1) + t2;
    f32x2 dn;
    dn.x = fminf(d[h].x, d2.x);
    dn.y = fminf(d[h].y, d2.y);
    d[h] = dn;
    int i0 = (2 * h) * 64 + lane;
    if (dn.x > bv[c]) { bv[c] = dn.x; bi[c] = i0; }
    if (dn.y > bv[c]) { bv[c] = dn.y; bi[c] = i0 + 64; }
  }
  // pairwise combine of 4 chains (2-level dep tree)
  unsigned h0 = __float_as_uint(bv[0]), l0 = ~(unsigned)bi[0];
  unsigned h1 = __float_as_uint(bv[1]), l1 = ~(unsigned)bi[1];
  unsigned h2 = __float_as_uint(bv[2]), l2 = ~(unsigned)bi[2];
  unsigned h3 = __float_as_uint(bv[3]), l3 = ~(unsigned)bi[3];
  bool t01 = (h1 > h0) || ((h1 == h0) && (l1 > l0));
  unsigned ha = t01 ? h1 : h0, la = t01 ? l1 : l0;
  bool t23 = (h3 > h2) || ((h3 == h2) && (l3 > l2));
  unsigned hb = t23 ? h3 : h2, lb = t23 ? l3 : l2;
  bool tab = (hb > ha) || ((hb == ha) && (lb > la));
  unsigned hi = tab ? hb : ha, lo = tab ? lb : la;
  FPS_RED_LEVEL(0x111)  // row_shr:1
  FPS_RED_LEVEL(0x112)  // row_shr:2
  FPS_RED_LEVEL(0x114)  // row_shr:4
  FPS_RED_LEVEL(0x118)  // row_shr:8
  FPS_RED_LEVEL(0x142)  // row_bcast:15
  FPS_RED_LEVEL(0x143)  // row_bcast:31
  unsigned flo = (unsigned)__builtin_amdgcn_readlane((int)lo, 63);
  return (int)~flo;
}

// fps1: 2048 -> 1024 centers. Single wave per batch; coords in VGPRs; winner
// coords broadcast via one ds_read_b128; centers bulk-stored at the end.
__global__ __launch_bounds__(64) void fps1_kernel(const float* __restrict__ pos,
                                                  float* __restrict__ p1) {
#pragma clang fp contract(off)
  const int b = blockIdx.x;
  const int lane = threadIdx.x;
  __shared__ __align__(16) float4 p4[2048];
  __shared__ __align__(16) float4 carr[1024];
  f32x2 qx[16], qy[16], qz[16], d[16];
#pragma unroll
  for (int h = 0; h < 16; ++h) {
    int i0 = (2 * h) * 64 + lane, i1 = i0 + 64;
    const float* a = pos + ((size_t)b * 2048 + i0) * 3;
    const float* c = pos + ((size_t)b * 2048 + i1) * 3;
    float x0 = a[0], y0 = a[1], z0 = a[2];
    float x1 = c[0], y1 = c[1], z1 = c[2];
    qx[h].x = x0; qx[h].y = x1;
    qy[h].x = y0; qy[h].y = y1;
    qz[h].x = z0; qz[h].y = z1;
    d[h].x = DEVINF; d[h].y = DEVINF;
    p4[i0] = float4{x0, y0, z0, 0.f};
    p4[i1] = float4{x1, y1, z1, 0.f};
  }
  int last = 0;
  for (int s = 0; s < 1024; ++s) {
    float4 c4 = p4[last];
    if (lane == 0) carr[s] = c4;
    last = fps_step<16>(qx, qy, qz, d, c4.x, c4.y, c4.z, lane);
  }
  for (int i = lane; i < 1024; i += 64) {
    float4 c = carr[i];
    p1[((size_t)b * 1024 + i) * 3 + 0] = c.x;
    p1[((size_t)b * 1024 + i) * 3 + 1] = c.y;
    p1[((size_t)b * 1024 + i) * 3 + 2] = c.z;
  }
}

// ---------------------------------------------------------------------------
// prep_all: all 9 weight transposes ([K][N] -> padded bf16 hi/lo [N][rl]).
// ---------------------------------------------------------------------------
struct PrepJobs {
  const float* src[9];
  unsigned short* hi[9];
  unsigned short* lo[9];
  int K[9], N[9], rl[9];
  int blk0[10];
};

__global__ __launch_bounds__(256) void prep_all(PrepJobs jb) {
  int blk = blockIdx.x;
  int j = 0;
#pragma unroll
  for (int t = 1; t < 9; ++t)
    if (blk >= jb.blk0[t]) j = t;
  int idx = (blk - jb.blk0[j]) * 256 + threadIdx.x;
  int rl = jb.rl[j], N = jb.N[j], K = jb.K[j];
  if (idx >= N * rl) return;
  int n = idx / rl, k = idx - n * rl;
  float v = (k < K) ? jb.src[j][(size_t)k * N + n] : 0.f;
  unsigned short h, l;
  split_bf(v, h, l);
  jb.hi[j][idx] = h;
  jb.lo[j][idx] = l;
}

// ---------------------------------------------------------------------------
// MFMA building blocks (as round 5; B fragments loaded once per 12 MFMAs).
// ---------------------------------------------------------------------------
template <int KS, int T>
__device__ __forceinline__ void mfma_allm(
    const unsigned short* __restrict__ inHi, const unsigned short* __restrict__ inLo,
    int sIn, const unsigned short* __restrict__ wHi,
    const unsigned short* __restrict__ wLo, int rl, const float* __restrict__ bias,
    int n0, int lane, f32x4 acc[4][T]) {
  const int col = lane & 15, quad = lane >> 4;
#pragma unroll
  for (int t = 0; t < T; ++t) {
    float bv = bias[n0 + t * 16 + col];
#pragma unroll
    for (int mt = 0; mt < 4; ++mt) {
      acc[mt][t].x = bv; acc[mt][t].y = bv; acc[mt][t].z = bv; acc[mt][t].w = bv;
    }
  }
#pragma unroll 1
  for (int ks = 0; ks < KS; ++ks) {
    bf16x8 ah[4], al[4];
#pragma unroll
    for (int mt = 0; mt < 4; ++mt) {
      int aoff = (mt * 16 + col) * sIn + ks * 32 + quad * 8;
      ah[mt] = *(const bf16x8*)(inHi + aoff);
      al[mt] = *(const bf16x8*)(inLo + aoff);
    }
#pragma unroll
    for (int t = 0; t < T; ++t) {
      size_t boff = (size_t)(n0 + t * 16 + col) * rl + ks * 32 + quad * 8;
      bf16x8 bh = *(const bf16x8*)(wHi + boff);
      bf16x8 bl = *(const bf16x8*)(wLo + boff);
#pragma unroll
      for (int mt = 0; mt < 4; ++mt) {
        acc[mt][t] = __builtin_amdgcn_mfma_f32_16x16x32_bf16(ah[mt], bh, acc[mt][t], 0, 0, 0);
        acc[mt][t] = __builtin_amdgcn_mfma_f32_16x16x32_bf16(ah[mt], bl, acc[mt][t], 0, 0, 0);
        acc[mt][t] = __builtin_amdgcn_mfma_f32_16x16x32_bf16(al[mt], bh, acc[mt][t], 0, 0, 0);
      }
    }
  }
}

template <int T>
__device__ __forceinline__ void store_allm(const f32x4 acc[4][T], int n0,
                                           unsigned short* outHi,
                                           unsigned short* outLo, int sOut,
                                           int lane) {
  const int col = lane & 15, quad = lane >> 4;
#pragma unroll
  for (int mt = 0; mt < 4; ++mt)
#pragma unroll
    for (int t = 0; t < T; ++t)
#pragma unroll
      for (int r = 0; r < 4; ++r) {
        int edge = mt * 16 + quad * 4 + r;
        float v = fmaxf(acc[mt][t][r], 0.f);
        unsigned short h, l;
        split_bf(v, h, l);
        outHi[edge * sOut + n0 + t * 16 + col] = h;
        outLo[edge * sOut + n0 + t * 16 + col] = l;
      }
}

template <int T>
__device__ __forceinline__ void outpool_allm(const f32x4 acc[4][T], int n0,
                                             float* __restrict__ outp, int nvalid,
                                             int lane) {
  const int col = lane & 15, quad = lane >> 4;
#pragma unroll
  for (int t = 0; t < T; ++t) {
    float m = -DEVINF;
#pragma unroll
    for (int mt = 0; mt < 4; ++mt)
#pragma unroll
      for (int r = 0; r < 4; ++r) {
        int edge = mt * 16 + quad * 4 + r;
        float v = fmaxf(acc[mt][t][r], 0.f);
        if (edge >= nvalid) v = -DEVINF;
        m = fmaxf(m, v);
      }
    m = fmaxf(m, __shfl_xor(m, 16, 64));
    m = fmaxf(m, __shfl_xor(m, 32, 64));
    if (quad == 0) outp[n0 + t * 16 + col] = m;
  }
}

// single-m-tile variants (gsa)
template <int KS, int T>
__device__ __forceinline__ void mfma_1m(
    const unsigned short* __restrict__ inHi, const unsigned short* __restrict__ inLo,
    int sIn, const unsigned short* __restrict__ wHi,
    const unsigned short* __restrict__ wLo, int rl, const float* __restrict__ bias,
    int n0, int lane, f32x4 acc[T]) {
  const int col = lane & 15, quad = lane >> 4;
#pragma unroll
  for (int t = 0; t < T; ++t) {
    float bv = bias[n0 + t * 16 + col];
    acc[t].x = bv; acc[t].y = bv; acc[t].z = bv; acc[t].w = bv;
  }
#pragma unroll 1
  for (int ks = 0; ks < KS; ++ks) {
    int aoff = col * sIn + ks * 32 + quad * 8;
    bf16x8 ah = *(const bf16x8*)(inHi + aoff);
    bf16x8 al = *(const bf16x8*)(inLo + aoff);
#pragma unroll
    for (int t = 0; t < T; ++t) {
      size_t boff = (size_t)(n0 + t * 16 + col) * rl + ks * 32 + quad * 8;
      bf16x8 bh = *(const bf16x8*)(wHi + boff);
      bf16x8 bl = *(const bf16x8*)(wLo + boff);
      acc[t] = __builtin_amdgcn_mfma_f32_16x16x32_bf16(ah, bh, acc[t], 0, 0, 0);
      acc[t] = __builtin_amdgcn_mfma_f32_16x16x32_bf16(ah, bl, acc[t], 0, 0, 0);
      acc[t] = __builtin_amdgcn_mfma_f32_16x16x32_bf16(al, bh, acc[t], 0, 0, 0);
    }
  }
}

template <int T>
__device__ __forceinline__ void store_1m(const f32x4 acc[T], int n0,
                                         unsigned short* outHi,
                                         unsigned short* outLo, int sOut, int lane) {
  const int col = lane & 15, quad = lane >> 4;
#pragma unroll
  for (int t = 0; t < T; ++t)
#pragma unroll
    for (int r = 0; r < 4; ++r) {
      int p = quad * 4 + r;
      float v = fmaxf(acc[t][r], 0.f);
      unsigned short h, l;
      split_bf(v, h, l);
      outHi[p * sOut + n0 + t * 16 + col] = h;
      outLo[p * sOut + n0 + t * 16 + col] = l;
    }
}

// ---------------------------------------------------------------------------
// SA1 (MFMA, wave=n-slice) + EMBEDDED fps2: blocks 0..15 run the serial fps2
// chain (p1 -> p2, 256 steps) concurrently with the 16384 sa1 blocks.
// ---------------------------------------------------------------------------
__global__ __launch_bounds__(256, 4) void sa1_kernel(
    const float* __restrict__ x,    // [16][2048][9]
    const float* __restrict__ pos,  // [16][2048][3]
    const float* __restrict__ ctr,  // p1: [16][1024][3]
    float* __restrict__ p2,         // [16][256][3] (fps2 output)
    const unsigned short* __restrict__ w1h, const unsigned short* __restrict__ w1l,
    const unsigned short* __restrict__ w2h, const unsigned short* __restrict__ w2l,
    const unsigned short* __restrict__ w3h, const unsigned short* __restrict__ w3l,
    const float* __restrict__ b1, const float* __restrict__ b2,
    const float* __restrict__ b3,
    float* __restrict__ out)        // [16][1024][128]
{
  const int N = 2048;
  const float r2 = (float)(0.2 * 0.2);
  const int tid = threadIdx.x;
  const int w = tid >> 6, lane = tid & 63;
  __shared__ __align__(16) unsigned short smem[4 * 4608];  // 36,864 B
  unsigned short* bufA_hi = smem;
  unsigned short* bufA_lo = smem + 4608;
  unsigned short* bufB_hi = smem + 9216;
  unsigned short* bufB_lo = smem + 13824;
  __shared__ int nb[64];
  __shared__ int nval_s;

  if (blockIdx.x < 16) {
    // ---------------- fps2: 1024 -> 256 centers, serial chain ----------------
    const int bb = blockIdx.x;
    float4* q4 = (float4*)smem;                  // 16 KB
    float4* carr = (float4*)(smem + 13824);      // 4 KB (offset 27,648 B)
    for (int i = tid; i < 1024; i += 256) {
      const float* pr = ctr + ((size_t)bb * 1024 + i) * 3;
      q4[i] = float4{pr[0], pr[1], pr[2], 0.f};
    }
    __syncthreads();
    if (w == 0) {
      f32x2 qx[8], qy[8], qz[8], d[8];
#pragma unroll
      for (int h = 0; h < 8; ++h) {
        int i0 = (2 * h) * 64 + lane, i1 = i0 + 64;
        float4 a = q4[i0], c = q4[i1];
        qx[h].x = a.x; qx[h].y = c.x;
        qy[h].x = a.y; qy[h].y = c.y;
        qz[h].x = a.z; qz[h].y = c.z;
        d[h].x = DEVINF; d[h].y = DEVINF;
      }
      int last = 0;
      for (int s = 0; s < 256; ++s) {
        float4 c4 = q4[last];
        if (lane == 0) carr[s] = c4;
        last = fps_step<8>(qx, qy, qz, d, c4.x, c4.y, c4.z, lane);
      }
      for (int i = lane; i < 256; i += 64) {
        float4 c = carr[i];
        p2[((size_t)bb * 256 + i) * 3 + 0] = c.x;
        p2[((size_t)bb * 256 + i) * 3 + 1] = c.y;
        p2[((size_t)bb * 256 + i) * 3 + 2] = c.z;
      }
    }
    return;
  }

  const int bs = blockIdx.x - 16;
  const int b = bs >> 10;
  const float cx = ctr[bs * 3 + 0], cy = ctr[bs * 3 + 1], cz = ctr[bs * 3 + 2];
  if (w == 0) {
    nb[lane] = 0;
    int cnt = 0;
    {
#pragma clang fp contract(off)
#pragma unroll 8
      for (int base = 0; base < N; base += 64) {
        int i = base + lane;
        const float* p = pos + ((size_t)b * N + i) * 3;
        float dx = p[0] - cx, dy = p[1] - cy, dz = p[2] - cz;
        float t0 = dx * dx, t1 = dy * dy, t2 = dz * dz;
        float d2 = (t0 + t1) + t2;
        bool inr = d2 <= r2;
        unsigned long long m = __ballot(inr);
        int posn = cnt + (int)__popcll(m & ((1ull << lane) - 1ull));
        if (inr && posn < 64) nb[posn] = i;
        cnt += (int)__popcll(m);
      }
    }
    if (lane == 0) nval_s = cnt < 64 ? cnt : 64;
  }
  __syncthreads();
  const int nvalid = nval_s;
  if (w == 0) {
    int j = nb[lane];
    const float* xr = x + ((size_t)b * N + j) * 9;
    const float* pr = pos + ((size_t)b * N + j) * 3;
    float f[12];
#pragma unroll
    for (int k = 0; k < 9; ++k) f[k] = xr[k];
    f[9] = pr[0] - cx; f[10] = pr[1] - cy; f[11] = pr[2] - cz;
#pragma unroll
    for (int k = 0; k < 12; ++k) {
      unsigned short h, l;
      split_bf(f[k], h, l);
      bufA_hi[lane * 72 + k] = h;
      bufA_lo[lane * 72 + k] = l;
    }
  } else if (w == 1) {
#pragma unroll
    for (int k = 12; k < 32; ++k) {
      bufA_hi[lane * 72 + k] = 0;
      bufA_lo[lane * 72 + k] = 0;
    }
  }
  __syncthreads();
  {  // L1: K=32(12), N=64; wave n-slice [w*16, w*16+16)
    f32x4 acc[4][1];
    mfma_allm<1, 1>(bufA_hi, bufA_lo, 72, w1h, w1l, 40, b1, w * 16, lane, acc);
    store_allm<1>(acc, w * 16, bufB_hi, bufB_lo, 72, lane);
  }
  __syncthreads();
  {  // L2: K=64, N=64; reads B, writes A
    f32x4 acc[4][1];
    mfma_allm<2, 1>(bufB_hi, bufB_lo, 72, w2h, w2l, 72, b2, w * 16, lane, acc);
    store_allm<1>(acc, w * 16, bufA_hi, bufA_lo, 72, lane);
  }
  __syncthreads();
  {  // L3: K=64, N=128; wave n-slice [w*32, w*32+32) + pool
    f32x4 acc[4][2];
    mfma_allm<2, 2>(bufA_hi, bufA_lo, 72, w3h, w3l, 72, b3, w * 32, lane, acc);
    outpool_allm<2>(acc, w * 32, out + (size_t)bs * 128, nvalid, lane);
  }
}

// ---------------------------------------------------------------------------
// SA2 (MFMA, wave=n-slice): ball query + MLP 131->128->128->256 + maxpool.
// ---------------------------------------------------------------------------
__global__ __launch_bounds__(256, 2) void sa2_kernel(
    const float* __restrict__ x1,   // [16][1024][128]
    const float* __restrict__ pos1, // [16][1024][3]
    const float* __restrict__ ctr,  // [16][256][3]
    const unsigned short* __restrict__ w1h, const unsigned short* __restrict__ w1l,
    const unsigned short* __restrict__ w2h, const unsigned short* __restrict__ w2l,
    const unsigned short* __restrict__ w3h, const unsigned short* __restrict__ w3l,
    const float* __restrict__ b1, const float* __restrict__ b2,
    const float* __restrict__ b3,
    float* __restrict__ out)        // [16][256][256]
{
  const int N = 1024;
  const float r2 = (float)(0.4 * 0.4);
  const int bs = blockIdx.x;
  const int b = bs >> 8;
  const int tid = threadIdx.x;
  const int w = tid >> 6, lane = tid & 63;
  const float cx = ctr[bs * 3 + 0], cy = ctr[bs * 3 + 1], cz = ctr[bs * 3 + 2];
  __shared__ __align__(16) unsigned short bufA_hi[64 * 168], bufA_lo[64 * 168];
  __shared__ __align__(16) unsigned short bufB_hi[64 * 136], bufB_lo[64 * 136];
  __shared__ int nb[64];
  __shared__ int nval_s;
  if (w == 0) {
    nb[lane] = 0;
    int cnt = 0;
    {
#pragma clang fp contract(off)
#pragma unroll 8
      for (int base = 0; base < N; base += 64) {
        int i = base + lane;
        const float* p = pos1 + ((size_t)b * N + i) * 3;
        float dx = p[0] - cx, dy = p[1] - cy, dz = p[2] - cz;
        float t0 = dx * dx, t1 = dy * dy, t2 = dz * dz;
        float d2 = (t0 + t1) + t2;
        bool inr = d2 <= r2;
        unsigned long long m = __ballot(inr);
        int posn = cnt + (int)__popcll(m & ((1ull << lane) - 1ull));
        if (inr && posn < 64) nb[posn] = i;
        cnt += (int)__popcll(m);
      }
    }
    if (lane == 0) nval_s = cnt < 64 ? cnt : 64;
  }
  __syncthreads();
  const int nvalid = nval_s;
  {  // stage features: quarter w loads k in [32w, 32w+32); w0 also rel+pad
    int j = nb[lane];
    const float* xr = x1 + ((size_t)b * N + j) * 128 + 32 * w;
#pragma unroll
    for (int g = 0; g < 8; ++g) {
      float4 v = *(const float4*)(xr + 4 * g);
      float vv[4] = {v.x, v.y, v.z, v.w};
#pragma unroll
      for (int e = 0; e < 4; ++e) {
        unsigned short h, l;
        split_bf(vv[e], h, l);
        int k = 32 * w + 4 * g + e;
        bufA_hi[lane * 168 + k] = h;
        bufA_lo[lane * 168 + k] = l;
      }
    }
    if (w == 0) {
      const float* pr = pos1 + ((size_t)b * N + j) * 3;
      float rr[3] = {pr[0] - cx, pr[1] - cy, pr[2] - cz};
#pragma unroll
      for (int c = 0; c < 3; ++c) {
        unsigned short h, l;
        split_bf(rr[c], h, l);
        bufA_hi[lane * 168 + 128 + c] = h;
        bufA_lo[lane * 168 + 128 + c] = l;
      }
#pragma unroll
      for (int k = 131; k < 160; ++k) {
        bufA_hi[lane * 168 + k] = 0;
        bufA_lo[lane * 168 + k] = 0;
      }
    }
  }
  __syncthreads();
  {  // L1: K=160(131), N=128; n-slice [w*32, w*32+32)
    f32x4 acc[4][2];
    mfma_allm<5, 2>(bufA_hi, bufA_lo, 168, w1h, w1l, 168, b1, w * 32, lane, acc);
    store_allm<2>(acc, w * 32, bufB_hi, bufB_lo, 136, lane);
  }
  __syncthreads();
  {  // L2: K=128, N=128; reads B, writes A
    f32x4 acc[4][2];
    mfma_allm<4, 2>(bufB_hi, bufB_lo, 136, w2h, w2l, 136, b2, w * 32, lane, acc);
    store_allm<2>(acc, w * 32, bufA_hi, bufA_lo, 168, lane);
  }
  __syncthreads();
  {  // L3: K=128, N=256; n-slice [w*64, w*64+64) + pool
    f32x4 acc[4][4];
    mfma_allm<4, 4>(bufA_hi, bufA_lo, 168, w3h, w3l, 136, b3, w * 64, lane, acc);
    outpool_allm<4>(acc, w * 64, out + (size_t)bs * 256, nvalid, lane);
  }
}

// ---------------------------------------------------------------------------
// Global SA (MFMA): MLP 259->256->512->1024, 16 points/block, wave=n-quarter.
// ---------------------------------------------------------------------------
__global__ __launch_bounds__(256, 2) void gsa_kernel(
    const float* __restrict__ x2,  // [16][256][256]
    const float* __restrict__ p2,  // [16][256][3]
    const unsigned short* __restrict__ g1h, const unsigned short* __restrict__ g1l,
    const unsigned short* __restrict__ g2h, const unsigned short* __restrict__ g2l,
    const unsigned short* __restrict__ g3h, const unsigned short* __restrict__ g3l,
    const float* __restrict__ b1, const float* __restrict__ b2,
    const float* __restrict__ b3,
    float* __restrict__ part)      // [16][16][1024]
{
  const int blk = blockIdx.x;  // 256
  const int bt = blk >> 4, gidx = blk & 15;
  const int tid = threadIdx.x;
  const int w = tid >> 6, lane = tid & 63;
  const int p0 = gidx * 16;
  __shared__ __align__(16) unsigned short inH[16 * 296], inL[16 * 296];
  __shared__ __align__(16) unsigned short h1H[16 * 264], h1L[16 * 264];
  __shared__ __align__(16) unsigned short h2H[16 * 520], h2L[16 * 520];
  {  // stage 16 points x 256 feats + 3 pos + zero pad to 288
    int p = tid >> 4, seg = tid & 15;
    const float* xr = x2 + ((size_t)(bt * 256 + p0 + p)) * 256 + seg * 16;
#pragma unroll
    for (int g = 0; g < 4; ++g) {
      float4 v = *(const float4*)(xr + 4 * g);
      float vv[4] = {v.x, v.y, v.z, v.w};
#pragma unroll
      for (int e = 0; e < 4; ++e) {
        unsigned short h, l;
        split_bf(vv[e], h, l);
        int k = seg * 16 + 4 * g + e;
        inH[p * 296 + k] = h;
        inL[p * 296 + k] = l;
      }
    }
    if (tid < 16) {
      const float* pr = p2 + (bt * 256 + p0 + tid) * 3;
#pragma unroll
      for (int c = 0; c < 3; ++c) {
        unsigned short h, l;
        split_bf(pr[c], h, l);
        inH[tid * 296 + 256 + c] = h;
        inL[tid * 296 + 256 + c] = l;
      }
      for (int k = 259; k < 288; ++k) {
        inH[tid * 296 + k] = 0;
        inL[tid * 296 + k] = 0;
      }
    }
  }
  __syncthreads();
  {  // L1: K=288(259), N=256
    f32x4 acc[4];
    mfma_1m<9, 4>(inH, inL, 296, g1h, g1l, 296, b1, w * 64, lane, acc);
    store_1m<4>(acc, w * 64, h1H, h1L, 264, lane);
  }
  __syncthreads();
  {  // L2: K=256, N=512
    f32x4 acc[8];
    mfma_1m<8, 8>(h1H, h1L, 264, g2h, g2l, 264, b2, w * 128, lane, acc);
    store_1m<8>(acc, w * 128, h2H, h2L, 520, lane);
  }
  __syncthreads();
  {  // L3: K=512, N=1024 + max over 16 points
    f32x4 acc[16];
    mfma_1m<16, 16>(h2H, h2L, 520, g3h, g3l, 520, b3, w * 256, lane, acc);
    const int col = lane & 15;
    float* op = part + ((size_t)(bt * 16 + gidx)) * 1024 + w * 256;
#pragma unroll
    for (int t = 0; t < 16; ++t) {
      float m = -DEVINF;
#pragma unroll
      for (int r = 0; r < 4; ++r) m = fmaxf(m, fmaxf(acc[t][r], 0.f));
      m = fmaxf(m, __shfl_xor(m, 16, 64));
      m = fmaxf(m, __shfl_xor(m, 32, 64));
      if ((lane >> 4) == 0) op[t * 16 + col] = m;
    }
  }
}

// ---------------------------------------------------------------------------
// head1: gmax + l1 + l2 + l3. One block per B-row (16 blocks).
// Identical summation order to reference (bias + ascending-k fmaf).
// ---------------------------------------------------------------------------
__global__ __launch_bounds__(256) void head1_kernel(
    const float* __restrict__ part,  // [16][16][1024]
    const float* __restrict__ l1w, const float* __restrict__ l1b,
    const float* __restrict__ l2w, const float* __restrict__ l2b,
    const float* __restrict__ l3w, const float* __restrict__ l3b,
    float* __restrict__ hC)          // [16][256]
{
  const int m = blockIdx.x;
  const int tid = threadIdx.x;
  __shared__ float gA[1024];
  __shared__ float hX[512];
  __shared__ float hY[256];
#pragma unroll
  for (int j = 0; j < 4; ++j) {
    int c = j * 256 + tid;
    float mx = -DEVINF;
#pragma unroll
    for (int t = 0; t < 16; ++t)
      mx = fmaxf(mx, part[((size_t)(m * 16 + t)) * 1024 + c]);
    gA[c] = mx;
  }
  __syncthreads();
  {  // l1: 1024 -> 512, relu
    float a0 = l1b[tid], a1 = l1b[tid + 256];
#pragma unroll 4
    for (int k = 0; k < 1024; ++k) {
      float v = gA[k];
      a0 = fmaf(v, l1w[(size_t)k * 512 + tid], a0);
      a1 = fmaf(v, l1w[(size_t)k * 512 + tid + 256], a1);
    }
    hX[tid] = fmaxf(a0, 0.f);
    hX[tid + 256] = fmaxf(a1, 0.f);
  }
  __syncthreads();
  {  // l2: 512 -> 256, relu
    float a = l2b[tid];
#pragma unroll 4
    for (int k = 0; k < 512; ++k) a = fmaf(hX[k], l2w[(size_t)k * 256 + tid], a);
    hY[tid] = fmaxf(a, 0.f);
  }
  __syncthreads();
  {  // l3: 256 -> 256, no relu
    float a = l3b[tid];
#pragma unroll 4
    for (int k = 0; k < 256; ++k) a = fmaf(hY[k], l3w[(size_t)k * 256 + tid], a);
    hC[(size_t)m * 256 + tid] = a;
  }
}

// ---------------------------------------------------------------------------
// head2: fusion MLP (fw1,fw2,fw3) + l4 + l5. One block per fused row (4).
// ---------------------------------------------------------------------------
__global__ __launch_bounds__(256) void head2_kernel(
    const float* __restrict__ hC,  // [4][1024]
    const float* __restrict__ fw1, const float* __restrict__ fb1,
    const float* __restrict__ fw2, const float* __restrict__ fb2,
    const float* __restrict__ fw3, const float* __restrict__ fb3,
    const float* __restrict__ l4w, const float* __restrict__ l4b,
    const float* __restrict__ l5w, const float* __restrict__ l5b,
    float* __restrict__ out)       // [4][128]
{
  const int m = blockIdx.x;
  const int tid = threadIdx.x;
  __shared__ float A[1024];
  __shared__ float Bf[512];
#pragma unroll
  for (int j = 0; j < 4; ++j) A[j * 256 + tid] = hC[(size_t)m * 1024 + j * 256 + tid];
  __syncthreads();
  {  // fw1: 1024 -> 512 relu, A -> Bf
    float a0 = fb1[tid], a1 = fb1[tid + 256];
#pragma unroll 4
    for (int k = 0; k < 1024; ++k) {
      float v = A[k];
      a0 = fmaf(v, fw1[(size_t)k * 512 + tid], a0);
      a1 = fmaf(v, fw1[(size_t)k * 512 + tid + 256], a1);
    }
    Bf[tid] = fmaxf(a0, 0.f);
    Bf[tid + 256] = fmaxf(a1, 0.f);
  }
  __syncthreads();
  {  // fw2: 512 -> 512 relu, Bf -> A
    float a0 = fb2[tid], a1 = fb2[tid + 256];
#pragma unroll 4
    for (int k = 0; k < 512; ++k) {
      float v = Bf[k];
      a0 = fmaf(v, fw2[(size_t)k * 512 + tid], a0);
      a1 = fmaf(v, fw2[(size_t)k * 512 + tid + 256], a1);
    }
    __syncthreads();  // all Bf reads done before Bf is rewritten next layer
    A[tid] = fmaxf(a0, 0.f);
    A[tid + 256] = fmaxf(a1, 0.f);
  }
  __syncthreads();
  {  // fw3: 512 -> 256 relu, A -> Bf
    float a = fb3[tid];
#pragma unroll 4
    for (int k = 0; k < 512; ++k) a = fmaf(A[k], fw3[(size_t)k * 256 + tid], a);
    __syncthreads();  // all A reads done before A rewritten next layer
    Bf[tid] = fmaxf(a, 0.f);
  }
  __syncthreads();
  {  // l4: 256 -> 128 relu, Bf -> A
    float a = 0.f;
    if (tid < 128) {
      a = l4b[tid];
#pragma unroll 4
      for (int k = 0; k < 256; ++k) a = fmaf(Bf[k], l4w[(size_t)k * 128 + tid], a);
      A[tid] = fmaxf(a, 0.f);
    }
  }
  __syncthreads();
  {  // l5: 128 -> 128, A -> out
    if (tid < 128) {
      float a = l5b[tid];
#pragma unroll 4
      for (int k = 0; k < 128; ++k) a = fmaf(A[k], l5w[(size_t)k * 128 + tid], a);
      out[(size_t)m * 128 + tid] = a;
    }
  }
}

// ---------------------------------------------------------------------------
extern "C" void kernel_launch(void* const* d_in, const int* in_sizes, int n_in,
                              void* d_out, int out_size, void* d_ws, size_t ws_size,
                              hipStream_t stream) {
  (void)in_sizes; (void)n_in; (void)out_size; (void)ws_size;
  const float* x    = (const float*)d_in[0];
  const float* pos  = (const float*)d_in[1];
  const float* s1w1 = (const float*)d_in[2];  const float* s1b1 = (const float*)d_in[3];
  const float* s1w2 = (const float*)d_in[4];  const float* s1b2 = (const float*)d_in[5];
  const float* s1w3 = (const float*)d_in[6];  const float* s1b3 = (const float*)d_in[7];
  const float* s2w1 = (const float*)d_in[8];  const float* s2b1 = (const float*)d_in[9];
  const float* s2w2 = (const float*)d_in[10]; const float* s2b2 = (const float*)d_in[11];
  const float* s2w3 = (const float*)d_in[12]; const float* s2b3 = (const float*)d_in[13];
  const float* s3w1 = (const float*)d_in[14]; const float* s3b1 = (const float*)d_in[15];
  const float* s3w2 = (const float*)d_in[16]; const float* s3b2 = (const float*)d_in[17];
  const float* s3w3 = (const float*)d_in[18]; const float* s3b3 = (const float*)d_in[19];
  const float* fw1  = (const float*)d_in[20]; const float* fb1  = (const float*)d_in[21];
  const float* fw2  = (const float*)d_in[22]; const float* fb2  = (const float*)d_in[23];
  const float* fw3  = (const float*)d_in[24]; const float* fb3  = (const float*)d_in[25];
  const float* l1w  = (const float*)d_in[26]; const float* l1b  = (const float*)d_in[27];
  const float* l2w  = (const float*)d_in[28]; const float* l2b  = (const float*)d_in[29];
  const float* l3w  = (const float*)d_in[30]; const float* l3b  = (const float*)d_in[31];
  const float* l4w  = (const float*)d_in[32]; const float* l4b  = (const float*)d_in[33];
  const float* l5w  = (const float*)d_in[34]; const float* l5b  = (const float*)d_in[35];
  float* out = (float*)d_out;

  float* ws = (float*)d_ws;
  float* p1   = ws;                  // 16*1024*3
  float* x1   = p1 + 49152;          // 16*1024*128
  float* p2   = x1 + 2097152;        // 16*256*3
  float* x2   = p2 + 12288;          // 16*256*256
  float* part = x2 + 1048576;        // 16*16*1024
  float* hC   = part + 262144;       // 16*256
  // bf16 hi/lo transposed weight planes (u16)
  unsigned short* wp = (unsigned short*)(hC + 4096);
  unsigned short* s1w1h = wp;              unsigned short* s1w1l = s1w1h + 2560;    // [64][40]
  unsigned short* s1w2h = s1w1l + 2560;    unsigned short* s1w2l = s1w2h + 4608;    // [64][72]
  unsigned short* s1w3h = s1w2l + 4608;    unsigned short* s1w3l = s1w3h + 9216;    // [128][72]
  unsigned short* s2w1h = s1w3l + 9216;    unsigned short* s2w1l = s2w1h + 21504;   // [128][168]
  unsigned short* s2w2h = s2w1l + 21504;   unsigned short* s2w2l = s2w2h + 17408;   // [128][136]
  unsigned short* s2w3h = s2w2l + 17408;   unsigned short* s2w3l = s2w3h + 34816;   // [256][136]
  unsigned short* g1h   = s2w3l + 34816;   unsigned short* g1l   = g1h + 75776;     // [256][296]
  unsigned short* g2h   = g1l + 75776;     unsigned short* g2l   = g2h + 135168;    // [512][264]
  unsigned short* g3h   = g2l + 135168;    unsigned short* g3l   = g3h + 532480;    // [1024][520]

  PrepJobs jb;
  const float* srcs[9] = {s1w1, s1w2, s1w3, s2w1, s2w2, s2w3, s3w1, s3w2, s3w3};
  unsigned short* his[9] = {s1w1h, s1w2h, s1w3h, s2w1h, s2w2h, s2w3h, g1h, g2h, g3h};
  unsigned short* los[9] = {s1w1l, s1w2l, s1w3l, s2w1l, s2w2l, s2w3l, g1l, g2l, g3l};
  int Ks[9]  = {12, 64, 64, 131, 128, 128, 259, 256, 512};
  int Ns[9]  = {64, 64, 128, 128, 128, 256, 256, 512, 1024};
  int rls[9] = {40, 72, 72, 168, 136, 136, 296, 264, 520};
  int acc_blk = 0;
  for (int j = 0; j < 9; ++j) {
    jb.src[j] = srcs[j]; jb.hi[j] = his[j]; jb.lo[j] = los[j];
    jb.K[j] = Ks[j]; jb.N[j] = Ns[j]; jb.rl[j] = rls[j];
    jb.blk0[j] = acc_blk;
    acc_blk += (Ns[j] * rls[j] + 255) / 256;
  }
  jb.blk0[9] = acc_blk;

  prep_all<<<acc_blk, 256, 0, stream>>>(jb);
  fps1_kernel<<<16, 64, 0, stream>>>(pos, p1);
  sa1_kernel<<<16 * 1024 + 16, 256, 0, stream>>>(x, pos, p1, p2, s1w1h, s1w1l,
                                                 s1w2h, s1w2l, s1w3h, s1w3l,
                                                 s1b1, s1b2, s1b3, x1);
  sa2_kernel<<<16 * 256, 256, 0, stream>>>(x1, p1, p2, s2w1h, s2w1l, s2w2h,
                                           s2w2l, s2w3h, s2w3l, s2b1, s2b2,
                                           s2b3, x2);
  gsa_kernel<<<256, 256, 0, stream>>>(x2, p2, g1h, g1l, g2h, g2l, g3h, g3l,
                                      s3b1, s3b2, s3b3, part);
  head1_kernel<<<16, 256, 0, stream>>>(part, l1w, l1b, l2w, l2b, l3w, l3b, hC);
  head2_kernel<<<4, 256, 0, stream>>>(hC, fw1, fb1, fw2, fb2, fw3, fb3, l4w,
                                      l4b, l5w, l5b, out);
}

// Round 7
// 1789.389 us; speedup vs baseline: 3.5142x; 1.0374x over previous
//
#include <hip/hip_runtime.h>
#include <cstddef>

#define DEVINF __builtin_inff()

typedef __attribute__((ext_vector_type(8))) short bf16x8;
typedef __attribute__((ext_vector_type(4))) float f32x4;
typedef __attribute__((ext_vector_type(2))) float f32x2;

__device__ __forceinline__ unsigned short f2bf(float x) {
  unsigned u = __float_as_uint(x);
  return (unsigned short)((u + 0x7fff + ((u >> 16) & 1)) >> 16);
}
__device__ __forceinline__ float bf2f(unsigned short h) {
  return __uint_as_float(((unsigned)h) << 16);
}
__device__ __forceinline__ void split_bf(float x, unsigned short& hi, unsigned short& lo) {
  hi = f2bf(x);
  lo = f2bf(x - bf2f(hi));
}

// ---------------------------------------------------------------------------
// FPS step: update per-lane min-dists, argmax with numpy first-max semantics.
// 4 independent chains -> pairwise combine -> DPP row_shr/row_bcast ladder on
// packed key (val_bits, ~idx); u32-pair max == (max val, lowest idx).
// ---------------------------------------------------------------------------
#define FPS_RED_LEVEL(CTRL)                                                      \
  {                                                                              \
    int th = __builtin_amdgcn_update_dpp((int)hi, (int)hi, CTRL, 0xf, 0xf, false); \
    int tl = __builtin_amdgcn_update_dpp((int)lo, (int)lo, CTRL, 0xf, 0xf, false); \
    bool take = ((unsigned)th > hi) || (((unsigned)th == hi) && ((unsigned)tl > lo)); \
    hi = take ? (unsigned)th : hi;                                               \
    lo = take ? (unsigned)tl : lo;                                               \
  }

template <int PPLH>
__device__ __forceinline__ int fps_step(f32x2* qx, f32x2* qy, f32x2* qz,
                                        f32x2* d, float lx, float ly, float lz,
                                        int lane) {
#pragma clang fp contract(off)
  const int CH = PPLH / 4;
  float bv[4];
  int bi[4];
#pragma unroll
  for (int c = 0; c < 4; ++c) { bv[c] = -DEVINF; bi[c] = 0x7fffffff; }
  f32x2 lxv = {lx, lx}, lyv = {ly, ly}, lzv = {lz, lz};
#pragma unroll
  for (int h = 0; h < PPLH; ++h) {
    const int c = h / CH;
    f32x2 dx = qx[h] - lxv, dy = qy[h] - lyv, dz = qz[h] - lzv;
    f32x2 t0 = dx * dx, t1 = dy * dy, t2 = dz * dz;
    f32x2 d2 = (t0 + t1) + t2;
    f32x2 dn;
    dn.x = fminf(d[h].x, d2.x);
    dn.y = fminf(d[h].y, d2.y);
    d[h] = dn;
    int i0 = (2 * h) * 64 + lane;
    if (dn.x > bv[c]) { bv[c] = dn.x; bi[c] = i0; }
    if (dn.y > bv[c]) { bv[c] = dn.y; bi[c] = i0 + 64; }
  }
  // pairwise combine of 4 chains (2-level dep tree)
  unsigned h0 = __float_as_uint(bv[0]), l0 = ~(unsigned)bi[0];
  unsigned h1 = __float_as_uint(bv[1]), l1 = ~(unsigned)bi[1];
  unsigned h2 = __float_as_uint(bv[2]), l2 = ~(unsigned)bi[2];
  unsigned h3 = __float_as_uint(bv[3]), l3 = ~(unsigned)bi[3];
  bool t01 = (h1 > h0) || ((h1 == h0) && (l1 > l0));
  unsigned ha = t01 ? h1 : h0, la = t01 ? l1 : l0;
  bool t23 = (h3 > h2) || ((h3 == h2) && (l3 > l2));
  unsigned hb = t23 ? h3 : h2, lb = t23 ? l3 : l2;
  bool tab = (hb > ha) || ((hb == ha) && (lb > la));
  unsigned hi = tab ? hb : ha, lo = tab ? lb : la;
  FPS_RED_LEVEL(0x111)  // row_shr:1
  FPS_RED_LEVEL(0x112)  // row_shr:2
  FPS_RED_LEVEL(0x114)  // row_shr:4
  FPS_RED_LEVEL(0x118)  // row_shr:8
  FPS_RED_LEVEL(0x142)  // row_bcast:15
  FPS_RED_LEVEL(0x143)  // row_bcast:31
  unsigned flo = (unsigned)__builtin_amdgcn_readlane((int)lo, 63);
  return (int)~flo;
}

// ---------------------------------------------------------------------------
// prep jobs table: weight transposes ([K][N] -> padded bf16 hi/lo [N][rl]),
// fused into the fps1 launch (64-thread granularity).
// ---------------------------------------------------------------------------
struct PrepJobs {
  const float* src[9];
  unsigned short* hi[9];
  unsigned short* lo[9];
  int K[9], N[9], rl[9];
  int blk0[10];
};

// ---------------------------------------------------------------------------
// fps1 (blocks 0..15): 2048 -> 1024 centers, single-wave serial chain.
// __launch_bounds__(64,1): FPS state alone is 128 VGPRs; min-waves=1 frees
// the register allocator (~512 VGPR budget) so the 16-h update loop can be
// software-pipelined instead of serializing on 4 spare temps.
// blocks 16..: weight-prep elements (runs on the 240 idle CUs, hidden).
// ---------------------------------------------------------------------------
__global__ __launch_bounds__(64, 1) void fps1_prep_kernel(
    const float* __restrict__ pos, float* __restrict__ p1, PrepJobs jb) {
#pragma clang fp contract(off)
  const int lane = threadIdx.x;
  if (blockIdx.x >= 16) {
    int blk = blockIdx.x - 16;
    int j = 0;
#pragma unroll
    for (int t = 1; t < 9; ++t)
      if (blk >= jb.blk0[t]) j = t;
    int idx = (blk - jb.blk0[j]) * 64 + lane;
    int rl = jb.rl[j], N = jb.N[j], K = jb.K[j];
    if (idx >= N * rl) return;
    int n = idx / rl, k = idx - n * rl;
    float v = (k < K) ? jb.src[j][(size_t)k * N + n] : 0.f;
    unsigned short h, l;
    split_bf(v, h, l);
    jb.hi[j][idx] = h;
    jb.lo[j][idx] = l;
    return;
  }
  const int b = blockIdx.x;
  __shared__ __align__(16) float4 p4[2048];
  __shared__ __align__(16) float4 carr[1024];
  f32x2 qx[16], qy[16], qz[16], d[16];
#pragma unroll
  for (int h = 0; h < 16; ++h) {
    int i0 = (2 * h) * 64 + lane, i1 = i0 + 64;
    const float* a = pos + ((size_t)b * 2048 + i0) * 3;
    const float* c = pos + ((size_t)b * 2048 + i1) * 3;
    float x0 = a[0], y0 = a[1], z0 = a[2];
    float x1 = c[0], y1 = c[1], z1 = c[2];
    qx[h].x = x0; qx[h].y = x1;
    qy[h].x = y0; qy[h].y = y1;
    qz[h].x = z0; qz[h].y = z1;
    d[h].x = DEVINF; d[h].y = DEVINF;
    p4[i0] = float4{x0, y0, z0, 0.f};
    p4[i1] = float4{x1, y1, z1, 0.f};
  }
  int last = 0;
  for (int s = 0; s < 1024; ++s) {
    float4 c4 = p4[last];
    if (lane == 0) carr[s] = c4;
    last = fps_step<16>(qx, qy, qz, d, c4.x, c4.y, c4.z, lane);
  }
  for (int i = lane; i < 1024; i += 64) {
    float4 c = carr[i];
    p1[((size_t)b * 1024 + i) * 3 + 0] = c.x;
    p1[((size_t)b * 1024 + i) * 3 + 1] = c.y;
    p1[((size_t)b * 1024 + i) * 3 + 2] = c.z;
  }
}

// ---------------------------------------------------------------------------
// MFMA building blocks (B fragments loaded once per 12 MFMAs).
// A-frag: lane l -> A[m=l&15][k=ks*32+(l>>4)*8+j]; B from wT[n][k];
// C/D: col=l&15, row=(l>>4)*4+reg.
// ---------------------------------------------------------------------------
template <int KS, int T>
__device__ __forceinline__ void mfma_allm(
    const unsigned short* __restrict__ inHi, const unsigned short* __restrict__ inLo,
    int sIn, const unsigned short* __restrict__ wHi,
    const unsigned short* __restrict__ wLo, int rl, const float* __restrict__ bias,
    int n0, int lane, f32x4 acc[4][T]) {
  const int col = lane & 15, quad = lane >> 4;
#pragma unroll
  for (int t = 0; t < T; ++t) {
    float bv = bias[n0 + t * 16 + col];
#pragma unroll
    for (int mt = 0; mt < 4; ++mt) {
      acc[mt][t].x = bv; acc[mt][t].y = bv; acc[mt][t].z = bv; acc[mt][t].w = bv;
    }
  }
#pragma unroll 1
  for (int ks = 0; ks < KS; ++ks) {
    bf16x8 ah[4], al[4];
#pragma unroll
    for (int mt = 0; mt < 4; ++mt) {
      int aoff = (mt * 16 + col) * sIn + ks * 32 + quad * 8;
      ah[mt] = *(const bf16x8*)(inHi + aoff);
      al[mt] = *(const bf16x8*)(inLo + aoff);
    }
#pragma unroll
    for (int t = 0; t < T; ++t) {
      size_t boff = (size_t)(n0 + t * 16 + col) * rl + ks * 32 + quad * 8;
      bf16x8 bh = *(const bf16x8*)(wHi + boff);
      bf16x8 bl = *(const bf16x8*)(wLo + boff);
#pragma unroll
      for (int mt = 0; mt < 4; ++mt) {
        acc[mt][t] = __builtin_amdgcn_mfma_f32_16x16x32_bf16(ah[mt], bh, acc[mt][t], 0, 0, 0);
        acc[mt][t] = __builtin_amdgcn_mfma_f32_16x16x32_bf16(ah[mt], bl, acc[mt][t], 0, 0, 0);
        acc[mt][t] = __builtin_amdgcn_mfma_f32_16x16x32_bf16(al[mt], bh, acc[mt][t], 0, 0, 0);
      }
    }
  }
}

template <int T>
__device__ __forceinline__ void store_allm(const f32x4 acc[4][T], int n0,
                                           unsigned short* outHi,
                                           unsigned short* outLo, int sOut,
                                           int lane) {
  const int col = lane & 15, quad = lane >> 4;
#pragma unroll
  for (int mt = 0; mt < 4; ++mt)
#pragma unroll
    for (int t = 0; t < T; ++t)
#pragma unroll
      for (int r = 0; r < 4; ++r) {
        int edge = mt * 16 + quad * 4 + r;
        float v = fmaxf(acc[mt][t][r], 0.f);
        unsigned short h, l;
        split_bf(v, h, l);
        outHi[edge * sOut + n0 + t * 16 + col] = h;
        outLo[edge * sOut + n0 + t * 16 + col] = l;
      }
}

template <int T>
__device__ __forceinline__ void outpool_allm(const f32x4 acc[4][T], int n0,
                                             float* __restrict__ outp, int nvalid,
                                             int lane) {
  const int col = lane & 15, quad = lane >> 4;
#pragma unroll
  for (int t = 0; t < T; ++t) {
    float m = -DEVINF;
#pragma unroll
    for (int mt = 0; mt < 4; ++mt)
#pragma unroll
      for (int r = 0; r < 4; ++r) {
        int edge = mt * 16 + quad * 4 + r;
        float v = fmaxf(acc[mt][t][r], 0.f);
        if (edge >= nvalid) v = -DEVINF;
        m = fmaxf(m, v);
      }
    m = fmaxf(m, __shfl_xor(m, 16, 64));
    m = fmaxf(m, __shfl_xor(m, 32, 64));
    if (quad == 0) outp[n0 + t * 16 + col] = m;
  }
}

// single-m-tile variants (gsa)
template <int KS, int T>
__device__ __forceinline__ void mfma_1m(
    const unsigned short* __restrict__ inHi, const unsigned short* __restrict__ inLo,
    int sIn, const unsigned short* __restrict__ wHi,
    const unsigned short* __restrict__ wLo, int rl, const float* __restrict__ bias,
    int n0, int lane, f32x4 acc[T]) {
  const int col = lane & 15, quad = lane >> 4;
#pragma unroll
  for (int t = 0; t < T; ++t) {
    float bv = bias[n0 + t * 16 + col];
    acc[t].x = bv; acc[t].y = bv; acc[t].z = bv; acc[t].w = bv;
  }
#pragma unroll 1
  for (int ks = 0; ks < KS; ++ks) {
    int aoff = col * sIn + ks * 32 + quad * 8;
    bf16x8 ah = *(const bf16x8*)(inHi + aoff);
    bf16x8 al = *(const bf16x8*)(inLo + aoff);
#pragma unroll
    for (int t = 0; t < T; ++t) {
      size_t boff = (size_t)(n0 + t * 16 + col) * rl + ks * 32 + quad * 8;
      bf16x8 bh = *(const bf16x8*)(wHi + boff);
      bf16x8 bl = *(const bf16x8*)(wLo + boff);
      acc[t] = __builtin_amdgcn_mfma_f32_16x16x32_bf16(ah, bh, acc[t], 0, 0, 0);
      acc[t] = __builtin_amdgcn_mfma_f32_16x16x32_bf16(ah, bl, acc[t], 0, 0, 0);
      acc[t] = __builtin_amdgcn_mfma_f32_16x16x32_bf16(al, bh, acc[t], 0, 0, 0);
    }
  }
}

template <int T>
__device__ __forceinline__ void store_1m(const f32x4 acc[T], int n0,
                                         unsigned short* outHi,
                                         unsigned short* outLo, int sOut, int lane) {
  const int col = lane & 15, quad = lane >> 4;
#pragma unroll
  for (int t = 0; t < T; ++t)
#pragma unroll
    for (int r = 0; r < 4; ++r) {
      int p = quad * 4 + r;
      float v = fmaxf(acc[t][r], 0.f);
      unsigned short h, l;
      split_bf(v, h, l);
      outHi[p * sOut + n0 + t * 16 + col] = h;
      outLo[p * sOut + n0 + t * 16 + col] = l;
    }
}

// ---------------------------------------------------------------------------
// SA1 (MFMA, wave=n-slice) + EMBEDDED fps2 (blocks 0..15).
// Ball query v3: 4 waves compute in-radius masks in parallel -> LDS; each
// wave redundantly extracts the first-64-by-index list (bit-exact order).
// ---------------------------------------------------------------------------
__global__ __launch_bounds__(256, 4) void sa1_kernel(
    const float* __restrict__ x,    // [16][2048][9]
    const float* __restrict__ pos,  // [16][2048][3]
    const float* __restrict__ ctr,  // p1: [16][1024][3]
    float* __restrict__ p2,         // [16][256][3] (fps2 output)
    const unsigned short* __restrict__ w1h, const unsigned short* __restrict__ w1l,
    const unsigned short* __restrict__ w2h, const unsigned short* __restrict__ w2l,
    const unsigned short* __restrict__ w3h, const unsigned short* __restrict__ w3l,
    const float* __restrict__ b1, const float* __restrict__ b2,
    const float* __restrict__ b3,
    float* __restrict__ out)        // [16][1024][128]
{
  const int N = 2048;
  const float r2 = (float)(0.2 * 0.2);
  const int tid = threadIdx.x;
  const int w = tid >> 6, lane = tid & 63;
  __shared__ __align__(16) unsigned short smem[4 * 4608];  // 36,864 B
  unsigned short* bufA_hi = smem;
  unsigned short* bufA_lo = smem + 4608;
  unsigned short* bufB_hi = smem + 9216;
  unsigned short* bufB_lo = smem + 13824;
  __shared__ int nb[64];
  __shared__ unsigned long long mq[32];

  if (blockIdx.x < 16) {
    // ---------------- fps2: 1024 -> 256 centers, serial chain ----------------
    const int bb = blockIdx.x;
    float4* q4 = (float4*)smem;                  // 16 KB
    float4* carr = (float4*)(smem + 13824);      // 4 KB
    for (int i = tid; i < 1024; i += 256) {
      const float* pr = ctr + ((size_t)bb * 1024 + i) * 3;
      q4[i] = float4{pr[0], pr[1], pr[2], 0.f};
    }
    __syncthreads();
    if (w == 0) {
      f32x2 qx[8], qy[8], qz[8], d[8];
#pragma unroll
      for (int h = 0; h < 8; ++h) {
        int i0 = (2 * h) * 64 + lane, i1 = i0 + 64;
        float4 a = q4[i0], c = q4[i1];
        qx[h].x = a.x; qx[h].y = c.x;
        qy[h].x = a.y; qy[h].y = c.y;
        qz[h].x = a.z; qz[h].y = c.z;
        d[h].x = DEVINF; d[h].y = DEVINF;
      }
      int last = 0;
      for (int s = 0; s < 256; ++s) {
        float4 c4 = q4[last];
        if (lane == 0) carr[s] = c4;
        last = fps_step<8>(qx, qy, qz, d, c4.x, c4.y, c4.z, lane);
      }
      for (int i = lane; i < 256; i += 64) {
        float4 c = carr[i];
        p2[((size_t)bb * 256 + i) * 3 + 0] = c.x;
        p2[((size_t)bb * 256 + i) * 3 + 1] = c.y;
        p2[((size_t)bb * 256 + i) * 3 + 2] = c.z;
      }
    }
    return;
  }

  const int bs = blockIdx.x - 16;
  const int b = bs >> 10;
  const float cx = ctr[bs * 3 + 0], cy = ctr[bs * 3 + 1], cz = ctr[bs * 3 + 2];
  // ---- ball query: masks in parallel (each wave 8 of 32 groups) ----
  nb[lane] = 0;
  {
#pragma clang fp contract(off)
#pragma unroll
    for (int it = 0; it < 8; ++it) {
      int g = w * 8 + it;
      int i = g * 64 + lane;
      const float* p = pos + ((size_t)b * N + i) * 3;
      float dx = p[0] - cx, dy = p[1] - cy, dz = p[2] - cz;
      float t0 = dx * dx, t1 = dy * dy, t2 = dz * dz;
      float d2 = (t0 + t1) + t2;
      unsigned long long m = __ballot(d2 <= r2);
      if (lane == 0) mq[g] = m;
    }
  }
  __syncthreads();
  // ---- extraction (redundant per wave; identical values, benign races) ----
  int cnt = 0;
#pragma unroll 1
  for (int g = 0; g < 32; ++g) {
    unsigned long long m = mq[g];
    bool inr = (m >> lane) & 1;
    int posn = cnt + (int)__popcll(m & ((1ull << lane) - 1ull));
    if (inr && posn < 64) nb[posn] = g * 64 + lane;
    cnt += (int)__popcll(m);
    if (cnt >= 64) break;
  }
  const int nvalid = cnt < 64 ? cnt : 64;
  if (w == 0) {
    int j = nb[lane];
    const float* xr = x + ((size_t)b * N + j) * 9;
    const float* pr = pos + ((size_t)b * N + j) * 3;
    float f[12];
#pragma unroll
    for (int k = 0; k < 9; ++k) f[k] = xr[k];
    f[9] = pr[0] - cx; f[10] = pr[1] - cy; f[11] = pr[2] - cz;
#pragma unroll
    for (int k = 0; k < 12; ++k) {
      unsigned short h, l;
      split_bf(f[k], h, l);
      bufA_hi[lane * 72 + k] = h;
      bufA_lo[lane * 72 + k] = l;
    }
  } else if (w == 1) {
#pragma unroll
    for (int k = 12; k < 32; ++k) {
      bufA_hi[lane * 72 + k] = 0;
      bufA_lo[lane * 72 + k] = 0;
    }
  }
  __syncthreads();
  {  // L1: K=32(12), N=64; wave n-slice [w*16, w*16+16)
    f32x4 acc[4][1];
    mfma_allm<1, 1>(bufA_hi, bufA_lo, 72, w1h, w1l, 40, b1, w * 16, lane, acc);
    store_allm<1>(acc, w * 16, bufB_hi, bufB_lo, 72, lane);
  }
  __syncthreads();
  {  // L2: K=64, N=64; reads B, writes A
    f32x4 acc[4][1];
    mfma_allm<2, 1>(bufB_hi, bufB_lo, 72, w2h, w2l, 72, b2, w * 16, lane, acc);
    store_allm<1>(acc, w * 16, bufA_hi, bufA_lo, 72, lane);
  }
  __syncthreads();
  {  // L3: K=64, N=128; wave n-slice [w*32, w*32+32) + pool
    f32x4 acc[4][2];
    mfma_allm<2, 2>(bufA_hi, bufA_lo, 72, w3h, w3l, 72, b3, w * 32, lane, acc);
    outpool_allm<2>(acc, w * 32, out + (size_t)bs * 128, nvalid, lane);
  }
}

// ---------------------------------------------------------------------------
// SA2 (MFMA, wave=n-slice): parallel-mask ball query + MLP + maxpool.
// ---------------------------------------------------------------------------
__global__ __launch_bounds__(256, 2) void sa2_kernel(
    const float* __restrict__ x1,   // [16][1024][128]
    const float* __restrict__ pos1, // [16][1024][3]
    const float* __restrict__ ctr,  // [16][256][3]
    const unsigned short* __restrict__ w1h, const unsigned short* __restrict__ w1l,
    const unsigned short* __restrict__ w2h, const unsigned short* __restrict__ w2l,
    const unsigned short* __restrict__ w3h, const unsigned short* __restrict__ w3l,
    const float* __restrict__ b1, const float* __restrict__ b2,
    const float* __restrict__ b3,
    float* __restrict__ out)        // [16][256][256]
{
  const int N = 1024;
  const float r2 = (float)(0.4 * 0.4);
  const int bs = blockIdx.x;
  const int b = bs >> 8;
  const int tid = threadIdx.x;
  const int w = tid >> 6, lane = tid & 63;
  const float cx = ctr[bs * 3 + 0], cy = ctr[bs * 3 + 1], cz = ctr[bs * 3 + 2];
  __shared__ __align__(16) unsigned short bufA_hi[64 * 168], bufA_lo[64 * 168];
  __shared__ __align__(16) unsigned short bufB_hi[64 * 136], bufB_lo[64 * 136];
  __shared__ int nb[64];
  __shared__ unsigned long long mq[16];
  nb[lane] = 0;
  {
#pragma clang fp contract(off)
#pragma unroll
    for (int it = 0; it < 4; ++it) {
      int g = w * 4 + it;
      int i = g * 64 + lane;
      const float* p = pos1 + ((size_t)b * N + i) * 3;
      float dx = p[0] - cx, dy = p[1] - cy, dz = p[2] - cz;
      float t0 = dx * dx, t1 = dy * dy, t2 = dz * dz;
      float d2 = (t0 + t1) + t2;
      unsigned long long m = __ballot(d2 <= r2);
      if (lane == 0) mq[g] = m;
    }
  }
  __syncthreads();
  int cnt = 0;
#pragma unroll 1
  for (int g = 0; g < 16; ++g) {
    unsigned long long m = mq[g];
    bool inr = (m >> lane) & 1;
    int posn = cnt + (int)__popcll(m & ((1ull << lane) - 1ull));
    if (inr && posn < 64) nb[posn] = g * 64 + lane;
    cnt += (int)__popcll(m);
    if (cnt >= 64) break;
  }
  const int nvalid = cnt < 64 ? cnt : 64;
  {  // stage features: quarter w loads k in [32w, 32w+32); w0 also rel+pad
    int j = nb[lane];
    const float* xr = x1 + ((size_t)b * N + j) * 128 + 32 * w;
#pragma unroll
    for (int g = 0; g < 8; ++g) {
      float4 v = *(const float4*)(xr + 4 * g);
      float vv[4] = {v.x, v.y, v.z, v.w};
#pragma unroll
      for (int e = 0; e < 4; ++e) {
        unsigned short h, l;
        split_bf(vv[e], h, l);
        int k = 32 * w + 4 * g + e;
        bufA_hi[lane * 168 + k] = h;
        bufA_lo[lane * 168 + k] = l;
      }
    }
    if (w == 0) {
      const float* pr = pos1 + ((size_t)b * N + j) * 3;
      float rr[3] = {pr[0] - cx, pr[1] - cy, pr[2] - cz};
#pragma unroll
      for (int c = 0; c < 3; ++c) {
        unsigned short h, l;
        split_bf(rr[c], h, l);
        bufA_hi[lane * 168 + 128 + c] = h;
        bufA_lo[lane * 168 + 128 + c] = l;
      }
#pragma unroll
      for (int k = 131; k < 160; ++k) {
        bufA_hi[lane * 168 + k] = 0;
        bufA_lo[lane * 168 + k] = 0;
      }
    }
  }
  __syncthreads();
  {  // L1: K=160(131), N=128; n-slice [w*32, w*32+32)
    f32x4 acc[4][2];
    mfma_allm<5, 2>(bufA_hi, bufA_lo, 168, w1h, w1l, 168, b1, w * 32, lane, acc);
    store_allm<2>(acc, w * 32, bufB_hi, bufB_lo, 136, lane);
  }
  __syncthreads();
  {  // L2: K=128, N=128; reads B, writes A
    f32x4 acc[4][2];
    mfma_allm<4, 2>(bufB_hi, bufB_lo, 136, w2h, w2l, 136, b2, w * 32, lane, acc);
    store_allm<2>(acc, w * 32, bufA_hi, bufA_lo, 168, lane);
  }
  __syncthreads();
  {  // L3: K=128, N=256; n-slice [w*64, w*64+64) + pool
    f32x4 acc[4][4];
    mfma_allm<4, 4>(bufA_hi, bufA_lo, 168, w3h, w3l, 136, b3, w * 64, lane, acc);
    outpool_allm<4>(acc, w * 64, out + (size_t)bs * 256, nvalid, lane);
  }
}

// ---------------------------------------------------------------------------
// Global SA (MFMA): MLP 259->256->512->1024, 16 points/block, wave=n-quarter.
// ---------------------------------------------------------------------------
__global__ __launch_bounds__(256, 2) void gsa_kernel(
    const float* __restrict__ x2,  // [16][256][256]
    const float* __restrict__ p2,  // [16][256][3]
    const unsigned short* __restrict__ g1h, const unsigned short* __restrict__ g1l,
    const unsigned short* __restrict__ g2h, const unsigned short* __restrict__ g2l,
    const unsigned short* __restrict__ g3h, const unsigned short* __restrict__ g3l,
    const float* __restrict__ b1, const float* __restrict__ b2,
    const float* __restrict__ b3,
    float* __restrict__ part)      // [16][16][1024]
{
  const int blk = blockIdx.x;  // 256
  const int bt = blk >> 4, gidx = blk & 15;
  const int tid = threadIdx.x;
  const int w = tid >> 6, lane = tid & 63;
  const int p0 = gidx * 16;
  __shared__ __align__(16) unsigned short inH[16 * 296], inL[16 * 296];
  __shared__ __align__(16) unsigned short h1H[16 * 264], h1L[16 * 264];
  __shared__ __align__(16) unsigned short h2H[16 * 520], h2L[16 * 520];
  {  // stage 16 points x 256 feats + 3 pos + zero pad to 288
    int p = tid >> 4, seg = tid & 15;
    const float* xr = x2 + ((size_t)(bt * 256 + p0 + p)) * 256 + seg * 16;
#pragma unroll
    for (int g = 0; g < 4; ++g) {
      float4 v = *(const float4*)(xr + 4 * g);
      float vv[4] = {v.x, v.y, v.z, v.w};
#pragma unroll
      for (int e = 0; e < 4; ++e) {
        unsigned short h, l;
        split_bf(vv[e], h, l);
        int k = seg * 16 + 4 * g + e;
        inH[p * 296 + k] = h;
        inL[p * 296 + k] = l;
      }
    }
    if (tid < 16) {
      const float* pr = p2 + (bt * 256 + p0 + tid) * 3;
#pragma unroll
      for (int c = 0; c < 3; ++c) {
        unsigned short h, l;
        split_bf(pr[c], h, l);
        inH[tid * 296 + 256 + c] = h;
        inL[tid * 296 + 256 + c] = l;
      }
      for (int k = 259; k < 288; ++k) {
        inH[tid * 296 + k] = 0;
        inL[tid * 296 + k] = 0;
      }
    }
  }
  __syncthreads();
  {  // L1: K=288(259), N=256
    f32x4 acc[4];
    mfma_1m<9, 4>(inH, inL, 296, g1h, g1l, 296, b1, w * 64, lane, acc);
    store_1m<4>(acc, w * 64, h1H, h1L, 264, lane);
  }
  __syncthreads();
  {  // L2: K=256, N=512
    f32x4 acc[8];
    mfma_1m<8, 8>(h1H, h1L, 264, g2h, g2l, 264, b2, w * 128, lane, acc);
    store_1m<8>(acc, w * 128, h2H, h2L, 520, lane);
  }
  __syncthreads();
  {  // L3: K=512, N=1024 + max over 16 points
    f32x4 acc[16];
    mfma_1m<16, 16>(h2H, h2L, 520, g3h, g3l, 520, b3, w * 256, lane, acc);
    const int col = lane & 15;
    float* op = part + ((size_t)(bt * 16 + gidx)) * 1024 + w * 256;
#pragma unroll
    for (int t = 0; t < 16; ++t) {
      float m = -DEVINF;
#pragma unroll
      for (int r = 0; r < 4; ++r) m = fmaxf(m, fmaxf(acc[t][r], 0.f));
      m = fmaxf(m, __shfl_xor(m, 16, 64));
      m = fmaxf(m, __shfl_xor(m, 32, 64));
      if ((lane >> 4) == 0) op[t * 16 + col] = m;
    }
  }
}

// ---------------------------------------------------------------------------
// head1: gmax + l1 + l2 + l3. One block per B-row (16 blocks).
// ---------------------------------------------------------------------------
__global__ __launch_bounds__(256) void head1_kernel(
    const float* __restrict__ part,  // [16][16][1024]
    const float* __restrict__ l1w, const float* __restrict__ l1b,
    const float* __restrict__ l2w, const float* __restrict__ l2b,
    const float* __restrict__ l3w, const float* __restrict__ l3b,
    float* __restrict__ hC)          // [16][256]
{
  const int m = blockIdx.x;
  const int tid = threadIdx.x;
  __shared__ float gA[1024];
  __shared__ float hX[512];
  __shared__ float hY[256];
#pragma unroll
  for (int j = 0; j < 4; ++j) {
    int c = j * 256 + tid;
    float mx = -DEVINF;
#pragma unroll
    for (int t = 0; t < 16; ++t)
      mx = fmaxf(mx, part[((size_t)(m * 16 + t)) * 1024 + c]);
    gA[c] = mx;
  }
  __syncthreads();
  {  // l1: 1024 -> 512, relu
    float a0 = l1b[tid], a1 = l1b[tid + 256];
#pragma unroll 4
    for (int k = 0; k < 1024; ++k) {
      float v = gA[k];
      a0 = fmaf(v, l1w[(size_t)k * 512 + tid], a0);
      a1 = fmaf(v, l1w[(size_t)k * 512 + tid + 256], a1);
    }
    hX[tid] = fmaxf(a0, 0.f);
    hX[tid + 256] = fmaxf(a1, 0.f);
  }
  __syncthreads();
  {  // l2: 512 -> 256, relu
    float a = l2b[tid];
#pragma unroll 4
    for (int k = 0; k < 512; ++k) a = fmaf(hX[k], l2w[(size_t)k * 256 + tid], a);
    hY[tid] = fmaxf(a, 0.f);
  }
  __syncthreads();
  {  // l3: 256 -> 256, no relu
    float a = l3b[tid];
#pragma unroll 4
    for (int k = 0; k < 256; ++k) a = fmaf(hY[k], l3w[(size_t)k * 256 + tid], a);
    hC[(size_t)m * 256 + tid] = a;
  }
}

// ---------------------------------------------------------------------------
// head2: fusion MLP (fw1,fw2,fw3) + l4 + l5. One block per fused row (4).
// ---------------------------------------------------------------------------
__global__ __launch_bounds__(256) void head2_kernel(
    const float* __restrict__ hC,  // [4][1024]
    const float* __restrict__ fw1, const float* __restrict__ fb1,
    const float* __restrict__ fw2, const float* __restrict__ fb2,
    const float* __restrict__ fw3, const float* __restrict__ fb3,
    const float* __restrict__ l4w, const float* __restrict__ l4b,
    const float* __restrict__ l5w, const float* __restrict__ l5b,
    float* __restrict__ out)       // [4][128]
{
  const int m = blockIdx.x;
  const int tid = threadIdx.x;
  __shared__ float A[1024];
  __shared__ float Bf[512];
#pragma unroll
  for (int j = 0; j < 4; ++j) A[j * 256 + tid] = hC[(size_t)m * 1024 + j * 256 + tid];
  __syncthreads();
  {  // fw1: 1024 -> 512 relu, A -> Bf
    float a0 = fb1[tid], a1 = fb1[tid + 256];
#pragma unroll 4
    for (int k = 0; k < 1024; ++k) {
      float v = A[k];
      a0 = fmaf(v, fw1[(size_t)k * 512 + tid], a0);
      a1 = fmaf(v, fw1[(size_t)k * 512 + tid + 256], a1);
    }
    Bf[tid] = fmaxf(a0, 0.f);
    Bf[tid + 256] = fmaxf(a1, 0.f);
  }
  __syncthreads();
  {  // fw2: 512 -> 512 relu, Bf -> A
    float a0 = fb2[tid], a1 = fb2[tid + 256];
#pragma unroll 4
    for (int k = 0; k < 512; ++k) {
      float v = Bf[k];
      a0 = fmaf(v, fw2[(size_t)k * 512 + tid], a0);
      a1 = fmaf(v, fw2[(size_t)k * 512 + tid + 256], a1);
    }
    __syncthreads();
    A[tid] = fmaxf(a0, 0.f);
    A[tid + 256] = fmaxf(a1, 0.f);
  }
  __syncthreads();
  {  // fw3: 512 -> 256 relu, A -> Bf
    float a = fb3[tid];
#pragma unroll 4
    for (int k = 0; k < 512; ++k) a = fmaf(A[k], fw3[(size_t)k * 256 + tid], a);
    __syncthreads();
    Bf[tid] = fmaxf(a, 0.f);
  }
  __syncthreads();
  {  // l4: 256 -> 128 relu, Bf -> A
    if (tid < 128) {
      float a = l4b[tid];
#pragma unroll 4
      for (int k = 0; k < 256; ++k) a = fmaf(Bf[k], l4w[(size_t)k * 128 + tid], a);
      A[tid] = fmaxf(a, 0.f);
    }
  }
  __syncthreads();
  {  // l5: 128 -> 128, A -> out
    if (tid < 128) {
      float a = l5b[tid];
#pragma unroll 4
      for (int k = 0; k < 128; ++k) a = fmaf(A[k], l5w[(size_t)k * 128 + tid], a);
      out[(size_t)m * 128 + tid] = a;
    }
  }
}

// ---------------------------------------------------------------------------
extern "C" void kernel_launch(void* const* d_in, const int* in_sizes, int n_in,
                              void* d_out, int out_size, void* d_ws, size_t ws_size,
                              hipStream_t stream) {
  (void)in_sizes; (void)n_in; (void)out_size; (void)ws_size;
  const float* x    = (const float*)d_in[0];
  const float* pos  = (const float*)d_in[1];
  const float* s1w1 = (const float*)d_in[2];  const float* s1b1 = (const float*)d_in[3];
  const float* s1w2 = (const float*)d_in[4];  const float* s1b2 = (const float*)d_in[5];
  const float* s1w3 = (const float*)d_in[6];  const float* s1b3 = (const float*)d_in[7];
  const float* s2w1 = (const float*)d_in[8];  const float* s2b1 = (const float*)d_in[9];
  const float* s2w2 = (const float*)d_in[10]; const float* s2b2 = (const float*)d_in[11];
  const float* s2w3 = (const float*)d_in[12]; const float* s2b3 = (const float*)d_in[13];
  const float* s3w1 = (const float*)d_in[14]; const float* s3b1 = (const float*)d_in[15];
  const float* s3w2 = (const float*)d_in[16]; const float* s3b2 = (const float*)d_in[17];
  const float* s3w3 = (const float*)d_in[18]; const float* s3b3 = (const float*)d_in[19];
  const float* fw1  = (const float*)d_in[20]; const float* fb1  = (const float*)d_in[21];
  const float* fw2  = (const float*)d_in[22]; const float* fb2  = (const float*)d_in[23];
  const float* fw3  = (const float*)d_in[24]; const float* fb3  = (const float*)d_in[25];
  const float* l1w  = (const float*)d_in[26]; const float* l1b  = (const float*)d_in[27];
  const float* l2w  = (const float*)d_in[28]; const float* l2b  = (const float*)d_in[29];
  const float* l3w  = (const float*)d_in[30]; const float* l3b  = (const float*)d_in[31];
  const float* l4w  = (const float*)d_in[32]; const float* l4b  = (const float*)d_in[33];
  const float* l5w  = (const float*)d_in[34]; const float* l5b  = (const float*)d_in[35];
  float* out = (float*)d_out;

  float* ws = (float*)d_ws;
  float* p1   = ws;                  // 16*1024*3
  float* x1   = p1 + 49152;          // 16*1024*128
  float* p2   = x1 + 2097152;        // 16*256*3
  float* x2   = p2 + 12288;          // 16*256*256
  float* part = x2 + 1048576;        // 16*16*1024
  float* hC   = part + 262144;       // 16*256
  // bf16 hi/lo transposed weight planes (u16)
  unsigned short* wp = (unsigned short*)(hC + 4096);
  unsigned short* s1w1h = wp;              unsigned short* s1w1l = s1w1h + 2560;    // [64][40]
  unsigned short* s1w2h = s1w1l + 2560;    unsigned short* s1w2l = s1w2h + 4608;    // [64][72]
  unsigned short* s1w3h = s1w2l + 4608;    unsigned short* s1w3l = s1w3h + 9216;    // [128][72]
  unsigned short* s2w1h = s1w3l + 9216;    unsigned short* s2w1l = s2w1h + 21504;   // [128][168]
  unsigned short* s2w2h = s2w1l + 21504;   unsigned short* s2w2l = s2w2h + 17408;   // [128][136]
  unsigned short* s2w3h = s2w2l + 17408;   unsigned short* s2w3l = s2w3h + 34816;   // [256][136]
  unsigned short* g1h   = s2w3l + 34816;   unsigned short* g1l   = g1h + 75776;     // [256][296]
  unsigned short* g2h   = g1l + 75776;     unsigned short* g2l   = g2h + 135168;    // [512][264]
  unsigned short* g3h   = g2l + 135168;    unsigned short* g3l   = g3h + 532480;    // [1024][520]

  PrepJobs jb;
  const float* srcs[9] = {s1w1, s1w2, s1w3, s2w1, s2w2, s2w3, s3w1, s3w2, s3w3};
  unsigned short* his[9] = {s1w1h, s1w2h, s1w3h, s2w1h, s2w2h, s2w3h, g1h, g2h, g3h};
  unsigned short* los[9] = {s1w1l, s1w2l, s1w3l, s2w1l, s2w2l, s2w3l, g1l, g2l, g3l};
  int Ks[9]  = {12, 64, 64, 131, 128, 128, 259, 256, 512};
  int Ns[9]  = {64, 64, 128, 128, 128, 256, 256, 512, 1024};
  int rls[9] = {40, 72, 72, 168, 136, 136, 296, 264, 520};
  int acc_blk = 0;
  for (int j = 0; j < 9; ++j) {
    jb.src[j] = srcs[j]; jb.hi[j] = his[j]; jb.lo[j] = los[j];
    jb.K[j] = Ks[j]; jb.N[j] = Ns[j]; jb.rl[j] = rls[j];
    jb.blk0[j] = acc_blk;
    acc_blk += (Ns[j] * rls[j] + 63) / 64;   // 64-thread granularity
  }
  jb.blk0[9] = acc_blk;

  fps1_prep_kernel<<<16 + acc_blk, 64, 0, stream>>>(pos, p1, jb);
  sa1_kernel<<<16 * 1024 + 16, 256, 0, stream>>>(x, pos, p1, p2, s1w1h, s1w1l,
                                                 s1w2h, s1w2l, s1w3h, s1w3l,
                                                 s1b1, s1b2, s1b3, x1);
  sa2_kernel<<<16 * 256, 256, 0, stream>>>(x1, p1, p2, s2w1h, s2w1l, s2w2h,
                                           s2w2l, s2w3h, s2w3l, s2b1, s2b2,
                                           s2b3, x2);
  gsa_kernel<<<256, 256, 0, stream>>>(x2, p2, g1h, g1l, g2h, g2l, g3h, g3l,
                                      s3b1, s3b2, s3b3, part);
  head1_kernel<<<16, 256, 0, stream>>>(part, l1w, l1b, l2w, l2b, l3w, l3b, hC);
  head2_kernel<<<4, 256, 0, stream>>>(hC, fw1, fb1, fw2, fb2, fw3, fb3, l4w,
                                      l4b, l5w, l5b, out);
}

// Round 8
// 1479.425 us; speedup vs baseline: 4.2505x; 1.2095x over previous
//
#include <hip/hip_runtime.h>
#include <cstddef>

#define DEVINF __builtin_inff()

typedef __attribute__((ext_vector_type(8))) short bf16x8;
typedef __attribute__((ext_vector_type(4))) float f32x4;
typedef __attribute__((ext_vector_type(2))) float f32x2;

__device__ __forceinline__ unsigned short f2bf(float x) {
  unsigned u = __float_as_uint(x);
  return (unsigned short)((u + 0x7fff + ((u >> 16) & 1)) >> 16);
}
__device__ __forceinline__ float bf2f(unsigned short h) {
  return __uint_as_float(((unsigned)h) << 16);
}
__device__ __forceinline__ void split_bf(float x, unsigned short& hi, unsigned short& lo) {
  hi = f2bf(x);
  lo = f2bf(x - bf2f(hi));
}

// ---------------------------------------------------------------------------
// FPS cooperative step: each wave updates its own point range (PPLH f32x2 per
// lane), reduces to a per-wave winner key via DPP; caller exchanges 4 keys
// through LDS. Key = (val_bits<<32)|~idx: u64 max == (max val, lowest idx)
// == numpy first-max (distances >= 0 so bit-ordering is valid). Each chain
// scans ascending indices -> bit-exact vs single-wave version.
// ---------------------------------------------------------------------------
#define FPS_RED_LEVEL(CTRL)                                                      \
  {                                                                              \
    int th = __builtin_amdgcn_update_dpp((int)hi, (int)hi, CTRL, 0xf, 0xf, false); \
    int tl = __builtin_amdgcn_update_dpp((int)lo, (int)lo, CTRL, 0xf, 0xf, false); \
    bool take = ((unsigned)th > hi) || (((unsigned)th == hi) && ((unsigned)tl > lo)); \
    hi = take ? (unsigned)th : hi;                                               \
    lo = take ? (unsigned)tl : lo;                                               \
  }

template <int PPLH, int NCH>
__device__ __forceinline__ unsigned long long fps_wave_step(
    f32x2* qx, f32x2* qy, f32x2* qz, f32x2* d, float lx, float ly, float lz,
    int lane, int ibase) {
#pragma clang fp contract(off)
  const int CH = PPLH / NCH;
  float bv[NCH];
  int bi[NCH];
#pragma unroll
  for (int c = 0; c < NCH; ++c) { bv[c] = -DEVINF; bi[c] = 0x7fffffff; }
  f32x2 lxv = {lx, lx}, lyv = {ly, ly}, lzv = {lz, lz};
#pragma unroll
  for (int h = 0; h < PPLH; ++h) {
    const int c = h / CH;
    f32x2 dx = qx[h] - lxv, dy = qy[h] - lyv, dz = qz[h] - lzv;
    f32x2 t0 = dx * dx, t1 = dy * dy, t2 = dz * dz;
    f32x2 d2 = (t0 + t1) + t2;
    f32x2 dn;
    dn.x = fminf(d[h].x, d2.x);
    dn.y = fminf(d[h].y, d2.y);
    d[h] = dn;
    int i0 = ibase + (2 * h) * 64 + lane;
    if (dn.x > bv[c]) { bv[c] = dn.x; bi[c] = i0; }
    if (dn.y > bv[c]) { bv[c] = dn.y; bi[c] = i0 + 64; }
  }
  unsigned hi, lo;
  if (NCH == 4) {
    unsigned h0 = __float_as_uint(bv[0]), l0 = ~(unsigned)bi[0];
    unsigned h1 = __float_as_uint(bv[1]), l1 = ~(unsigned)bi[1];
    unsigned h2 = __float_as_uint(bv[2]), l2 = ~(unsigned)bi[2];
    unsigned h3 = __float_as_uint(bv[3]), l3 = ~(unsigned)bi[3];
    bool t01 = (h1 > h0) || ((h1 == h0) && (l1 > l0));
    unsigned ha = t01 ? h1 : h0, la = t01 ? l1 : l0;
    bool t23 = (h3 > h2) || ((h3 == h2) && (l3 > l2));
    unsigned hb = t23 ? h3 : h2, lb = t23 ? l3 : l2;
    bool tab = (hb > ha) || ((hb == ha) && (lb > la));
    hi = tab ? hb : ha;
    lo = tab ? lb : la;
  } else {
    const int c1 = (NCH > 1) ? 1 : 0;
    unsigned h0 = __float_as_uint(bv[0]), l0 = ~(unsigned)bi[0];
    unsigned h1 = __float_as_uint(bv[c1]), l1 = ~(unsigned)bi[c1];
    bool t01 = (h1 > h0) || ((h1 == h0) && (l1 > l0));
    hi = t01 ? h1 : h0;
    lo = t01 ? l1 : l0;
  }
  FPS_RED_LEVEL(0x111)  // row_shr:1
  FPS_RED_LEVEL(0x112)  // row_shr:2
  FPS_RED_LEVEL(0x114)  // row_shr:4
  FPS_RED_LEVEL(0x118)  // row_shr:8
  FPS_RED_LEVEL(0x142)  // row_bcast:15
  FPS_RED_LEVEL(0x143)  // row_bcast:31
  return (((unsigned long long)hi) << 32) | lo;  // valid on lane 63
}

// ---------------------------------------------------------------------------
// prep jobs table (weight transposes fused into fps1 launch, 256-granular).
// ---------------------------------------------------------------------------
struct PrepJobs {
  const float* src[9];
  unsigned short* hi[9];
  unsigned short* lo[9];
  int K[9], N[9], rl[9];
  int blk0[10];
};

// ---------------------------------------------------------------------------
// fps1 (blocks 0..15): 2048 -> 1024 centers, 4 waves cooperate per step:
// per-wave update over 512 points, DPP wave-reduce, LDS key exchange (double
// buffered), u64-max fold. blocks 16..: weight prep.
// ---------------------------------------------------------------------------
__global__ __launch_bounds__(256, 1) void fps1_prep_kernel(
    const float* __restrict__ pos, float* __restrict__ p1, PrepJobs jb) {
#pragma clang fp contract(off)
  const int tid = threadIdx.x;
  if (blockIdx.x >= 16) {
    int blk = blockIdx.x - 16;
    int j = 0;
#pragma unroll
    for (int t = 1; t < 9; ++t)
      if (blk >= jb.blk0[t]) j = t;
    int idx = (blk - jb.blk0[j]) * 256 + tid;
    int rl = jb.rl[j], N = jb.N[j], K = jb.K[j];
    if (idx >= N * rl) return;
    int n = idx / rl, k = idx - n * rl;
    float v = (k < K) ? jb.src[j][(size_t)k * N + n] : 0.f;
    unsigned short h, l;
    split_bf(v, h, l);
    jb.hi[j][idx] = h;
    jb.lo[j][idx] = l;
    return;
  }
  const int b = blockIdx.x;
  const int w = tid >> 6, lane = tid & 63;
  __shared__ __align__(16) float4 p4[2048];
  __shared__ __align__(16) float4 carr[1024];
  __shared__ unsigned long long kv[2][4];
  f32x2 qx[4], qy[4], qz[4], d[4];
  const int ibase = w * 512;
#pragma unroll
  for (int h = 0; h < 4; ++h) {
    int i0 = ibase + (2 * h) * 64 + lane, i1 = i0 + 64;
    const float* a = pos + ((size_t)b * 2048 + i0) * 3;
    const float* c = pos + ((size_t)b * 2048 + i1) * 3;
    float x0 = a[0], y0 = a[1], z0 = a[2];
    float x1 = c[0], y1 = c[1], z1 = c[2];
    qx[h].x = x0; qx[h].y = x1;
    qy[h].x = y0; qy[h].y = y1;
    qz[h].x = z0; qz[h].y = z1;
    d[h].x = DEVINF; d[h].y = DEVINF;
    p4[i0] = float4{x0, y0, z0, 0.f};
    p4[i1] = float4{x1, y1, z1, 0.f};
  }
  __syncthreads();
  int last = 0;
  for (int s = 0; s < 1024; ++s) {
    float4 c4 = p4[last];
    if (tid == 0) carr[s] = c4;
    unsigned long long k =
        fps_wave_step<4, 4>(qx, qy, qz, d, c4.x, c4.y, c4.z, lane, ibase);
    if (lane == 63) kv[s & 1][w] = k;
    __syncthreads();
    unsigned long long k0 = kv[s & 1][0], k1 = kv[s & 1][1];
    unsigned long long k2 = kv[s & 1][2], k3 = kv[s & 1][3];
    unsigned long long ka = k0 > k1 ? k0 : k1;
    unsigned long long kb = k2 > k3 ? k2 : k3;
    unsigned long long kk = ka > kb ? ka : kb;
    last = (int)~(unsigned)kk;
  }
  for (int i = tid; i < 1024; i += 256) {
    float4 c = carr[i];
    p1[((size_t)b * 1024 + i) * 3 + 0] = c.x;
    p1[((size_t)b * 1024 + i) * 3 + 1] = c.y;
    p1[((size_t)b * 1024 + i) * 3 + 2] = c.z;
  }
}

// ---------------------------------------------------------------------------
// MFMA building blocks (B fragments loaded once per 12 MFMAs).
// A-frag: lane l -> A[m=l&15][k=ks*32+(l>>4)*8+j]; B from wT[n][k];
// C/D: col=l&15, row=(l>>4)*4+reg.
// ---------------------------------------------------------------------------
template <int KS, int T>
__device__ __forceinline__ void mfma_allm(
    const unsigned short* __restrict__ inHi, const unsigned short* __restrict__ inLo,
    int sIn, const unsigned short* __restrict__ wHi,
    const unsigned short* __restrict__ wLo, int rl, const float* __restrict__ bias,
    int n0, int lane, f32x4 acc[4][T]) {
  const int col = lane & 15, quad = lane >> 4;
#pragma unroll
  for (int t = 0; t < T; ++t) {
    float bv = bias[n0 + t * 16 + col];
#pragma unroll
    for (int mt = 0; mt < 4; ++mt) {
      acc[mt][t].x = bv; acc[mt][t].y = bv; acc[mt][t].z = bv; acc[mt][t].w = bv;
    }
  }
#pragma unroll 1
  for (int ks = 0; ks < KS; ++ks) {
    bf16x8 ah[4], al[4];
#pragma unroll
    for (int mt = 0; mt < 4; ++mt) {
      int aoff = (mt * 16 + col) * sIn + ks * 32 + quad * 8;
      ah[mt] = *(const bf16x8*)(inHi + aoff);
      al[mt] = *(const bf16x8*)(inLo + aoff);
    }
#pragma unroll
    for (int t = 0; t < T; ++t) {
      size_t boff = (size_t)(n0 + t * 16 + col) * rl + ks * 32 + quad * 8;
      bf16x8 bh = *(const bf16x8*)(wHi + boff);
      bf16x8 bl = *(const bf16x8*)(wLo + boff);
#pragma unroll
      for (int mt = 0; mt < 4; ++mt) {
        acc[mt][t] = __builtin_amdgcn_mfma_f32_16x16x32_bf16(ah[mt], bh, acc[mt][t], 0, 0, 0);
        acc[mt][t] = __builtin_amdgcn_mfma_f32_16x16x32_bf16(ah[mt], bl, acc[mt][t], 0, 0, 0);
        acc[mt][t] = __builtin_amdgcn_mfma_f32_16x16x32_bf16(al[mt], bh, acc[mt][t], 0, 0, 0);
      }
    }
  }
}

template <int T>
__device__ __forceinline__ void store_allm(const f32x4 acc[4][T], int n0,
                                           unsigned short* outHi,
                                           unsigned short* outLo, int sOut,
                                           int lane) {
  const int col = lane & 15, quad = lane >> 4;
#pragma unroll
  for (int mt = 0; mt < 4; ++mt)
#pragma unroll
    for (int t = 0; t < T; ++t)
#pragma unroll
      for (int r = 0; r < 4; ++r) {
        int edge = mt * 16 + quad * 4 + r;
        float v = fmaxf(acc[mt][t][r], 0.f);
        unsigned short h, l;
        split_bf(v, h, l);
        outHi[edge * sOut + n0 + t * 16 + col] = h;
        outLo[edge * sOut + n0 + t * 16 + col] = l;
      }
}

template <int T>
__device__ __forceinline__ void outpool_allm(const f32x4 acc[4][T], int n0,
                                             float* __restrict__ outp, int nvalid,
                                             int lane) {
  const int col = lane & 15, quad = lane >> 4;
#pragma unroll
  for (int t = 0; t < T; ++t) {
    float m = -DEVINF;
#pragma unroll
    for (int mt = 0; mt < 4; ++mt)
#pragma unroll
      for (int r = 0; r < 4; ++r) {
        int edge = mt * 16 + quad * 4 + r;
        float v = fmaxf(acc[mt][t][r], 0.f);
        if (edge >= nvalid) v = -DEVINF;
        m = fmaxf(m, v);
      }
    m = fmaxf(m, __shfl_xor(m, 16, 64));
    m = fmaxf(m, __shfl_xor(m, 32, 64));
    if (quad == 0) outp[n0 + t * 16 + col] = m;
  }
}

// single-m-tile variants (gsa)
template <int KS, int T>
__device__ __forceinline__ void mfma_1m(
    const unsigned short* __restrict__ inHi, const unsigned short* __restrict__ inLo,
    int sIn, const unsigned short* __restrict__ wHi,
    const unsigned short* __restrict__ wLo, int rl, const float* __restrict__ bias,
    int n0, int lane, f32x4 acc[T]) {
  const int col = lane & 15, quad = lane >> 4;
#pragma unroll
  for (int t = 0; t < T; ++t) {
    float bv = bias[n0 + t * 16 + col];
    acc[t].x = bv; acc[t].y = bv; acc[t].z = bv; acc[t].w = bv;
  }
#pragma unroll 1
  for (int ks = 0; ks < KS; ++ks) {
    int aoff = col * sIn + ks * 32 + quad * 8;
    bf16x8 ah = *(const bf16x8*)(inHi + aoff);
    bf16x8 al = *(const bf16x8*)(inLo + aoff);
#pragma unroll
    for (int t = 0; t < T; ++t) {
      size_t boff = (size_t)(n0 + t * 16 + col) * rl + ks * 32 + quad * 8;
      bf16x8 bh = *(const bf16x8*)(wHi + boff);
      bf16x8 bl = *(const bf16x8*)(wLo + boff);
      acc[t] = __builtin_amdgcn_mfma_f32_16x16x32_bf16(ah, bh, acc[t], 0, 0, 0);
      acc[t] = __builtin_amdgcn_mfma_f32_16x16x32_bf16(ah, bl, acc[t], 0, 0, 0);
      acc[t] = __builtin_amdgcn_mfma_f32_16x16x32_bf16(al, bh, acc[t], 0, 0, 0);
    }
  }
}

template <int T>
__device__ __forceinline__ void store_1m(const f32x4 acc[T], int n0,
                                         unsigned short* outHi,
                                         unsigned short* outLo, int sOut, int lane) {
  const int col = lane & 15, quad = lane >> 4;
#pragma unroll
  for (int t = 0; t < T; ++t)
#pragma unroll
    for (int r = 0; r < 4; ++r) {
      int p = quad * 4 + r;
      float v = fmaxf(acc[t][r], 0.f);
      unsigned short h, l;
      split_bf(v, h, l);
      outHi[p * sOut + n0 + t * 16 + col] = h;
      outLo[p * sOut + n0 + t * 16 + col] = l;
    }
}

// ---------------------------------------------------------------------------
// SA1 (MFMA, wave=n-slice) + EMBEDDED fps2 (blocks 0..15, now 4-wave).
// ---------------------------------------------------------------------------
__global__ __launch_bounds__(256, 4) void sa1_kernel(
    const float* __restrict__ x,    // [16][2048][9]
    const float* __restrict__ pos,  // [16][2048][3]
    const float* __restrict__ ctr,  // p1: [16][1024][3]
    float* __restrict__ p2,         // [16][256][3] (fps2 output)
    const unsigned short* __restrict__ w1h, const unsigned short* __restrict__ w1l,
    const unsigned short* __restrict__ w2h, const unsigned short* __restrict__ w2l,
    const unsigned short* __restrict__ w3h, const unsigned short* __restrict__ w3l,
    const float* __restrict__ b1, const float* __restrict__ b2,
    const float* __restrict__ b3,
    float* __restrict__ out)        // [16][1024][128]
{
  const int N = 2048;
  const float r2 = (float)(0.2 * 0.2);
  const int tid = threadIdx.x;
  const int w = tid >> 6, lane = tid & 63;
  __shared__ __align__(16) unsigned short smem[4 * 4608];  // 36,864 B
  unsigned short* bufA_hi = smem;
  unsigned short* bufA_lo = smem + 4608;
  unsigned short* bufB_hi = smem + 9216;
  unsigned short* bufB_lo = smem + 13824;
  __shared__ int nb[64];
  __shared__ unsigned long long mq[32];
  __shared__ unsigned long long kv2[2][4];

  if (blockIdx.x < 16) {
    // ------------- fps2: 1024 -> 256 centers, 4-wave cooperative -------------
    const int bb = blockIdx.x;
    float4* q4 = (float4*)smem;              // 16 KB
    float4* carr = (float4*)(smem + 8192);   // u16 units: byte offset 16384; 4 KB
    for (int i = tid; i < 1024; i += 256) {
      const float* pr = ctr + ((size_t)bb * 1024 + i) * 3;
      q4[i] = float4{pr[0], pr[1], pr[2], 0.f};
    }
    __syncthreads();
    f32x2 qx[2], qy[2], qz[2], d[2];
    const int ibase = w * 256;
#pragma unroll
    for (int h = 0; h < 2; ++h) {
      int i0 = ibase + (2 * h) * 64 + lane, i1 = i0 + 64;
      float4 a = q4[i0], c = q4[i1];
      qx[h].x = a.x; qx[h].y = c.x;
      qy[h].x = a.y; qy[h].y = c.y;
      qz[h].x = a.z; qz[h].y = c.z;
      d[h].x = DEVINF; d[h].y = DEVINF;
    }
    int last = 0;
    for (int s = 0; s < 256; ++s) {
      float4 c4 = q4[last];
      if (tid == 0) carr[s] = c4;
      unsigned long long k =
          fps_wave_step<2, 2>(qx, qy, qz, d, c4.x, c4.y, c4.z, lane, ibase);
      if (lane == 63) kv2[s & 1][w] = k;
      __syncthreads();
      unsigned long long k0 = kv2[s & 1][0], k1 = kv2[s & 1][1];
      unsigned long long k2 = kv2[s & 1][2], k3 = kv2[s & 1][3];
      unsigned long long ka = k0 > k1 ? k0 : k1;
      unsigned long long kb = k2 > k3 ? k2 : k3;
      unsigned long long kk = ka > kb ? ka : kb;
      last = (int)~(unsigned)kk;
    }
    {
      float4 c = carr[tid];
      p2[((size_t)bb * 256 + tid) * 3 + 0] = c.x;
      p2[((size_t)bb * 256 + tid) * 3 + 1] = c.y;
      p2[((size_t)bb * 256 + tid) * 3 + 2] = c.z;
    }
    return;
  }

  const int bs = blockIdx.x - 16;
  const int b = bs >> 10;
  const float cx = ctr[bs * 3 + 0], cy = ctr[bs * 3 + 1], cz = ctr[bs * 3 + 2];
  // ---- ball query: masks in parallel (each wave 8 of 32 groups) ----
  nb[lane] = 0;
  {
#pragma clang fp contract(off)
#pragma unroll
    for (int it = 0; it < 8; ++it) {
      int g = w * 8 + it;
      int i = g * 64 + lane;
      const float* p = pos + ((size_t)b * N + i) * 3;
      float dx = p[0] - cx, dy = p[1] - cy, dz = p[2] - cz;
      float t0 = dx * dx, t1 = dy * dy, t2 = dz * dz;
      float d2 = (t0 + t1) + t2;
      unsigned long long m = __ballot(d2 <= r2);
      if (lane == 0) mq[g] = m;
    }
  }
  __syncthreads();
  // ---- extraction (redundant per wave; identical values, benign races) ----
  int cnt = 0;
#pragma unroll 1
  for (int g = 0; g < 32; ++g) {
    unsigned long long m = mq[g];
    bool inr = (m >> lane) & 1;
    int posn = cnt + (int)__popcll(m & ((1ull << lane) - 1ull));
    if (inr && posn < 64) nb[posn] = g * 64 + lane;
    cnt += (int)__popcll(m);
    if (cnt >= 64) break;
  }
  const int nvalid = cnt < 64 ? cnt : 64;
  if (w == 0) {
    int j = nb[lane];
    const float* xr = x + ((size_t)b * N + j) * 9;
    const float* pr = pos + ((size_t)b * N + j) * 3;
    float f[12];
#pragma unroll
    for (int k = 0; k < 9; ++k) f[k] = xr[k];
    f[9] = pr[0] - cx; f[10] = pr[1] - cy; f[11] = pr[2] - cz;
#pragma unroll
    for (int k = 0; k < 12; ++k) {
      unsigned short h, l;
      split_bf(f[k], h, l);
      bufA_hi[lane * 72 + k] = h;
      bufA_lo[lane * 72 + k] = l;
    }
  } else if (w == 1) {
#pragma unroll
    for (int k = 12; k < 32; ++k) {
      bufA_hi[lane * 72 + k] = 0;
      bufA_lo[lane * 72 + k] = 0;
    }
  }
  __syncthreads();
  {  // L1: K=32(12), N=64; wave n-slice [w*16, w*16+16)
    f32x4 acc[4][1];
    mfma_allm<1, 1>(bufA_hi, bufA_lo, 72, w1h, w1l, 40, b1, w * 16, lane, acc);
    store_allm<1>(acc, w * 16, bufB_hi, bufB_lo, 72, lane);
  }
  __syncthreads();
  {  // L2: K=64, N=64; reads B, writes A
    f32x4 acc[4][1];
    mfma_allm<2, 1>(bufB_hi, bufB_lo, 72, w2h, w2l, 72, b2, w * 16, lane, acc);
    store_allm<1>(acc, w * 16, bufA_hi, bufA_lo, 72, lane);
  }
  __syncthreads();
  {  // L3: K=64, N=128; wave n-slice [w*32, w*32+32) + pool
    f32x4 acc[4][2];
    mfma_allm<2, 2>(bufA_hi, bufA_lo, 72, w3h, w3l, 72, b3, w * 32, lane, acc);
    outpool_allm<2>(acc, w * 32, out + (size_t)bs * 128, nvalid, lane);
  }
}

// ---------------------------------------------------------------------------
// SA2 (MFMA, wave=n-slice): parallel-mask ball query + MLP + maxpool.
// ---------------------------------------------------------------------------
__global__ __launch_bounds__(256, 2) void sa2_kernel(
    const float* __restrict__ x1,   // [16][1024][128]
    const float* __restrict__ pos1, // [16][1024][3]
    const float* __restrict__ ctr,  // [16][256][3]
    const unsigned short* __restrict__ w1h, const unsigned short* __restrict__ w1l,
    const unsigned short* __restrict__ w2h, const unsigned short* __restrict__ w2l,
    const unsigned short* __restrict__ w3h, const unsigned short* __restrict__ w3l,
    const float* __restrict__ b1, const float* __restrict__ b2,
    const float* __restrict__ b3,
    float* __restrict__ out)        // [16][256][256]
{
  const int N = 1024;
  const float r2 = (float)(0.4 * 0.4);
  const int bs = blockIdx.x;
  const int b = bs >> 8;
  const int tid = threadIdx.x;
  const int w = tid >> 6, lane = tid & 63;
  const float cx = ctr[bs * 3 + 0], cy = ctr[bs * 3 + 1], cz = ctr[bs * 3 + 2];
  __shared__ __align__(16) unsigned short bufA_hi[64 * 168], bufA_lo[64 * 168];
  __shared__ __align__(16) unsigned short bufB_hi[64 * 136], bufB_lo[64 * 136];
  __shared__ int nb[64];
  __shared__ unsigned long long mq[16];
  nb[lane] = 0;
  {
#pragma clang fp contract(off)
#pragma unroll
    for (int it = 0; it < 4; ++it) {
      int g = w * 4 + it;
      int i = g * 64 + lane;
      const float* p = pos1 + ((size_t)b * N + i) * 3;
      float dx = p[0] - cx, dy = p[1] - cy, dz = p[2] - cz;
      float t0 = dx * dx, t1 = dy * dy, t2 = dz * dz;
      float d2 = (t0 + t1) + t2;
      unsigned long long m = __ballot(d2 <= r2);
      if (lane == 0) mq[g] = m;
    }
  }
  __syncthreads();
  int cnt = 0;
#pragma unroll 1
  for (int g = 0; g < 16; ++g) {
    unsigned long long m = mq[g];
    bool inr = (m >> lane) & 1;
    int posn = cnt + (int)__popcll(m & ((1ull << lane) - 1ull));
    if (inr && posn < 64) nb[posn] = g * 64 + lane;
    cnt += (int)__popcll(m);
    if (cnt >= 64) break;
  }
  const int nvalid = cnt < 64 ? cnt : 64;
  {  // stage features: quarter w loads k in [32w, 32w+32); w0 also rel+pad
    int j = nb[lane];
    const float* xr = x1 + ((size_t)b * N + j) * 128 + 32 * w;
#pragma unroll
    for (int g = 0; g < 8; ++g) {
      float4 v = *(const float4*)(xr + 4 * g);
      float vv[4] = {v.x, v.y, v.z, v.w};
#pragma unroll
      for (int e = 0; e < 4; ++e) {
        unsigned short h, l;
        split_bf(vv[e], h, l);
        int k = 32 * w + 4 * g + e;
        bufA_hi[lane * 168 + k] = h;
        bufA_lo[lane * 168 + k] = l;
      }
    }
    if (w == 0) {
      const float* pr = pos1 + ((size_t)b * N + j) * 3;
      float rr[3] = {pr[0] - cx, pr[1] - cy, pr[2] - cz};
#pragma unroll
      for (int c = 0; c < 3; ++c) {
        unsigned short h, l;
        split_bf(rr[c], h, l);
        bufA_hi[lane * 168 + 128 + c] = h;
        bufA_lo[lane * 168 + 128 + c] = l;
      }
#pragma unroll
      for (int k = 131; k < 160; ++k) {
        bufA_hi[lane * 168 + k] = 0;
        bufA_lo[lane * 168 + k] = 0;
      }
    }
  }
  __syncthreads();
  {  // L1: K=160(131), N=128; n-slice [w*32, w*32+32)
    f32x4 acc[4][2];
    mfma_allm<5, 2>(bufA_hi, bufA_lo, 168, w1h, w1l, 168, b1, w * 32, lane, acc);
    store_allm<2>(acc, w * 32, bufB_hi, bufB_lo, 136, lane);
  }
  __syncthreads();
  {  // L2: K=128, N=128; reads B, writes A
    f32x4 acc[4][2];
    mfma_allm<4, 2>(bufB_hi, bufB_lo, 136, w2h, w2l, 136, b2, w * 32, lane, acc);
    store_allm<2>(acc, w * 32, bufA_hi, bufA_lo, 168, lane);
  }
  __syncthreads();
  {  // L3: K=128, N=256; n-slice [w*64, w*64+64) + pool
    f32x4 acc[4][4];
    mfma_allm<4, 4>(bufA_hi, bufA_lo, 168, w3h, w3l, 136, b3, w * 64, lane, acc);
    outpool_allm<4>(acc, w * 64, out + (size_t)bs * 256, nvalid, lane);
  }
}

// ---------------------------------------------------------------------------
// Global SA (MFMA): MLP 259->256->512->1024, 16 points/block, wave=n-quarter.
// ---------------------------------------------------------------------------
__global__ __launch_bounds__(256, 2) void gsa_kernel(
    const float* __restrict__ x2,  // [16][256][256]
    const float* __restrict__ p2,  // [16][256][3]
    const unsigned short* __restrict__ g1h, const unsigned short* __restrict__ g1l,
    const unsigned short* __restrict__ g2h, const unsigned short* __restrict__ g2l,
    const unsigned short* __restrict__ g3h, const unsigned short* __restrict__ g3l,
    const float* __restrict__ b1, const float* __restrict__ b2,
    const float* __restrict__ b3,
    float* __restrict__ part)      // [16][16][1024]
{
  const int blk = blockIdx.x;  // 256
  const int bt = blk >> 4, gidx = blk & 15;
  const int tid = threadIdx.x;
  const int w = tid >> 6, lane = tid & 63;
  const int p0 = gidx * 16;
  __shared__ __align__(16) unsigned short inH[16 * 296], inL[16 * 296];
  __shared__ __align__(16) unsigned short h1H[16 * 264], h1L[16 * 264];
  __shared__ __align__(16) unsigned short h2H[16 * 520], h2L[16 * 520];
  {  // stage 16 points x 256 feats + 3 pos + zero pad to 288
    int p = tid >> 4, seg = tid & 15;
    const float* xr = x2 + ((size_t)(bt * 256 + p0 + p)) * 256 + seg * 16;
#pragma unroll
    for (int g = 0; g < 4; ++g) {
      float4 v = *(const float4*)(xr + 4 * g);
      float vv[4] = {v.x, v.y, v.z, v.w};
#pragma unroll
      for (int e = 0; e < 4; ++e) {
        unsigned short h, l;
        split_bf(vv[e], h, l);
        int k = seg * 16 + 4 * g + e;
        inH[p * 296 + k] = h;
        inL[p * 296 + k] = l;
      }
    }
    if (tid < 16) {
      const float* pr = p2 + (bt * 256 + p0 + tid) * 3;
#pragma unroll
      for (int c = 0; c < 3; ++c) {
        unsigned short h, l;
        split_bf(pr[c], h, l);
        inH[tid * 296 + 256 + c] = h;
        inL[tid * 296 + 256 + c] = l;
      }
      for (int k = 259; k < 288; ++k) {
        inH[tid * 296 + k] = 0;
        inL[tid * 296 + k] = 0;
      }
    }
  }
  __syncthreads();
  {  // L1: K=288(259), N=256
    f32x4 acc[4];
    mfma_1m<9, 4>(inH, inL, 296, g1h, g1l, 296, b1, w * 64, lane, acc);
    store_1m<4>(acc, w * 64, h1H, h1L, 264, lane);
  }
  __syncthreads();
  {  // L2: K=256, N=512
    f32x4 acc[8];
    mfma_1m<8, 8>(h1H, h1L, 264, g2h, g2l, 264, b2, w * 128, lane, acc);
    store_1m<8>(acc, w * 128, h2H, h2L, 520, lane);
  }
  __syncthreads();
  {  // L3: K=512, N=1024 + max over 16 points
    f32x4 acc[16];
    mfma_1m<16, 16>(h2H, h2L, 520, g3h, g3l, 520, b3, w * 256, lane, acc);
    const int col = lane & 15;
    float* op = part + ((size_t)(bt * 16 + gidx)) * 1024 + w * 256;
#pragma unroll
    for (int t = 0; t < 16; ++t) {
      float m = -DEVINF;
#pragma unroll
      for (int r = 0; r < 4; ++r) m = fmaxf(m, fmaxf(acc[t][r], 0.f));
      m = fmaxf(m, __shfl_xor(m, 16, 64));
      m = fmaxf(m, __shfl_xor(m, 32, 64));
      if ((lane >> 4) == 0) op[t * 16 + col] = m;
    }
  }
}

// ---------------------------------------------------------------------------
// head1: gmax + l1 + l2 + l3. One block per B-row (16 blocks).
// ---------------------------------------------------------------------------
__global__ __launch_bounds__(256) void head1_kernel(
    const float* __restrict__ part,  // [16][16][1024]
    const float* __restrict__ l1w, const float* __restrict__ l1b,
    const float* __restrict__ l2w, const float* __restrict__ l2b,
    const float* __restrict__ l3w, const float* __restrict__ l3b,
    float* __restrict__ hC)          // [16][256]
{
  const int m = blockIdx.x;
  const int tid = threadIdx.x;
  __shared__ float gA[1024];
  __shared__ float hX[512];
  __shared__ float hY[256];
#pragma unroll
  for (int j = 0; j < 4; ++j) {
    int c = j * 256 + tid;
    float mx = -DEVINF;
#pragma unroll
    for (int t = 0; t < 16; ++t)
      mx = fmaxf(mx, part[((size_t)(m * 16 + t)) * 1024 + c]);
    gA[c] = mx;
  }
  __syncthreads();
  {  // l1: 1024 -> 512, relu
    float a0 = l1b[tid], a1 = l1b[tid + 256];
#pragma unroll 4
    for (int k = 0; k < 1024; ++k) {
      float v = gA[k];
      a0 = fmaf(v, l1w[(size_t)k * 512 + tid], a0);
      a1 = fmaf(v, l1w[(size_t)k * 512 + tid + 256], a1);
    }
    hX[tid] = fmaxf(a0, 0.f);
    hX[tid + 256] = fmaxf(a1, 0.f);
  }
  __syncthreads();
  {  // l2: 512 -> 256, relu
    float a = l2b[tid];
#pragma unroll 4
    for (int k = 0; k < 512; ++k) a = fmaf(hX[k], l2w[(size_t)k * 256 + tid], a);
    hY[tid] = fmaxf(a, 0.f);
  }
  __syncthreads();
  {  // l3: 256 -> 256, no relu
    float a = l3b[tid];
#pragma unroll 4
    for (int k = 0; k < 256; ++k) a = fmaf(hY[k], l3w[(size_t)k * 256 + tid], a);
    hC[(size_t)m * 256 + tid] = a;
  }
}

// ---------------------------------------------------------------------------
// head2: fusion MLP (fw1,fw2,fw3) + l4 + l5. One block per fused row (4).
// ---------------------------------------------------------------------------
__global__ __launch_bounds__(256) void head2_kernel(
    const float* __restrict__ hC,  // [4][1024]
    const float* __restrict__ fw1, const float* __restrict__ fb1,
    const float* __restrict__ fw2, const float* __restrict__ fb2,
    const float* __restrict__ fw3, const float* __restrict__ fb3,
    const float* __restrict__ l4w, const float* __restrict__ l4b,
    const float* __restrict__ l5w, const float* __restrict__ l5b,
    float* __restrict__ out)       // [4][128]
{
  const int m = blockIdx.x;
  const int tid = threadIdx.x;
  __shared__ float A[1024];
  __shared__ float Bf[512];
#pragma unroll
  for (int j = 0; j < 4; ++j) A[j * 256 + tid] = hC[(size_t)m * 1024 + j * 256 + tid];
  __syncthreads();
  {  // fw1: 1024 -> 512 relu, A -> Bf
    float a0 = fb1[tid], a1 = fb1[tid + 256];
#pragma unroll 4
    for (int k = 0; k < 1024; ++k) {
      float v = A[k];
      a0 = fmaf(v, fw1[(size_t)k * 512 + tid], a0);
      a1 = fmaf(v, fw1[(size_t)k * 512 + tid + 256], a1);
    }
    Bf[tid] = fmaxf(a0, 0.f);
    Bf[tid + 256] = fmaxf(a1, 0.f);
  }
  __syncthreads();
  {  // fw2: 512 -> 512 relu, Bf -> A
    float a0 = fb2[tid], a1 = fb2[tid + 256];
#pragma unroll 4
    for (int k = 0; k < 512; ++k) {
      float v = Bf[k];
      a0 = fmaf(v, fw2[(size_t)k * 512 + tid], a0);
      a1 = fmaf(v, fw2[(size_t)k * 512 + tid + 256], a1);
    }
    __syncthreads();
    A[tid] = fmaxf(a0, 0.f);
    A[tid + 256] = fmaxf(a1, 0.f);
  }
  __syncthreads();
  {  // fw3: 512 -> 256 relu, A -> Bf
    float a = fb3[tid];
#pragma unroll 4
    for (int k = 0; k < 512; ++k) a = fmaf(A[k], fw3[(size_t)k * 256 + tid], a);
    __syncthreads();
    Bf[tid] = fmaxf(a, 0.f);
  }
  __syncthreads();
  {  // l4: 256 -> 128 relu, Bf -> A
    if (tid < 128) {
      float a = l4b[tid];
#pragma unroll 4
      for (int k = 0; k < 256; ++k) a = fmaf(Bf[k], l4w[(size_t)k * 128 + tid], a);
      A[tid] = fmaxf(a, 0.f);
    }
  }
  __syncthreads();
  {  // l5: 128 -> 128, A -> out
    if (tid < 128) {
      float a = l5b[tid];
#pragma unroll 4
      for (int k = 0; k < 128; ++k) a = fmaf(A[k], l5w[(size_t)k * 128 + tid], a);
      out[(size_t)m * 128 + tid] = a;
    }
  }
}

// ---------------------------------------------------------------------------
extern "C" void kernel_launch(void* const* d_in, const int* in_sizes, int n_in,
                              void* d_out, int out_size, void* d_ws, size_t ws_size,
                              hipStream_t stream) {
  (void)in_sizes; (void)n_in; (void)out_size; (void)ws_size;
  const float* x    = (const float*)d_in[0];
  const float* pos  = (const float*)d_in[1];
  const float* s1w1 = (const float*)d_in[2];  const float* s1b1 = (const float*)d_in[3];
  const float* s1w2 = (const float*)d_in[4];  const float* s1b2 = (const float*)d_in[5];
  const float* s1w3 = (const float*)d_in[6];  const float* s1b3 = (const float*)d_in[7];
  const float* s2w1 = (const float*)d_in[8];  const float* s2b1 = (const float*)d_in[9];
  const float* s2w2 = (const float*)d_in[10]; const float* s2b2 = (const float*)d_in[11];
  const float* s2w3 = (const float*)d_in[12]; const float* s2b3 = (const float*)d_in[13];
  const float* s3w1 = (const float*)d_in[14]; const float* s3b1 = (const float*)d_in[15];
  const float* s3w2 = (const float*)d_in[16]; const float* s3b2 = (const float*)d_in[17];
  const float* s3w3 = (const float*)d_in[18]; const float* s3b3 = (const float*)d_in[19];
  const float* fw1  = (const float*)d_in[20]; const float* fb1  = (const float*)d_in[21];
  const float* fw2  = (const float*)d_in[22]; const float* fb2  = (const float*)d_in[23];
  const float* fw3  = (const float*)d_in[24]; const float* fb3  = (const float*)d_in[25];
  const float* l1w  = (const float*)d_in[26]; const float* l1b  = (const float*)d_in[27];
  const float* l2w  = (const float*)d_in[28]; const float* l2b  = (const float*)d_in[29];
  const float* l3w  = (const float*)d_in[30]; const float* l3b  = (const float*)d_in[31];
  const float* l4w  = (const float*)d_in[32]; const float* l4b  = (const float*)d_in[33];
  const float* l5w  = (const float*)d_in[34]; const float* l5b  = (const float*)d_in[35];
  float* out = (float*)d_out;

  float* ws = (float*)d_ws;
  float* p1   = ws;                  // 16*1024*3
  float* x1   = p1 + 49152;          // 16*1024*128
  float* p2   = x1 + 2097152;        // 16*256*3
  float* x2   = p2 + 12288;          // 16*256*256
  float* part = x2 + 1048576;        // 16*16*1024
  float* hC   = part + 262144;       // 16*256
  // bf16 hi/lo transposed weight planes (u16)
  unsigned short* wp = (unsigned short*)(hC + 4096);
  unsigned short* s1w1h = wp;              unsigned short* s1w1l = s1w1h + 2560;    // [64][40]
  unsigned short* s1w2h = s1w1l + 2560;    unsigned short* s1w2l = s1w2h + 4608;    // [64][72]
  unsigned short* s1w3h = s1w2l + 4608;    unsigned short* s1w3l = s1w3h + 9216;    // [128][72]
  unsigned short* s2w1h = s1w3l + 9216;    unsigned short* s2w1l = s2w1h + 21504;   // [128][168]
  unsigned short* s2w2h = s2w1l + 21504;   unsigned short* s2w2l = s2w2h + 17408;   // [128][136]
  unsigned short* s2w3h = s2w2l + 17408;   unsigned short* s2w3l = s2w3h + 34816;   // [256][136]
  unsigned short* g1h   = s2w3l + 34816;   unsigned short* g1l   = g1h + 75776;     // [256][296]
  unsigned short* g2h   = g1l + 75776;     unsigned short* g2l   = g2h + 135168;    // [512][264]
  unsigned short* g3h   = g2l + 135168;    unsigned short* g3l   = g3h + 532480;    // [1024][520]

  PrepJobs jb;
  const float* srcs[9] = {s1w1, s1w2, s1w3, s2w1, s2w2, s2w3, s3w1, s3w2, s3w3};
  unsigned short* his[9] = {s1w1h, s1w2h, s1w3h, s2w1h, s2w2h, s2w3h, g1h, g2h, g3h};
  unsigned short* los[9] = {s1w1l, s1w2l, s1w3l, s2w1l, s2w2l, s2w3l, g1l, g2l, g3l};
  int Ks[9]  = {12, 64, 64, 131, 128, 128, 259, 256, 512};
  int Ns[9]  = {64, 64, 128, 128, 128, 256, 256, 512, 1024};
  int rls[9] = {40, 72, 72, 168, 136, 136, 296, 264, 520};
  int acc_blk = 0;
  for (int j = 0; j < 9; ++j) {
    jb.src[j] = srcs[j]; jb.hi[j] = his[j]; jb.lo[j] = los[j];
    jb.K[j] = Ks[j]; jb.N[j] = Ns[j]; jb.rl[j] = rls[j];
    jb.blk0[j] = acc_blk;
    acc_blk += (Ns[j] * rls[j] + 255) / 256;   // 256-thread granularity
  }
  jb.blk0[9] = acc_blk;

  fps1_prep_kernel<<<16 + acc_blk, 256, 0, stream>>>(pos, p1, jb);
  sa1_kernel<<<16 * 1024 + 16, 256, 0, stream>>>(x, pos, p1, p2, s1w1h, s1w1l,
                                                 s1w2h, s1w2l, s1w3h, s1w3l,
                                                 s1b1, s1b2, s1b3, x1);
  sa2_kernel<<<16 * 256, 256, 0, stream>>>(x1, p1, p2, s2w1h, s2w1l, s2w2h,
                                           s2w2l, s2w3h, s2w3l, s2b1, s2b2,
                                           s2b3, x2);
  gsa_kernel<<<256, 256, 0, stream>>>(x2, p2, g1h, g1l, g2h, g2l, g3h, g3l,
                                      s3b1, s3b2, s3b3, part);
  head1_kernel<<<16, 256, 0, stream>>>(part, l1w, l1b, l2w, l2b, l3w, l3b, hC);
  head2_kernel<<<4, 256, 0, stream>>>(hC, fw1, fb1, fw2, fb2, fw3, fb3, l4w,
                                      l4b, l5w, l5b, out);
}

// Round 9
// 1411.976 us; speedup vs baseline: 4.4536x; 1.0478x over previous
//
#include <hip/hip_runtime.h>
#include <cstddef>

#define DEVINF __builtin_inff()

typedef __attribute__((ext_vector_type(8))) short bf16x8;
typedef __attribute__((ext_vector_type(4))) float f32x4;
typedef __attribute__((ext_vector_type(2))) float f32x2;

__device__ __forceinline__ unsigned short f2bf(float x) {
  unsigned u = __float_as_uint(x);
  return (unsigned short)((u + 0x7fff + ((u >> 16) & 1)) >> 16);
}
__device__ __forceinline__ float bf2f(unsigned short h) {
  return __uint_as_float(((unsigned)h) << 16);
}
__device__ __forceinline__ void split_bf(float x, unsigned short& hi, unsigned short& lo) {
  hi = f2bf(x);
  lo = f2bf(x - bf2f(hi));
}

// ---------------------------------------------------------------------------
// FPS cooperative step: each wave updates its own point range (PPLH f32x2 per
// lane), reduces to a per-wave winner key via DPP; caller exchanges 4 keys
// through LDS. Key = (val_bits<<32)|~idx: u64 max == (max val, lowest idx)
// == numpy first-max (distances >= 0 so bit-ordering is valid).
// ---------------------------------------------------------------------------
#define FPS_RED_LEVEL(CTRL)                                                      \
  {                                                                              \
    int th = __builtin_amdgcn_update_dpp((int)hi, (int)hi, CTRL, 0xf, 0xf, false); \
    int tl = __builtin_amdgcn_update_dpp((int)lo, (int)lo, CTRL, 0xf, 0xf, false); \
    bool take = ((unsigned)th > hi) || (((unsigned)th == hi) && ((unsigned)tl > lo)); \
    hi = take ? (unsigned)th : hi;                                               \
    lo = take ? (unsigned)tl : lo;                                               \
  }

template <int PPLH, int NCH>
__device__ __forceinline__ unsigned long long fps_wave_step(
    f32x2* qx, f32x2* qy, f32x2* qz, f32x2* d, float lx, float ly, float lz,
    int lane, int ibase) {
#pragma clang fp contract(off)
  const int CH = PPLH / NCH;
  float bv[NCH];
  int bi[NCH];
#pragma unroll
  for (int c = 0; c < NCH; ++c) { bv[c] = -DEVINF; bi[c] = 0x7fffffff; }
  f32x2 lxv = {lx, lx}, lyv = {ly, ly}, lzv = {lz, lz};
#pragma unroll
  for (int h = 0; h < PPLH; ++h) {
    const int c = h / CH;
    f32x2 dx = qx[h] - lxv, dy = qy[h] - lyv, dz = qz[h] - lzv;
    f32x2 t0 = dx * dx, t1 = dy * dy, t2 = dz * dz;
    f32x2 d2 = (t0 + t1) + t2;
    f32x2 dn;
    dn.x = fminf(d[h].x, d2.x);
    dn.y = fminf(d[h].y, d2.y);
    d[h] = dn;
    int i0 = ibase + (2 * h) * 64 + lane;
    if (dn.x > bv[c]) { bv[c] = dn.x; bi[c] = i0; }
    if (dn.y > bv[c]) { bv[c] = dn.y; bi[c] = i0 + 64; }
  }
  unsigned hi, lo;
  if (NCH == 4) {
    unsigned h0 = __float_as_uint(bv[0]), l0 = ~(unsigned)bi[0];
    unsigned h1 = __float_as_uint(bv[1]), l1 = ~(unsigned)bi[1];
    unsigned h2 = __float_as_uint(bv[2]), l2 = ~(unsigned)bi[2];
    unsigned h3 = __float_as_uint(bv[3]), l3 = ~(unsigned)bi[3];
    bool t01 = (h1 > h0) || ((h1 == h0) && (l1 > l0));
    unsigned ha = t01 ? h1 : h0, la = t01 ? l1 : l0;
    bool t23 = (h3 > h2) || ((h3 == h2) && (l3 > l2));
    unsigned hb = t23 ? h3 : h2, lb = t23 ? l3 : l2;
    bool tab = (hb > ha) || ((hb == ha) && (lb > la));
    hi = tab ? hb : ha;
    lo = tab ? lb : la;
  } else {
    const int c1 = (NCH > 1) ? 1 : 0;
    unsigned h0 = __float_as_uint(bv[0]), l0 = ~(unsigned)bi[0];
    unsigned h1 = __float_as_uint(bv[c1]), l1 = ~(unsigned)bi[c1];
    bool t01 = (h1 > h0) || ((h1 == h0) && (l1 > l0));
    hi = t01 ? h1 : h0;
    lo = t01 ? l1 : l0;
  }
  FPS_RED_LEVEL(0x111)  // row_shr:1
  FPS_RED_LEVEL(0x112)  // row_shr:2
  FPS_RED_LEVEL(0x114)  // row_shr:4
  FPS_RED_LEVEL(0x118)  // row_shr:8
  FPS_RED_LEVEL(0x142)  // row_bcast:15
  FPS_RED_LEVEL(0x143)  // row_bcast:31
  return (((unsigned long long)hi) << 32) | lo;  // valid on lane 63
}

// ---------------------------------------------------------------------------
// prep jobs table (weight transposes fused into fps1 launch, 256-granular).
// ---------------------------------------------------------------------------
struct PrepJobs {
  const float* src[9];
  unsigned short* hi[9];
  unsigned short* lo[9];
  int K[9], N[9], rl[9];
  int blk0[10];
};

// ---------------------------------------------------------------------------
// fps1 (blocks 0..15): 2048 -> 1024 centers, 4 waves cooperate per step.
// blocks 16..: weight prep.
// ---------------------------------------------------------------------------
__global__ __launch_bounds__(256, 1) void fps1_prep_kernel(
    const float* __restrict__ pos, float* __restrict__ p1, PrepJobs jb) {
#pragma clang fp contract(off)
  const int tid = threadIdx.x;
  if (blockIdx.x >= 16) {
    int blk = blockIdx.x - 16;
    int j = 0;
#pragma unroll
    for (int t = 1; t < 9; ++t)
      if (blk >= jb.blk0[t]) j = t;
    int idx = (blk - jb.blk0[j]) * 256 + tid;
    int rl = jb.rl[j], N = jb.N[j], K = jb.K[j];
    if (idx >= N * rl) return;
    int n = idx / rl, k = idx - n * rl;
    float v = (k < K) ? jb.src[j][(size_t)k * N + n] : 0.f;
    unsigned short h, l;
    split_bf(v, h, l);
    jb.hi[j][idx] = h;
    jb.lo[j][idx] = l;
    return;
  }
  const int b = blockIdx.x;
  const int w = tid >> 6, lane = tid & 63;
  __shared__ __align__(16) float4 p4[2048];
  __shared__ __align__(16) float4 carr[1024];
  __shared__ unsigned long long kv[2][4];
  f32x2 qx[4], qy[4], qz[4], d[4];
  const int ibase = w * 512;
#pragma unroll
  for (int h = 0; h < 4; ++h) {
    int i0 = ibase + (2 * h) * 64 + lane, i1 = i0 + 64;
    const float* a = pos + ((size_t)b * 2048 + i0) * 3;
    const float* c = pos + ((size_t)b * 2048 + i1) * 3;
    float x0 = a[0], y0 = a[1], z0 = a[2];
    float x1 = c[0], y1 = c[1], z1 = c[2];
    qx[h].x = x0; qx[h].y = x1;
    qy[h].x = y0; qy[h].y = y1;
    qz[h].x = z0; qz[h].y = z1;
    d[h].x = DEVINF; d[h].y = DEVINF;
    p4[i0] = float4{x0, y0, z0, 0.f};
    p4[i1] = float4{x1, y1, z1, 0.f};
  }
  __syncthreads();
  int last = 0;
  for (int s = 0; s < 1024; ++s) {
    float4 c4 = p4[last];
    if (tid == 0) carr[s] = c4;
    unsigned long long k =
        fps_wave_step<4, 4>(qx, qy, qz, d, c4.x, c4.y, c4.z, lane, ibase);
    if (lane == 63) kv[s & 1][w] = k;
    __syncthreads();
    unsigned long long k0 = kv[s & 1][0], k1 = kv[s & 1][1];
    unsigned long long k2 = kv[s & 1][2], k3 = kv[s & 1][3];
    unsigned long long ka = k0 > k1 ? k0 : k1;
    unsigned long long kb = k2 > k3 ? k2 : k3;
    unsigned long long kk = ka > kb ? ka : kb;
    last = (int)~(unsigned)kk;
  }
  for (int i = tid; i < 1024; i += 256) {
    float4 c = carr[i];
    p1[((size_t)b * 1024 + i) * 3 + 0] = c.x;
    p1[((size_t)b * 1024 + i) * 3 + 1] = c.y;
    p1[((size_t)b * 1024 + i) * 3 + 2] = c.z;
  }
}

// ---------------------------------------------------------------------------
// MFMA building blocks (B fragments loaded once per 12 MFMAs).
// ---------------------------------------------------------------------------
template <int KS, int T>
__device__ __forceinline__ void mfma_allm(
    const unsigned short* __restrict__ inHi, const unsigned short* __restrict__ inLo,
    int sIn, const unsigned short* __restrict__ wHi,
    const unsigned short* __restrict__ wLo, int rl, const float* __restrict__ bias,
    int n0, int lane, f32x4 acc[4][T]) {
  const int col = lane & 15, quad = lane >> 4;
#pragma unroll
  for (int t = 0; t < T; ++t) {
    float bv = bias[n0 + t * 16 + col];
#pragma unroll
    for (int mt = 0; mt < 4; ++mt) {
      acc[mt][t].x = bv; acc[mt][t].y = bv; acc[mt][t].z = bv; acc[mt][t].w = bv;
    }
  }
#pragma unroll 1
  for (int ks = 0; ks < KS; ++ks) {
    bf16x8 ah[4], al[4];
#pragma unroll
    for (int mt = 0; mt < 4; ++mt) {
      int aoff = (mt * 16 + col) * sIn + ks * 32 + quad * 8;
      ah[mt] = *(const bf16x8*)(inHi + aoff);
      al[mt] = *(const bf16x8*)(inLo + aoff);
    }
#pragma unroll
    for (int t = 0; t < T; ++t) {
      size_t boff = (size_t)(n0 + t * 16 + col) * rl + ks * 32 + quad * 8;
      bf16x8 bh = *(const bf16x8*)(wHi + boff);
      bf16x8 bl = *(const bf16x8*)(wLo + boff);
#pragma unroll
      for (int mt = 0; mt < 4; ++mt) {
        acc[mt][t] = __builtin_amdgcn_mfma_f32_16x16x32_bf16(ah[mt], bh, acc[mt][t], 0, 0, 0);
        acc[mt][t] = __builtin_amdgcn_mfma_f32_16x16x32_bf16(ah[mt], bl, acc[mt][t], 0, 0, 0);
        acc[mt][t] = __builtin_amdgcn_mfma_f32_16x16x32_bf16(al[mt], bh, acc[mt][t], 0, 0, 0);
      }
    }
  }
}

template <int T>
__device__ __forceinline__ void store_allm(const f32x4 acc[4][T], int n0,
                                           unsigned short* outHi,
                                           unsigned short* outLo, int sOut,
                                           int lane) {
  const int col = lane & 15, quad = lane >> 4;
#pragma unroll
  for (int mt = 0; mt < 4; ++mt)
#pragma unroll
    for (int t = 0; t < T; ++t)
#pragma unroll
      for (int r = 0; r < 4; ++r) {
        int edge = mt * 16 + quad * 4 + r;
        float v = fmaxf(acc[mt][t][r], 0.f);
        unsigned short h, l;
        split_bf(v, h, l);
        outHi[edge * sOut + n0 + t * 16 + col] = h;
        outLo[edge * sOut + n0 + t * 16 + col] = l;
      }
}

template <int T>
__device__ __forceinline__ void outpool_allm(const f32x4 acc[4][T], int n0,
                                             float* __restrict__ outp, int nvalid,
                                             int lane) {
  const int col = lane & 15, quad = lane >> 4;
#pragma unroll
  for (int t = 0; t < T; ++t) {
    float m = -DEVINF;
#pragma unroll
    for (int mt = 0; mt < 4; ++mt)
#pragma unroll
      for (int r = 0; r < 4; ++r) {
        int edge = mt * 16 + quad * 4 + r;
        float v = fmaxf(acc[mt][t][r], 0.f);
        if (edge >= nvalid) v = -DEVINF;
        m = fmaxf(m, v);
      }
    m = fmaxf(m, __shfl_xor(m, 16, 64));
    m = fmaxf(m, __shfl_xor(m, 32, 64));
    if (quad == 0) outp[n0 + t * 16 + col] = m;
  }
}

// single-m-tile variants (gsa)
template <int KS, int T>
__device__ __forceinline__ void mfma_1m(
    const unsigned short* __restrict__ inHi, const unsigned short* __restrict__ inLo,
    int sIn, const unsigned short* __restrict__ wHi,
    const unsigned short* __restrict__ wLo, int rl, const float* __restrict__ bias,
    int n0, int lane, f32x4 acc[T]) {
  const int col = lane & 15, quad = lane >> 4;
#pragma unroll
  for (int t = 0; t < T; ++t) {
    float bv = bias[n0 + t * 16 + col];
    acc[t].x = bv; acc[t].y = bv; acc[t].z = bv; acc[t].w = bv;
  }
#pragma unroll 1
  for (int ks = 0; ks < KS; ++ks) {
    int aoff = col * sIn + ks * 32 + quad * 8;
    bf16x8 ah = *(const bf16x8*)(inHi + aoff);
    bf16x8 al = *(const bf16x8*)(inLo + aoff);
#pragma unroll
    for (int t = 0; t < T; ++t) {
      size_t boff = (size_t)(n0 + t * 16 + col) * rl + ks * 32 + quad * 8;
      bf16x8 bh = *(const bf16x8*)(wHi + boff);
      bf16x8 bl = *(const bf16x8*)(wLo + boff);
      acc[t] = __builtin_amdgcn_mfma_f32_16x16x32_bf16(ah, bh, acc[t], 0, 0, 0);
      acc[t] = __builtin_amdgcn_mfma_f32_16x16x32_bf16(ah, bl, acc[t], 0, 0, 0);
      acc[t] = __builtin_amdgcn_mfma_f32_16x16x32_bf16(al, bh, acc[t], 0, 0, 0);
    }
  }
}

template <int T>
__device__ __forceinline__ void store_1m(const f32x4 acc[T], int n0,
                                         unsigned short* outHi,
                                         unsigned short* outLo, int sOut, int lane) {
  const int col = lane & 15, quad = lane >> 4;
#pragma unroll
  for (int t = 0; t < T; ++t)
#pragma unroll
    for (int r = 0; r < 4; ++r) {
      int p = quad * 4 + r;
      float v = fmaxf(acc[t][r], 0.f);
      unsigned short h, l;
      split_bf(v, h, l);
      outHi[p * sOut + n0 + t * 16 + col] = h;
      outLo[p * sOut + n0 + t * 16 + col] = l;
    }
}

// ---------------------------------------------------------------------------
// SA1 (MFMA, wave=n-slice) + EMBEDDED fps2 (blocks 0..15, 4-wave).
// Ball query v4: masks stay in registers per wave; cross-wave exclusive
// prefix via tot[4]; extraction is a register-only 8-iter chain (no LDS
// reads). Group order + posn arithmetic identical -> bit-exact.
// ---------------------------------------------------------------------------
__global__ __launch_bounds__(256, 4) void sa1_kernel(
    const float* __restrict__ x,    // [16][2048][9]
    const float* __restrict__ pos,  // [16][2048][3]
    const float* __restrict__ ctr,  // p1: [16][1024][3]
    float* __restrict__ p2,         // [16][256][3] (fps2 output)
    const unsigned short* __restrict__ w1h, const unsigned short* __restrict__ w1l,
    const unsigned short* __restrict__ w2h, const unsigned short* __restrict__ w2l,
    const unsigned short* __restrict__ w3h, const unsigned short* __restrict__ w3l,
    const float* __restrict__ b1, const float* __restrict__ b2,
    const float* __restrict__ b3,
    float* __restrict__ out)        // [16][1024][128]
{
  const int N = 2048;
  const float r2 = (float)(0.2 * 0.2);
  const int tid = threadIdx.x;
  const int w = tid >> 6, lane = tid & 63;
  __shared__ __align__(16) unsigned short smem[4 * 4608];  // 36,864 B
  unsigned short* bufA_hi = smem;
  unsigned short* bufA_lo = smem + 4608;
  unsigned short* bufB_hi = smem + 9216;
  unsigned short* bufB_lo = smem + 13824;
  __shared__ int nb[64];
  __shared__ int tot[4];
  __shared__ unsigned long long kv2[2][4];

  if (blockIdx.x < 16) {
    // ------------- fps2: 1024 -> 256 centers, 4-wave cooperative -------------
    const int bb = blockIdx.x;
    float4* q4 = (float4*)smem;              // 16 KB
    float4* carr = (float4*)(smem + 8192);   // byte offset 16384; 4 KB
    for (int i = tid; i < 1024; i += 256) {
      const float* pr = ctr + ((size_t)bb * 1024 + i) * 3;
      q4[i] = float4{pr[0], pr[1], pr[2], 0.f};
    }
    __syncthreads();
    f32x2 qx[2], qy[2], qz[2], d[2];
    const int ibase = w * 256;
#pragma unroll
    for (int h = 0; h < 2; ++h) {
      int i0 = ibase + (2 * h) * 64 + lane, i1 = i0 + 64;
      float4 a = q4[i0], c = q4[i1];
      qx[h].x = a.x; qx[h].y = c.x;
      qy[h].x = a.y; qy[h].y = c.y;
      qz[h].x = a.z; qz[h].y = c.z;
      d[h].x = DEVINF; d[h].y = DEVINF;
    }
    int last = 0;
    for (int s = 0; s < 256; ++s) {
      float4 c4 = q4[last];
      if (tid == 0) carr[s] = c4;
      unsigned long long k =
          fps_wave_step<2, 2>(qx, qy, qz, d, c4.x, c4.y, c4.z, lane, ibase);
      if (lane == 63) kv2[s & 1][w] = k;
      __syncthreads();
      unsigned long long k0 = kv2[s & 1][0], k1 = kv2[s & 1][1];
      unsigned long long k2 = kv2[s & 1][2], k3 = kv2[s & 1][3];
      unsigned long long ka = k0 > k1 ? k0 : k1;
      unsigned long long kb = k2 > k3 ? k2 : k3;
      unsigned long long kk = ka > kb ? ka : kb;
      last = (int)~(unsigned)kk;
    }
    {
      float4 c = carr[tid];
      p2[((size_t)bb * 256 + tid) * 3 + 0] = c.x;
      p2[((size_t)bb * 256 + tid) * 3 + 1] = c.y;
      p2[((size_t)bb * 256 + tid) * 3 + 2] = c.z;
    }
    return;
  }

  const int bs = blockIdx.x - 16;
  const int b = bs >> 10;
  const float cx = ctr[bs * 3 + 0], cy = ctr[bs * 3 + 1], cz = ctr[bs * 3 + 2];
  // ---- ball query: masks in registers (wave w owns groups w*8..w*8+7) ----
  nb[lane] = 0;
  unsigned long long mloc[8];
  {
#pragma clang fp contract(off)
#pragma unroll
    for (int it = 0; it < 8; ++it) {
      int i = (w * 8 + it) * 64 + lane;
      const float* p = pos + ((size_t)b * N + i) * 3;
      float dx = p[0] - cx, dy = p[1] - cy, dz = p[2] - cz;
      float t0 = dx * dx, t1 = dy * dy, t2 = dz * dz;
      float d2 = (t0 + t1) + t2;
      mloc[it] = __ballot(d2 <= r2);
    }
  }
  {
    int mytot = 0;
#pragma unroll
    for (int it = 0; it < 8; ++it) mytot += (int)__popcll(mloc[it]);
    if (lane == 0) tot[w] = mytot;
  }
  __syncthreads();
  const int t0s = tot[0], t1s = tot[1], t2s = tot[2], t3s = tot[3];
  {
    int cnt = (w > 0 ? t0s : 0) + (w > 1 ? t1s : 0) + (w > 2 ? t2s : 0);
#pragma unroll
    for (int it = 0; it < 8; ++it) {
      unsigned long long m = mloc[it];
      bool inr = (m >> lane) & 1;
      int posn = cnt + (int)__popcll(m & ((1ull << lane) - 1ull));
      if (inr && posn < 64) nb[posn] = (w * 8 + it) * 64 + lane;
      cnt += (int)__popcll(m);
    }
  }
  const int total = t0s + t1s + t2s + t3s;
  const int nvalid = total < 64 ? total : 64;
  __syncthreads();  // nb complete & visible
  // ---- feature staging split across waves: w0..w2 -> x feats, w3 -> rel+pad
  {
    int j = nb[lane];
    if (w < 3) {
      const float* xr = x + ((size_t)b * N + j) * 9 + w * 3;
      float f0 = xr[0], f1 = xr[1], f2 = xr[2];
      unsigned short h, l;
      split_bf(f0, h, l); bufA_hi[lane * 72 + w * 3 + 0] = h; bufA_lo[lane * 72 + w * 3 + 0] = l;
      split_bf(f1, h, l); bufA_hi[lane * 72 + w * 3 + 1] = h; bufA_lo[lane * 72 + w * 3 + 1] = l;
      split_bf(f2, h, l); bufA_hi[lane * 72 + w * 3 + 2] = h; bufA_lo[lane * 72 + w * 3 + 2] = l;
    } else {
      const float* pr = pos + ((size_t)b * N + j) * 3;
      float rr[3] = {pr[0] - cx, pr[1] - cy, pr[2] - cz};
#pragma unroll
      for (int c = 0; c < 3; ++c) {
        unsigned short h, l;
        split_bf(rr[c], h, l);
        bufA_hi[lane * 72 + 9 + c] = h;
        bufA_lo[lane * 72 + 9 + c] = l;
      }
#pragma unroll
      for (int k = 12; k < 32; ++k) {
        bufA_hi[lane * 72 + k] = 0;
        bufA_lo[lane * 72 + k] = 0;
      }
    }
  }
  __syncthreads();
  {  // L1: K=32(12), N=64; wave n-slice [w*16, w*16+16)
    f32x4 acc[4][1];
    mfma_allm<1, 1>(bufA_hi, bufA_lo, 72, w1h, w1l, 40, b1, w * 16, lane, acc);
    store_allm<1>(acc, w * 16, bufB_hi, bufB_lo, 72, lane);
  }
  __syncthreads();
  {  // L2: K=64, N=64; reads B, writes A
    f32x4 acc[4][1];
    mfma_allm<2, 1>(bufB_hi, bufB_lo, 72, w2h, w2l, 72, b2, w * 16, lane, acc);
    store_allm<1>(acc, w * 16, bufA_hi, bufA_lo, 72, lane);
  }
  __syncthreads();
  {  // L3: K=64, N=128; wave n-slice [w*32, w*32+32) + pool
    f32x4 acc[4][2];
    mfma_allm<2, 2>(bufA_hi, bufA_lo, 72, w3h, w3l, 72, b3, w * 32, lane, acc);
    outpool_allm<2>(acc, w * 32, out + (size_t)bs * 128, nvalid, lane);
  }
}

// ---------------------------------------------------------------------------
// SA2 (MFMA, wave=n-slice): register-mask ball query + MLP + maxpool.
// ---------------------------------------------------------------------------
__global__ __launch_bounds__(256, 2) void sa2_kernel(
    const float* __restrict__ x1,   // [16][1024][128]
    const float* __restrict__ pos1, // [16][1024][3]
    const float* __restrict__ ctr,  // [16][256][3]
    const unsigned short* __restrict__ w1h, const unsigned short* __restrict__ w1l,
    const unsigned short* __restrict__ w2h, const unsigned short* __restrict__ w2l,
    const unsigned short* __restrict__ w3h, const unsigned short* __restrict__ w3l,
    const float* __restrict__ b1, const float* __restrict__ b2,
    const float* __restrict__ b3,
    float* __restrict__ out)        // [16][256][256]
{
  const int N = 1024;
  const float r2 = (float)(0.4 * 0.4);
  const int bs = blockIdx.x;
  const int b = bs >> 8;
  const int tid = threadIdx.x;
  const int w = tid >> 6, lane = tid & 63;
  const float cx = ctr[bs * 3 + 0], cy = ctr[bs * 3 + 1], cz = ctr[bs * 3 + 2];
  __shared__ __align__(16) unsigned short bufA_hi[64 * 168], bufA_lo[64 * 168];
  __shared__ __align__(16) unsigned short bufB_hi[64 * 136], bufB_lo[64 * 136];
  __shared__ int nb[64];
  __shared__ int tot[4];
  nb[lane] = 0;
  unsigned long long mloc[4];
  {
#pragma clang fp contract(off)
#pragma unroll
    for (int it = 0; it < 4; ++it) {
      int i = (w * 4 + it) * 64 + lane;
      const float* p = pos1 + ((size_t)b * N + i) * 3;
      float dx = p[0] - cx, dy = p[1] - cy, dz = p[2] - cz;
      float t0 = dx * dx, t1 = dy * dy, t2 = dz * dz;
      float d2 = (t0 + t1) + t2;
      mloc[it] = __ballot(d2 <= r2);
    }
  }
  {
    int mytot = 0;
#pragma unroll
    for (int it = 0; it < 4; ++it) mytot += (int)__popcll(mloc[it]);
    if (lane == 0) tot[w] = mytot;
  }
  __syncthreads();
  const int t0s = tot[0], t1s = tot[1], t2s = tot[2], t3s = tot[3];
  {
    int cnt = (w > 0 ? t0s : 0) + (w > 1 ? t1s : 0) + (w > 2 ? t2s : 0);
#pragma unroll
    for (int it = 0; it < 4; ++it) {
      unsigned long long m = mloc[it];
      bool inr = (m >> lane) & 1;
      int posn = cnt + (int)__popcll(m & ((1ull << lane) - 1ull));
      if (inr && posn < 64) nb[posn] = (w * 4 + it) * 64 + lane;
      cnt += (int)__popcll(m);
    }
  }
  const int total = t0s + t1s + t2s + t3s;
  const int nvalid = total < 64 ? total : 64;
  __syncthreads();  // nb complete & visible
  {  // stage features: quarter w loads k in [32w, 32w+32); w0 also rel+pad
    int j = nb[lane];
    const float* xr = x1 + ((size_t)b * N + j) * 128 + 32 * w;
#pragma unroll
    for (int g = 0; g < 8; ++g) {
      float4 v = *(const float4*)(xr + 4 * g);
      float vv[4] = {v.x, v.y, v.z, v.w};
#pragma unroll
      for (int e = 0; e < 4; ++e) {
        unsigned short h, l;
        split_bf(vv[e], h, l);
        int k = 32 * w + 4 * g + e;
        bufA_hi[lane * 168 + k] = h;
        bufA_lo[lane * 168 + k] = l;
      }
    }
    if (w == 0) {
      const float* pr = pos1 + ((size_t)b * N + j) * 3;
      float rr[3] = {pr[0] - cx, pr[1] - cy, pr[2] - cz};
#pragma unroll
      for (int c = 0; c < 3; ++c) {
        unsigned short h, l;
        split_bf(rr[c], h, l);
        bufA_hi[lane * 168 + 128 + c] = h;
        bufA_lo[lane * 168 + 128 + c] = l;
      }
#pragma unroll
      for (int k = 131; k < 160; ++k) {
        bufA_hi[lane * 168 + k] = 0;
        bufA_lo[lane * 168 + k] = 0;
      }
    }
  }
  __syncthreads();
  {  // L1: K=160(131), N=128; n-slice [w*32, w*32+32)
    f32x4 acc[4][2];
    mfma_allm<5, 2>(bufA_hi, bufA_lo, 168, w1h, w1l, 168, b1, w * 32, lane, acc);
    store_allm<2>(acc, w * 32, bufB_hi, bufB_lo, 136, lane);
  }
  __syncthreads();
  {  // L2: K=128, N=128; reads B, writes A
    f32x4 acc[4][2];
    mfma_allm<4, 2>(bufB_hi, bufB_lo, 136, w2h, w2l, 136, b2, w * 32, lane, acc);
    store_allm<2>(acc, w * 32, bufA_hi, bufA_lo, 168, lane);
  }
  __syncthreads();
  {  // L3: K=128, N=256; n-slice [w*64, w*64+64) + pool
    f32x4 acc[4][4];
    mfma_allm<4, 4>(bufA_hi, bufA_lo, 168, w3h, w3l, 136, b3, w * 64, lane, acc);
    outpool_allm<4>(acc, w * 64, out + (size_t)bs * 256, nvalid, lane);
  }
}

// ---------------------------------------------------------------------------
// Global SA (MFMA): MLP 259->256->512->1024, 16 points/block, wave=n-quarter.
// ---------------------------------------------------------------------------
__global__ __launch_bounds__(256, 2) void gsa_kernel(
    const float* __restrict__ x2,  // [16][256][256]
    const float* __restrict__ p2,  // [16][256][3]
    const unsigned short* __restrict__ g1h, const unsigned short* __restrict__ g1l,
    const unsigned short* __restrict__ g2h, const unsigned short* __restrict__ g2l,
    const unsigned short* __restrict__ g3h, const unsigned short* __restrict__ g3l,
    const float* __restrict__ b1, const float* __restrict__ b2,
    const float* __restrict__ b3,
    float* __restrict__ part)      // [16][16][1024]
{
  const int blk = blockIdx.x;  // 256
  const int bt = blk >> 4, gidx = blk & 15;
  const int tid = threadIdx.x;
  const int w = tid >> 6, lane = tid & 63;
  const int p0 = gidx * 16;
  __shared__ __align__(16) unsigned short inH[16 * 296], inL[16 * 296];
  __shared__ __align__(16) unsigned short h1H[16 * 264], h1L[16 * 264];
  __shared__ __align__(16) unsigned short h2H[16 * 520], h2L[16 * 520];
  {  // stage 16 points x 256 feats + 3 pos + zero pad to 288
    int p = tid >> 4, seg = tid & 15;
    const float* xr = x2 + ((size_t)(bt * 256 + p0 + p)) * 256 + seg * 16;
#pragma unroll
    for (int g = 0; g < 4; ++g) {
      float4 v = *(const float4*)(xr + 4 * g);
      float vv[4] = {v.x, v.y, v.z, v.w};
#pragma unroll
      for (int e = 0; e < 4; ++e) {
        unsigned short h, l;
        split_bf(vv[e], h, l);
        int k = seg * 16 + 4 * g + e;
        inH[p * 296 + k] = h;
        inL[p * 296 + k] = l;
      }
    }
    if (tid < 16) {
      const float* pr = p2 + (bt * 256 + p0 + tid) * 3;
#pragma unroll
      for (int c = 0; c < 3; ++c) {
        unsigned short h, l;
        split_bf(pr[c], h, l);
        inH[tid * 296 + 256 + c] = h;
        inL[tid * 296 + 256 + c] = l;
      }
      for (int k = 259; k < 288; ++k) {
        inH[tid * 296 + k] = 0;
        inL[tid * 296 + k] = 0;
      }
    }
  }
  __syncthreads();
  {  // L1: K=288(259), N=256
    f32x4 acc[4];
    mfma_1m<9, 4>(inH, inL, 296, g1h, g1l, 296, b1, w * 64, lane, acc);
    store_1m<4>(acc, w * 64, h1H, h1L, 264, lane);
  }
  __syncthreads();
  {  // L2: K=256, N=512
    f32x4 acc[8];
    mfma_1m<8, 8>(h1H, h1L, 264, g2h, g2l, 264, b2, w * 128, lane, acc);
    store_1m<8>(acc, w * 128, h2H, h2L, 520, lane);
  }
  __syncthreads();
  {  // L3: K=512, N=1024 + max over 16 points
    f32x4 acc[16];
    mfma_1m<16, 16>(h2H, h2L, 520, g3h, g3l, 520, b3, w * 256, lane, acc);
    const int col = lane & 15;
    float* op = part + ((size_t)(bt * 16 + gidx)) * 1024 + w * 256;
#pragma unroll
    for (int t = 0; t < 16; ++t) {
      float m = -DEVINF;
#pragma unroll
      for (int r = 0; r < 4; ++r) m = fmaxf(m, fmaxf(acc[t][r], 0.f));
      m = fmaxf(m, __shfl_xor(m, 16, 64));
      m = fmaxf(m, __shfl_xor(m, 32, 64));
      if ((lane >> 4) == 0) op[t * 16 + col] = m;
    }
  }
}

// ---------------------------------------------------------------------------
// head1: gmax + l1 + l2 + l3. One block per B-row (16 blocks).
// ---------------------------------------------------------------------------
__global__ __launch_bounds__(256) void head1_kernel(
    const float* __restrict__ part,  // [16][16][1024]
    const float* __restrict__ l1w, const float* __restrict__ l1b,
    const float* __restrict__ l2w, const float* __restrict__ l2b,
    const float* __restrict__ l3w, const float* __restrict__ l3b,
    float* __restrict__ hC)          // [16][256]
{
  const int m = blockIdx.x;
  const int tid = threadIdx.x;
  __shared__ float gA[1024];
  __shared__ float hX[512];
  __shared__ float hY[256];
#pragma unroll
  for (int j = 0; j < 4; ++j) {
    int c = j * 256 + tid;
    float mx = -DEVINF;
#pragma unroll
    for (int t = 0; t < 16; ++t)
      mx = fmaxf(mx, part[((size_t)(m * 16 + t)) * 1024 + c]);
    gA[c] = mx;
  }
  __syncthreads();
  {  // l1: 1024 -> 512, relu
    float a0 = l1b[tid], a1 = l1b[tid + 256];
#pragma unroll 4
    for (int k = 0; k < 1024; ++k) {
      float v = gA[k];
      a0 = fmaf(v, l1w[(size_t)k * 512 + tid], a0);
      a1 = fmaf(v, l1w[(size_t)k * 512 + tid + 256], a1);
    }
    hX[tid] = fmaxf(a0, 0.f);
    hX[tid + 256] = fmaxf(a1, 0.f);
  }
  __syncthreads();
  {  // l2: 512 -> 256, relu
    float a = l2b[tid];
#pragma unroll 4
    for (int k = 0; k < 512; ++k) a = fmaf(hX[k], l2w[(size_t)k * 256 + tid], a);
    hY[tid] = fmaxf(a, 0.f);
  }
  __syncthreads();
  {  // l3: 256 -> 256, no relu
    float a = l3b[tid];
#pragma unroll 4
    for (int k = 0; k < 256; ++k) a = fmaf(hY[k], l3w[(size_t)k * 256 + tid], a);
    hC[(size_t)m * 256 + tid] = a;
  }
}

// ---------------------------------------------------------------------------
// head2: fusion MLP (fw1,fw2,fw3) + l4 + l5. One block per fused row (4).
// ---------------------------------------------------------------------------
__global__ __launch_bounds__(256) void head2_kernel(
    const float* __restrict__ hC,  // [4][1024]
    const float* __restrict__ fw1, const float* __restrict__ fb1,
    const float* __restrict__ fw2, const float* __restrict__ fb2,
    const float* __restrict__ fw3, const float* __restrict__ fb3,
    const float* __restrict__ l4w, const float* __restrict__ l4b,
    const float* __restrict__ l5w, const float* __restrict__ l5b,
    float* __restrict__ out)       // [4][128]
{
  const int m = blockIdx.x;
  const int tid = threadIdx.x;
  __shared__ float A[1024];
  __shared__ float Bf[512];
#pragma unroll
  for (int j = 0; j < 4; ++j) A[j * 256 + tid] = hC[(size_t)m * 1024 + j * 256 + tid];
  __syncthreads();
  {  // fw1: 1024 -> 512 relu, A -> Bf
    float a0 = fb1[tid], a1 = fb1[tid + 256];
#pragma unroll 4
    for (int k = 0; k < 1024; ++k) {
      float v = A[k];
      a0 = fmaf(v, fw1[(size_t)k * 512 + tid], a0);
      a1 = fmaf(v, fw1[(size_t)k * 512 + tid + 256], a1);
    }
    Bf[tid] = fmaxf(a0, 0.f);
    Bf[tid + 256] = fmaxf(a1, 0.f);
  }
  __syncthreads();
  {  // fw2: 512 -> 512 relu, Bf -> A
    float a0 = fb2[tid], a1 = fb2[tid + 256];
#pragma unroll 4
    for (int k = 0; k < 512; ++k) {
      float v = Bf[k];
      a0 = fmaf(v, fw2[(size_t)k * 512 + tid], a0);
      a1 = fmaf(v, fw2[(size_t)k * 512 + tid + 256], a1);
    }
    __syncthreads();
    A[tid] = fmaxf(a0, 0.f);
    A[tid + 256] = fmaxf(a1, 0.f);
  }
  __syncthreads();
  {  // fw3: 512 -> 256 relu, A -> Bf
    float a = fb3[tid];
#pragma unroll 4
    for (int k = 0; k < 512; ++k) a = fmaf(A[k], fw3[(size_t)k * 256 + tid], a);
    __syncthreads();
    Bf[tid] = fmaxf(a, 0.f);
  }
  __syncthreads();
  {  // l4: 256 -> 128 relu, Bf -> A
    if (tid < 128) {
      float a = l4b[tid];
#pragma unroll 4
      for (int k = 0; k < 256; ++k) a = fmaf(Bf[k], l4w[(size_t)k * 128 + tid], a);
      A[tid] = fmaxf(a, 0.f);
    }
  }
  __syncthreads();
  {  // l5: 128 -> 128, A -> out
    if (tid < 128) {
      float a = l5b[tid];
#pragma unroll 4
      for (int k = 0; k < 128; ++k) a = fmaf(A[k], l5w[(size_t)k * 128 + tid], a);
      out[(size_t)m * 128 + tid] = a;
    }
  }
}

// ---------------------------------------------------------------------------
extern "C" void kernel_launch(void* const* d_in, const int* in_sizes, int n_in,
                              void* d_out, int out_size, void* d_ws, size_t ws_size,
                              hipStream_t stream) {
  (void)in_sizes; (void)n_in; (void)out_size; (void)ws_size;
  const float* x    = (const float*)d_in[0];
  const float* pos  = (const float*)d_in[1];
  const float* s1w1 = (const float*)d_in[2];  const float* s1b1 = (const float*)d_in[3];
  const float* s1w2 = (const float*)d_in[4];  const float* s1b2 = (const float*)d_in[5];
  const float* s1w3 = (const float*)d_in[6];  const float* s1b3 = (const float*)d_in[7];
  const float* s2w1 = (const float*)d_in[8];  const float* s2b1 = (const float*)d_in[9];
  const float* s2w2 = (const float*)d_in[10]; const float* s2b2 = (const float*)d_in[11];
  const float* s2w3 = (const float*)d_in[12]; const float* s2b3 = (const float*)d_in[13];
  const float* s3w1 = (const float*)d_in[14]; const float* s3b1 = (const float*)d_in[15];
  const float* s3w2 = (const float*)d_in[16]; const float* s3b2 = (const float*)d_in[17];
  const float* s3w3 = (const float*)d_in[18]; const float* s3b3 = (const float*)d_in[19];
  const float* fw1  = (const float*)d_in[20]; const float* fb1  = (const float*)d_in[21];
  const float* fw2  = (const float*)d_in[22]; const float* fb2  = (const float*)d_in[23];
  const float* fw3  = (const float*)d_in[24]; const float* fb3  = (const float*)d_in[25];
  const float* l1w  = (const float*)d_in[26]; const float* l1b  = (const float*)d_in[27];
  const float* l2w  = (const float*)d_in[28]; const float* l2b  = (const float*)d_in[29];
  const float* l3w  = (const float*)d_in[30]; const float* l3b  = (const float*)d_in[31];
  const float* l4w  = (const float*)d_in[32]; const float* l4b  = (const float*)d_in[33];
  const float* l5w  = (const float*)d_in[34]; const float* l5b  = (const float*)d_in[35];
  float* out = (float*)d_out;

  float* ws = (float*)d_ws;
  float* p1   = ws;                  // 16*1024*3
  float* x1   = p1 + 49152;          // 16*1024*128
  float* p2   = x1 + 2097152;        // 16*256*3
  float* x2   = p2 + 12288;          // 16*256*256
  float* part = x2 + 1048576;        // 16*16*1024
  float* hC   = part + 262144;       // 16*256
  // bf16 hi/lo transposed weight planes (u16)
  unsigned short* wp = (unsigned short*)(hC + 4096);
  unsigned short* s1w1h = wp;              unsigned short* s1w1l = s1w1h + 2560;    // [64][40]
  unsigned short* s1w2h = s1w1l + 2560;    unsigned short* s1w2l = s1w2h + 4608;    // [64][72]
  unsigned short* s1w3h = s1w2l + 4608;    unsigned short* s1w3l = s1w3h + 9216;    // [128][72]
  unsigned short* s2w1h = s1w3l + 9216;    unsigned short* s2w1l = s2w1h + 21504;   // [128][168]
  unsigned short* s2w2h = s2w1l + 21504;   unsigned short* s2w2l = s2w2h + 17408;   // [128][136]
  unsigned short* s2w3h = s2w2l + 17408;   unsigned short* s2w3l = s2w3h + 34816;   // [256][136]
  unsigned short* g1h   = s2w3l + 34816;   unsigned short* g1l   = g1h + 75776;     // [256][296]
  unsigned short* g2h   = g1l + 75776;     unsigned short* g2l   = g2h + 135168;    // [512][264]
  unsigned short* g3h   = g2l + 135168;    unsigned short* g3l   = g3h + 532480;    // [1024][520]

  PrepJobs jb;
  const float* srcs[9] = {s1w1, s1w2, s1w3, s2w1, s2w2, s2w3, s3w1, s3w2, s3w3};
  unsigned short* his[9] = {s1w1h, s1w2h, s1w3h, s2w1h, s2w2h, s2w3h, g1h, g2h, g3h};
  unsigned short* los[9] = {s1w1l, s1w2l, s1w3l, s2w1l, s2w2l, s2w3l, g1l, g2l, g3l};
  int Ks[9]  = {12, 64, 64, 131, 128, 128, 259, 256, 512};
  int Ns[9]  = {64, 64, 128, 128, 128, 256, 256, 512, 1024};
  int rls[9] = {40, 72, 72, 168, 136, 136, 296, 264, 520};
  int acc_blk = 0;
  for (int j = 0; j < 9; ++j) {
    jb.src[j] = srcs[j]; jb.hi[j] = his[j]; jb.lo[j] = los[j];
    jb.K[j] = Ks[j]; jb.N[j] = Ns[j]; jb.rl[j] = rls[j];
    jb.blk0[j] = acc_blk;
    acc_blk += (Ns[j] * rls[j] + 255) / 256;   // 256-thread granularity
  }
  jb.blk0[9] = acc_blk;

  fps1_prep_kernel<<<16 + acc_blk, 256, 0, stream>>>(pos, p1, jb);
  sa1_kernel<<<16 * 1024 + 16, 256, 0, stream>>>(x, pos, p1, p2, s1w1h, s1w1l,
                                                 s1w2h, s1w2l, s1w3h, s1w3l,
                                                 s1b1, s1b2, s1b3, x1);
  sa2_kernel<<<16 * 256, 256, 0, stream>>>(x1, p1, p2, s2w1h, s2w1l, s2w2h,
                                           s2w2l, s2w3h, s2w3l, s2b1, s2b2,
                                           s2b3, x2);
  gsa_kernel<<<256, 256, 0, stream>>>(x2, p2, g1h, g1l, g2h, g2l, g3h, g3l,
                                      s3b1, s3b2, s3b3, part);
  head1_kernel<<<16, 256, 0, stream>>>(part, l1w, l1b, l2w, l2b, l3w, l3b, hC);
  head2_kernel<<<4, 256, 0, stream>>>(hC, fw1, fb1, fw2, fb2, fw3, fb3, l4w,
                                      l4b, l5w, l5b, out);
}